// Round 3
// baseline (6817.344 us; speedup 1.0000x reference)
//
#include <hip/hip_runtime.h>

// NeuroSATAssign: B=4, L=2048, NC=4096, D=128, ITERS=4, NH=8, T=1024.
// Round 3: DTYPE-ADAPTIVE. Rounds 1-2 NaN'd with bf16-input assumption and
// the code has no arithmetic NaN path -> inputs are likely f32. Detector
// kernel inspects adjacency words ({0.0,1.0} exactly iff f32); all weights
// are upcast/copied into an f32 pool; adjacency GEMMs and output stores
// branch on the detected flag. f32 compute throughout.

#define B_    4
#define L_    2048
#define NC_   4096
#define D_    128
#define ITERS_ 4
#define NH_   8
#define T_    1024
#define C2_   256
#define HD_   32
#define BL_   (B_*L_)    // 8192
#define BNC_  (B_*NC_)   // 16384
#define RCH_  1024       // LSTM chunk rows

typedef unsigned short u16;

static __device__ __forceinline__ float bf2f(u16 u){
  union{unsigned int i; float f;} x; x.i = ((unsigned int)u) << 16; return x.f;
}
static __device__ __forceinline__ u16 f2bf(float f){
  union{float f; unsigned int i;} x; x.f = f;
  unsigned int r = x.i + 0x7fffu + ((x.i >> 16) & 1u);
  return (u16)(r >> 16);
}
static __device__ __forceinline__ float sigm(float x){ return 1.f/(1.f+expf(-x)); }

// ---- dtype detect: adjacency is exactly {0.0f,1.0f} iff stored as f32 ----
__global__ __launch_bounds__(256) void k_detect(const unsigned int* __restrict__ a,
                                                int* __restrict__ flag){
  int bad = 0;
  for (int i = threadIdx.x; i < 32768; i += 256){
    unsigned int w = a[i];
    if (w != 0u && w != 0x3F800000u) bad = 1;
  }
  __shared__ int s[256];
  s[threadIdx.x] = bad; __syncthreads();
  for (int o = 128; o > 0; o >>= 1){
    if (threadIdx.x < o) s[threadIdx.x] |= s[threadIdx.x + o];
    __syncthreads();
  }
  if (threadIdx.x == 0) *flag = s[0];   // 1 = bf16 inputs, 0 = f32 inputs
}

// ---- convert input tensor -> f32 pool (branch on flag) ----
__global__ __launch_bounds__(256) void k_cvt(const void* __restrict__ src,
                                             float* __restrict__ dst, int n,
                                             const int* __restrict__ flag){
  int i = blockIdx.x*256 + threadIdx.x;
  if (i >= n) return;
  if (*flag) dst[i] = bf2f(((const u16*)src)[i]);
  else       dst[i] = ((const float*)src)[i];
}

// ---------------- init: h[i] = init[i%D], c[i] = 0 ----------------
__global__ __launch_bounds__(256) void k_init(float* __restrict__ h, float* __restrict__ c,
                                              const float* __restrict__ init, int n){
  int i = blockIdx.x*256 + threadIdx.x;
  if (i < n){ h[i] = init[i & (D_-1)]; c[i] = 0.f; }
}

// ------------- GEMM: C[M,N] = act(A_f32[M,K] @ W_f32[K,N] + bias) -------------
// 64x64 tile, BK=16, 256 threads, 4x4 per thread.
template<int ACT>
__global__ __launch_bounds__(256) void k_gemm_aw(const float* __restrict__ A,
    const float* __restrict__ W, const float* __restrict__ bias,
    float* __restrict__ C, int M, int N, int K)
{
  __shared__ float As[64][17];
  __shared__ float Ws[16][65];
  int tid = threadIdx.x;
  int bm = blockIdx.y*64, bn = blockIdx.x*64;
  int tx = tid & 15, ty = tid >> 4;
  int la_m = tid >> 2, la_k = (tid & 3)*4;
  int lw_k = tid >> 4, lw_n = (tid & 15)*4;
  float acc[4][4] = {};
  for (int k0 = 0; k0 < K; k0 += 16){
    float4 av = *(const float4*)(A + (size_t)(bm+la_m)*K + k0 + la_k);
    As[la_m][la_k+0]=av.x; As[la_m][la_k+1]=av.y; As[la_m][la_k+2]=av.z; As[la_m][la_k+3]=av.w;
    float4 wv = *(const float4*)(W + (size_t)(k0+lw_k)*N + bn + lw_n);
    Ws[lw_k][lw_n+0]=wv.x; Ws[lw_k][lw_n+1]=wv.y; Ws[lw_k][lw_n+2]=wv.z; Ws[lw_k][lw_n+3]=wv.w;
    __syncthreads();
    #pragma unroll
    for (int kk = 0; kk < 16; kk++){
      float a[4], b[4];
      #pragma unroll
      for (int i = 0; i < 4; i++) a[i] = As[ty*4+i][kk];
      #pragma unroll
      for (int j = 0; j < 4; j++) b[j] = Ws[kk][tx*4+j];
      #pragma unroll
      for (int i = 0; i < 4; i++)
        #pragma unroll
        for (int j = 0; j < 4; j++) acc[i][j] += a[i]*b[j];
    }
    __syncthreads();
  }
  #pragma unroll
  for (int i = 0; i < 4; i++){
    size_t m = bm + ty*4 + i;
    #pragma unroll
    for (int j = 0; j < 4; j++){
      int n = bn + tx*4 + j;
      float vv = acc[i][j];
      if (bias) vv += bias[n];
      if (ACT) vv = fmaxf(vv, 0.f);
      C[m*(size_t)N + n] = vv;
    }
  }
}

// ------- CL = A @ M : per-batch z; A dtype selected by flag -------
__global__ __launch_bounds__(256) void k_gemm_nn_adj(const void* __restrict__ Agv,
    const float* __restrict__ Bm, float* __restrict__ C, int M, int N, int K,
    const int* __restrict__ flag)
{
  int b = blockIdx.z;
  const int isbf = *flag;
  Bm += (size_t)b*K*N; C += (size_t)b*M*N;
  const size_t abase = (size_t)b*M*K;
  __shared__ float As[64][17];
  __shared__ float Bs[16][65];
  int tid = threadIdx.x;
  int bm = blockIdx.y*64, bn = blockIdx.x*64;
  int tx = tid & 15, ty = tid >> 4;
  int la_m = tid >> 2, la_k = (tid & 3)*4;
  int lb_k = tid >> 4, lb_n = (tid & 15)*4;
  float acc[4][4] = {};
  for (int k0 = 0; k0 < K; k0 += 16){
    size_t ai = abase + (size_t)(bm+la_m)*K + k0 + la_k;
    if (isbf){
      ushort4 av = *(const ushort4*)((const u16*)Agv + ai);
      As[la_m][la_k+0]=bf2f(av.x); As[la_m][la_k+1]=bf2f(av.y);
      As[la_m][la_k+2]=bf2f(av.z); As[la_m][la_k+3]=bf2f(av.w);
    } else {
      float4 av = *(const float4*)((const float*)Agv + ai);
      As[la_m][la_k+0]=av.x; As[la_m][la_k+1]=av.y; As[la_m][la_k+2]=av.z; As[la_m][la_k+3]=av.w;
    }
    float4 bv = *(const float4*)(Bm + (size_t)(k0+lb_k)*N + bn + lb_n);
    Bs[lb_k][lb_n+0]=bv.x; Bs[lb_k][lb_n+1]=bv.y; Bs[lb_k][lb_n+2]=bv.z; Bs[lb_k][lb_n+3]=bv.w;
    __syncthreads();
    #pragma unroll
    for (int kk = 0; kk < 16; kk++){
      float a[4], b2[4];
      #pragma unroll
      for (int i = 0; i < 4; i++) a[i] = As[ty*4+i][kk];
      #pragma unroll
      for (int j = 0; j < 4; j++) b2[j] = Bs[kk][tx*4+j];
      #pragma unroll
      for (int i = 0; i < 4; i++)
        #pragma unroll
        for (int j = 0; j < 4; j++) acc[i][j] += a[i]*b2[j];
    }
    __syncthreads();
  }
  #pragma unroll
  for (int i = 0; i < 4; i++){
    size_t m = bm + ty*4 + i;
    #pragma unroll
    for (int j = 0; j < 4; j++) C[m*(size_t)N + bn + tx*4 + j] = acc[i][j];
  }
}

// --- LC = A^T @ M : A stored [K, M]; A dtype selected by flag ---
__global__ __launch_bounds__(256) void k_gemm_tn_adj(const void* __restrict__ Agv,
    const float* __restrict__ Bm, float* __restrict__ C, int M, int N, int K,
    const int* __restrict__ flag)
{
  int b = blockIdx.z;
  const int isbf = *flag;
  Bm += (size_t)b*(size_t)K*N; C += (size_t)b*(size_t)M*N;
  const size_t abase = (size_t)b*(size_t)K*M;
  __shared__ float As[16][65];
  __shared__ float Bs[16][65];
  int tid = threadIdx.x;
  int bm = blockIdx.y*64, bn = blockIdx.x*64;
  int tx = tid & 15, ty = tid >> 4;
  int lk = tid >> 4, lm = (tid & 15)*4;
  float acc[4][4] = {};
  for (int k0 = 0; k0 < K; k0 += 16){
    size_t ai = abase + (size_t)(k0+lk)*M + bm + lm;
    if (isbf){
      ushort4 av = *(const ushort4*)((const u16*)Agv + ai);
      As[lk][lm+0]=bf2f(av.x); As[lk][lm+1]=bf2f(av.y); As[lk][lm+2]=bf2f(av.z); As[lk][lm+3]=bf2f(av.w);
    } else {
      float4 av = *(const float4*)((const float*)Agv + ai);
      As[lk][lm+0]=av.x; As[lk][lm+1]=av.y; As[lk][lm+2]=av.z; As[lk][lm+3]=av.w;
    }
    float4 bv = *(const float4*)(Bm + (size_t)(k0+lk)*N + bn + lm);
    Bs[lk][lm+0]=bv.x; Bs[lk][lm+1]=bv.y; Bs[lk][lm+2]=bv.z; Bs[lk][lm+3]=bv.w;
    __syncthreads();
    #pragma unroll
    for (int kk = 0; kk < 16; kk++){
      float a[4], b2[4];
      #pragma unroll
      for (int i = 0; i < 4; i++) a[i] = As[kk][ty*4+i];
      #pragma unroll
      for (int j = 0; j < 4; j++) b2[j] = Bs[kk][tx*4+j];
      #pragma unroll
      for (int i = 0; i < 4; i++)
        #pragma unroll
        for (int j = 0; j < 4; j++) acc[i][j] += a[i]*b2[j];
    }
    __syncthreads();
  }
  #pragma unroll
  for (int i = 0; i < 4; i++){
    size_t m = bm + ty*4 + i;
    #pragma unroll
    for (int j = 0; j < 4; j++) C[m*(size_t)N + bn + tx*4 + j] = acc[i][j];
  }
}

// --------- fused LN + LSTM pointwise. One block (128 thr) per row ---------
__global__ __launch_bounds__(128) void k_lstm(const float* __restrict__ g1,
    const float* __restrict__ g2,
    const float* __restrict__ lni_g, const float* __restrict__ lni_b,
    const float* __restrict__ lnh_g, const float* __restrict__ lnh_b,
    const float* __restrict__ lnc_g, const float* __restrict__ lnc_b,
    float* __restrict__ h, float* __restrict__ c)
{
  int row = blockIdx.x, t = threadIdx.x;
  const float* r1 = g1 + (size_t)row*(4*D_);
  const float* r2 = g2 + (size_t)row*(4*D_);
  float x1[4], x2[4];
  float s1 = 0.f, q1 = 0.f, s2 = 0.f, q2 = 0.f;
  #pragma unroll
  for (int q = 0; q < 4; q++){
    x1[q] = r1[q*D_ + t]; x2[q] = r2[q*D_ + t];
    s1 += x1[q]; q1 += x1[q]*x1[q];
    s2 += x2[q]; q2 += x2[q]*x2[q];
  }
  #pragma unroll
  for (int off = 32; off > 0; off >>= 1){
    s1 += __shfl_down(s1, off); q1 += __shfl_down(q1, off);
    s2 += __shfl_down(s2, off); q2 += __shfl_down(q2, off);
  }
  __shared__ float red[4][2];
  int wid = t >> 6, lane = t & 63;
  if (lane == 0){ red[0][wid]=s1; red[1][wid]=q1; red[2][wid]=s2; red[3][wid]=q2; }
  __syncthreads();
  s1 = red[0][0]+red[0][1]; q1 = red[1][0]+red[1][1];
  s2 = red[2][0]+red[2][1]; q2 = red[3][0]+red[3][1];
  const float inv512 = 1.f/512.f;
  float m1 = s1*inv512, v1 = fmaxf(q1*inv512 - m1*m1, 0.f), rs1 = rsqrtf(v1 + 1e-5f);
  float m2 = s2*inv512, v2 = fmaxf(q2*inv512 - m2*m2, 0.f), rs2 = rsqrtf(v2 + 1e-5f);
  float gate[4];
  #pragma unroll
  for (int q = 0; q < 4; q++){
    int p = q*D_ + t;
    gate[q] = (x1[q]-m1)*rs1*lni_g[p] + lni_b[p]
            + (x2[q]-m2)*rs2*lnh_g[p] + lnh_b[p];
  }
  float iv = sigm(gate[0]), fv = sigm(gate[1]), gv = tanhf(gate[2]), ov = sigm(gate[3]);
  size_t hi = (size_t)row*D_ + t;
  float pre = fv*c[hi] + iv*gv;
  float s = pre, qq = pre*pre;
  #pragma unroll
  for (int off = 32; off > 0; off >>= 1){ s += __shfl_down(s, off); qq += __shfl_down(qq, off); }
  __syncthreads();
  if (lane == 0){ red[0][wid] = s; red[1][wid] = qq; }
  __syncthreads();
  s = red[0][0]+red[0][1]; qq = red[1][0]+red[1][1];
  const float inv128 = 1.f/128.f;
  float m = s*inv128, v = fmaxf(qq*inv128 - m*m, 0.f), rs = rsqrtf(v + 1e-5f);
  float cy = (pre - m)*rs*lnc_g[t] + lnc_b[t];
  c[hi] = cy;
  h[hi] = ov*tanhf(cy);
}

// --------- build literal-LSTM input: [CL | flip(Lh)] ---------
__global__ __launch_bounds__(256) void k_cat(const float* __restrict__ CL,
    const float* __restrict__ Lh, float* __restrict__ outb)
{
  int i = blockIdx.x*256 + threadIdx.x;
  if (i >= BL_*D_) return;
  int d = i & (D_-1);
  int r = i >> 7;          // b*L + l
  int l = r & (L_-1);
  int b = r >> 11;
  outb[(size_t)r*C2_ + d] = CL[i];
  int lf = (l + T_) & (L_-1);
  outb[(size_t)r*C2_ + D_ + d] = Lh[(size_t)(b*L_ + lf)*D_ + d];
}

// --------- readout: read[b,t] = mask * [Lh[b,t] | Lh[b,t+T]] ---------
__global__ __launch_bounds__(256) void k_read(const float* __restrict__ Lh,
    const int* __restrict__ counts, float* __restrict__ rd)
{
  int i = blockIdx.x*256 + threadIdx.x;
  if (i >= B_*T_*D_) return;
  int d = i & (D_-1);
  int r = i >> 7;          // b*T + t
  int t = r & (T_-1);
  int b = r >> 10;
  int half = counts[b] / 2; if (half > T_) half = T_;
  float m = (t < half) ? 1.f : 0.f;
  rd[(size_t)r*C2_ + d]      = m * Lh[(size_t)(b*L_ + t)*D_ + d];
  rd[(size_t)r*C2_ + D_ + d] = m * Lh[(size_t)(b*L_ + t + T_)*D_ + d];
}

// --------- fused attention: one wave per (b, h, t) row ---------
__global__ __launch_bounds__(64) void k_attn(const float* __restrict__ q,
    const float* __restrict__ k, const float* __restrict__ v,
    const int* __restrict__ counts, float* __restrict__ y)
{
  int t = blockIdx.x, h = blockIdx.y, b = blockIdx.z, lane = threadIdx.x;
  int half = counts[b] / 2; if (half > T_) half = T_;
  float* yrow = y + ((size_t)(b*T_ + t)*C2_ + h*HD_);
  if (t >= half){ if (lane < HD_) yrow[lane] = 0.f; return; }
  __shared__ float sc[T_];
  __shared__ float qs[HD_];
  const float* qrow = q + ((size_t)(b*T_ + t)*C2_ + h*HD_);
  if (lane < HD_) qs[lane] = qrow[lane];
  __syncthreads();
  const float scale = 0.17677669529663687f;  // 1/sqrt(32)
  for (int s = lane; s < T_; s += 64){
    float d = -1e30f;
    if (s < half){
      const float* kr = k + ((size_t)(b*T_ + s)*C2_ + h*HD_);
      float acc = 0.f;
      #pragma unroll
      for (int j = 0; j < HD_; j++) acc += qs[j]*kr[j];
      d = acc*scale;
    }
    sc[s] = d;
  }
  float mx = -1e30f;
  for (int s = lane; s < T_; s += 64) mx = fmaxf(mx, sc[s]);
  #pragma unroll
  for (int off = 32; off > 0; off >>= 1) mx = fmaxf(mx, __shfl_down(mx, off));
  mx = __shfl(mx, 0);
  float sum = 0.f;
  for (int s = lane; s < T_; s += 64){
    float p = (sc[s] > -1e29f) ? expf(sc[s] - mx) : 0.f;
    sc[s] = p; sum += p;
  }
  #pragma unroll
  for (int off = 32; off > 0; off >>= 1) sum += __shfl_down(sum, off);
  sum = __shfl(sum, 0);
  __syncthreads();
  float inv = (sum > 0.f) ? 1.f/sum : 0.f;
  int d = lane & 31, part = lane >> 5;
  float acc = 0.f;
  for (int s = part; s < half; s += 2)
    acc += sc[s] * v[((size_t)(b*T_ + s)*C2_ + h*HD_) + d];
  acc += __shfl_down(acc, 32);
  if (lane < 32) yrow[d] = acc*inv;
}

// --------- final heads: dot-128 + sigmoid; assignments out + vote atomics ---------
__global__ __launch_bounds__(128) void k_final(const float* __restrict__ ah,
    const float* __restrict__ vh,
    const float* __restrict__ aW2, const float* __restrict__ ab2,
    const float* __restrict__ vW2, const float* __restrict__ vb2,
    const int* __restrict__ counts, void* __restrict__ outv,
    float* __restrict__ vote_sum, const int* __restrict__ flag)
{
  int row = blockIdx.x, tid = threadIdx.x;
  int b = row / T_, t = row - b*T_;
  int half = counts[b] / 2; if (half > T_) half = T_;
  float pa = ah[(size_t)row*D_ + tid] * aW2[tid];
  float pv = vh[(size_t)row*D_ + tid] * vW2[tid];
  #pragma unroll
  for (int off = 32; off > 0; off >>= 1){ pa += __shfl_down(pa, off); pv += __shfl_down(pv, off); }
  __shared__ float r[2][2];
  int wid = tid >> 6, lane = tid & 63;
  if (lane == 0){ r[0][wid] = pa; r[1][wid] = pv; }
  __syncthreads();
  if (tid == 0){
    float a  = sigm(r[0][0] + r[0][1] + ab2[0]);
    float vv = sigm(r[1][0] + r[1][1] + vb2[0]);
    bool mk = (t < half);
    float av = mk ? a : 0.f;
    if (*flag) ((u16*)outv)[4 + row] = f2bf(av);
    else       ((float*)outv)[4 + row] = av;
    if (mk) atomicAdd(vote_sum + b, vv);
  }
}

__global__ void k_zero(float* p, int n){
  int i = blockIdx.x*64 + threadIdx.x; if (i < n) p[i] = 0.f;
}

__global__ void k_votes(const float* __restrict__ vote_sum, const int* __restrict__ counts,
                        void* __restrict__ outv, const int* __restrict__ flag){
  int b = threadIdx.x;
  if (b < B_){
    int half = counts[b] / 2; if (half > T_) half = T_;
    float den = (float)(half > 1 ? half : 1);
    float vv = vote_sum[b] / den;
    if (*flag) ((u16*)outv)[b] = f2bf(vv);
    else       ((float*)outv)[b] = vv;
  }
}

static void gemm_aw(const float* A, const float* W, const float* bias, float* C,
                    int M, int N, int K, int act, hipStream_t s){
  dim3 g(N/64, M/64);
  if (act) k_gemm_aw<1><<<g, 256, 0, s>>>(A, W, bias, C, M, N, K);
  else     k_gemm_aw<0><<<g, 256, 0, s>>>(A, W, bias, C, M, N, K);
}

extern "C" void kernel_launch(void* const* d_in, const int* in_sizes, int n_in,
                              void* d_out, int out_size, void* d_ws, size_t ws_size,
                              hipStream_t stream)
{
  const void* A_adj = d_in[0];
  const int* counts = (const int*)d_in[1];

  // workspace layout (floats)
  const size_t M_LH = (size_t)BL_*D_;    // 1,048,576
  const size_t M_CH = (size_t)BNC_*D_;   // 2,097,152
  const size_t M_G  = (size_t)RCH_*4*D_; // 524,288
  const size_t WPOOL = 700000;
  const size_t NEED = (2*M_LH + 2*M_CH + 2*M_CH + 2*M_G + WPOOL + 16) * sizeof(float);
  if (ws_size < NEED) return;  // out stays zeroed by harness -> finite absmax diagnostic

  float* ws   = (float*)d_ws;
  float* Lh   = ws;
  float* Lc   = Lh + M_LH;
  float* Ch   = Lc + M_LH;
  float* Cc   = Ch + M_CH;
  float* bufA = Cc + M_CH;          // 2M
  float* bufB = bufA + M_CH;        // 2M
  float* g1   = bufB + M_CH;        // 0.5M
  float* g2   = g1 + M_G;           // 0.5M
  float* wp   = g2 + M_G;           // weight pool
  float* tail = wp + WPOOL;
  float* vote_sum = tail;           // 4 floats
  int*   flag = (int*)(tail + 8);

  // ---- detect dtype ----
  k_detect<<<1, 256, 0, stream>>>((const unsigned int*)A_adj, flag);

  // ---- convert all weight/param tensors to f32 pool ----
  size_t off = 0;
  auto alloc = [&](size_t n)->float*{ float* p = wp + off; off += (n + 3) & ~(size_t)3; return p; };
  #define CVT(idx, n) ({ float* _d = alloc(n); \
    k_cvt<<<((n)+255)/256, 256, 0, stream>>>(d_in[idx], _d, (n), flag); _d; })

  float* Linit = CVT(2, D_);
  float* Cinit = CVT(3, D_);
  float *LC_W1=CVT(4,D_*D_),  *LC_b1=CVT(5,D_);
  float *LC_W2=CVT(6,D_*D_),  *LC_b2=CVT(7,D_);
  float *LC_W3=CVT(8,D_*D_),  *LC_b3=CVT(9,D_);
  float *CL_W1=CVT(10,D_*D_), *CL_b1=CVT(11,D_);
  float *CL_W2=CVT(12,D_*D_), *CL_b2=CVT(13,D_);
  float *CL_W3=CVT(14,D_*D_), *CL_b3=CVT(15,D_);
  float *Lu_Wih=CVT(16,2*D_*4*D_), *Lu_Whh=CVT(17,D_*4*D_);
  float *Lu_lni_g=CVT(18,4*D_), *Lu_lni_b=CVT(19,4*D_);
  float *Lu_lnh_g=CVT(20,4*D_), *Lu_lnh_b=CVT(21,4*D_);
  float *Lu_lnc_g=CVT(22,D_),   *Lu_lnc_b=CVT(23,D_);
  float *Cu_Wih=CVT(24,D_*4*D_), *Cu_Whh=CVT(25,D_*4*D_);
  float *Cu_lni_g=CVT(26,4*D_), *Cu_lni_b=CVT(27,4*D_);
  float *Cu_lnh_g=CVT(28,4*D_), *Cu_lnh_b=CVT(29,4*D_);
  float *Cu_lnc_g=CVT(30,D_),   *Cu_lnc_b=CVT(31,D_);
  float *att_Wk=CVT(32,C2_*C2_), *att_bk=CVT(33,C2_);
  float *att_Wq=CVT(34,C2_*C2_), *att_bq=CVT(35,C2_);
  float *att_Wv=CVT(36,C2_*C2_), *att_bv=CVT(37,C2_);
  float *asn_W1=CVT(38,C2_*D_), *asn_b1=CVT(39,D_);
  float *asn_W2=CVT(40,D_),     *asn_b2=CVT(41,1);
  float *vote_W1=CVT(42,C2_*D_), *vote_b1=CVT(43,D_);
  float *vote_W2=CVT(44,D_),     *vote_b2=CVT(45,1);
  #undef CVT

  k_init<<<(BL_*D_)/256, 256, 0, stream>>>(Lh, Lc, Linit, BL_*D_);
  k_init<<<(BNC_*D_)/256, 256, 0, stream>>>(Ch, Cc, Cinit, BNC_*D_);

  for (int it = 0; it < ITERS_; ++it){
    // literal -> clause messages: msgL = MLP3(Lh)
    gemm_aw(Lh,          LC_W1, LC_b1, bufA,        BL_, D_, D_, 1, stream);
    gemm_aw(bufA,        LC_W2, LC_b2, bufA + M_LH, BL_, D_, D_, 1, stream);
    gemm_aw(bufA + M_LH, LC_W3, LC_b3, bufA,        BL_, D_, D_, 0, stream);
    // LC[b] = A[b]^T @ msgL[b]  -> bufB [BNC, D]
    { dim3 g(D_/64, NC_/64, B_);
      k_gemm_tn_adj<<<g, 256, 0, stream>>>(A_adj, bufA, bufB, NC_, D_, L_, flag); }
    // clause LSTM, chunked
    for (int c0 = 0; c0 < BNC_; c0 += RCH_){
      gemm_aw(bufB + (size_t)c0*D_, Cu_Wih, nullptr, g1, RCH_, 4*D_, D_, 0, stream);
      gemm_aw(Ch   + (size_t)c0*D_, Cu_Whh, nullptr, g2, RCH_, 4*D_, D_, 0, stream);
      k_lstm<<<RCH_, 128, 0, stream>>>(g1, g2, Cu_lni_g, Cu_lni_b, Cu_lnh_g, Cu_lnh_b,
                                       Cu_lnc_g, Cu_lnc_b, Ch + (size_t)c0*D_, Cc + (size_t)c0*D_);
    }
    // clause -> literal messages: msgC = MLP3(Ch)
    gemm_aw(Ch,   CL_W1, CL_b1, bufA, BNC_, D_, D_, 1, stream);
    gemm_aw(bufA, CL_W2, CL_b2, bufB, BNC_, D_, D_, 1, stream);
    gemm_aw(bufB, CL_W3, CL_b3, bufA, BNC_, D_, D_, 0, stream);
    // CL[b] = A[b] @ msgC[b]  -> bufB[0 .. BL*D)
    { dim3 g(D_/64, L_/64, B_);
      k_gemm_nn_adj<<<g, 256, 0, stream>>>(A_adj, bufA, bufB, L_, D_, NC_, flag); }
    // literal LSTM input = [CL | flip(Lh)] -> bufA [BL, 2D]
    k_cat<<<(BL_*D_)/256, 256, 0, stream>>>(bufB, Lh, bufA);
    for (int c0 = 0; c0 < BL_; c0 += RCH_){
      gemm_aw(bufA + (size_t)c0*C2_, Lu_Wih, nullptr, g1, RCH_, 4*D_, 2*D_, 0, stream);
      gemm_aw(Lh   + (size_t)c0*D_,  Lu_Whh, nullptr, g2, RCH_, 4*D_, D_, 0, stream);
      k_lstm<<<RCH_, 128, 0, stream>>>(g1, g2, Lu_lni_g, Lu_lni_b, Lu_lnh_g, Lu_lnh_b,
                                       Lu_lnc_g, Lu_lnc_b, Lh + (size_t)c0*D_, Lc + (size_t)c0*D_);
    }
  }

  // readout + attention: reuse dead clause-phase regions
  float* readb = Ch;                // 1M
  float* qb    = Cc;                // 1M
  float* kb    = bufA;              // 1M
  float* vb    = bufA + M_LH;       // 1M
  float* yb    = bufB;              // 1M
  float* ah    = bufB + M_LH;       // 0.5M
  float* vh    = ah + (size_t)(B_*T_)*D_;  // 0.5M

  k_read<<<(B_*T_*D_)/256, 256, 0, stream>>>(Lh, counts, readb);
  gemm_aw(readb, att_Wq, att_bq, qb, B_*T_, C2_, C2_, 0, stream);
  gemm_aw(readb, att_Wk, att_bk, kb, B_*T_, C2_, C2_, 0, stream);
  gemm_aw(readb, att_Wv, att_bv, vb, B_*T_, C2_, C2_, 0, stream);
  { dim3 g(T_, NH_, B_); k_attn<<<g, 64, 0, stream>>>(qb, kb, vb, counts, yb); }
  gemm_aw(yb, asn_W1,  asn_b1,  ah, B_*T_, D_, C2_, 1, stream);
  gemm_aw(yb, vote_W1, vote_b1, vh, B_*T_, D_, C2_, 1, stream);
  k_zero<<<1, 64, 0, stream>>>(vote_sum, B_);
  k_final<<<B_*T_, 128, 0, stream>>>(ah, vh, asn_W2, asn_b2, vote_W2, vote_b2,
                                     counts, d_out, vote_sum, flag);
  k_votes<<<1, 64, 0, stream>>>(vote_sum, counts, d_out, flag);
}

// Round 4
// 4027.831 us; speedup vs baseline: 1.6926x; 1.6926x over previous
//
#include <hip/hip_runtime.h>

// NeuroSATAssign: B=4, L=2048, NC=4096, D=128, ITERS=4, NH=8, T=1024.
// Round 4: (1) sparse adjacency (CSR built per launch; A is exactly {0,1},
// 3% dense -> gather-sum SpMM replaces 69 of 111 GFLOP, exact f32 math);
// (2) mega-fused LN-LSTM kernel (gate GEMMs + 2 LayerNorms + pointwise +
// cell-LN in one kernel, wave-per-row reductions, no gate buffers);
// (3) fused 3-layer MLP (activations in LDS). Lh ping-pongs in a 5x1M
// rotating region to avoid the flip(Lh) cross-block hazard.
// ws = 49.1 MB <= 50.33 MB proven. Dtype-adaptive (flag) kept from round 3.

#define B_    4
#define L_    2048
#define NC_   4096
#define D_    128
#define ITERS_ 4
#define NH_   8
#define T_    1024
#define C2_   256
#define HD_   32
#define BL_   (B_*L_)    // 8192
#define BNC_  (B_*NC_)   // 16384
#define VCAP_ 1040000    // nnz capacity per CSR (expected 1.0066M, +33 sigma)

typedef unsigned short u16;

static __device__ __forceinline__ float bf2f(u16 u){
  union{unsigned int i; float f;} x; x.i = ((unsigned int)u) << 16; return x.f;
}
static __device__ __forceinline__ u16 f2bf(float f){
  union{float f; unsigned int i;} x; x.f = f;
  unsigned int r = x.i + 0x7fffu + ((x.i >> 16) & 1u);
  return (u16)(r >> 16);
}
static __device__ __forceinline__ float sigm(float x){ return 1.f/(1.f+expf(-x)); }

// ---- dtype detect: adjacency is exactly {0.0f,1.0f} iff stored as f32 ----
__global__ __launch_bounds__(256) void k_detect(const unsigned int* __restrict__ a,
                                                int* __restrict__ flag){
  int bad = 0;
  for (int i = threadIdx.x; i < 32768; i += 256){
    unsigned int w = a[i];
    if (w != 0u && w != 0x3F800000u) bad = 1;
  }
  __shared__ int s[256];
  s[threadIdx.x] = bad; __syncthreads();
  for (int o = 128; o > 0; o >>= 1){
    if (threadIdx.x < o) s[threadIdx.x] |= s[threadIdx.x + o];
    __syncthreads();
  }
  if (threadIdx.x == 0) *flag = s[0];   // 1 = bf16 inputs, 0 = f32 inputs
}

// ---- batch weight conversion into f32 pool ----
#define NJOBS_ 44
struct Jobs { const void* src[NJOBS_]; unsigned n[NJOBS_]; unsigned off[NJOBS_]; };

__global__ __launch_bounds__(256) void k_cvt_all(Jobs jb, float* __restrict__ pool,
                                                 const int* __restrict__ flag){
  int j = blockIdx.y;
  unsigned n = jb.n[j];
  unsigned i = blockIdx.x*256 + threadIdx.x;
  if (i >= n) return;
  float v;
  if (*flag) v = bf2f(((const u16*)jb.src[j])[i]);
  else       v = ((const float*)jb.src[j])[i];
  pool[jb.off[j] + i] = v;
}

// ---------------- init: h[i] = init[i%D], c[i] = 0 ----------------
__global__ __launch_bounds__(256) void k_init(float* __restrict__ h, float* __restrict__ c,
                                              const float* __restrict__ init, int n){
  int i = blockIdx.x*256 + threadIdx.x;
  if (i < n){ h[i] = init[i & (D_-1)]; c[i] = 0.f; }
}

__global__ void k_zero_u(unsigned* __restrict__ p, int n){
  int i = blockIdx.x*256 + threadIdx.x; if (i < n) p[i] = 0u;
}
__global__ void k_zero(float* p, int n){
  int i = blockIdx.x*64 + threadIdx.x; if (i < n) p[i] = 0.f;
}

// ---------------- sparse build: count / scan / fill ----------------
__global__ __launch_bounds__(256) void k_count(const void* __restrict__ A,
    unsigned* __restrict__ cnt_c, unsigned* __restrict__ cnt_l,
    const int* __restrict__ flag){
  int i4 = blockIdx.x*256 + threadIdx.x;
  if (i4 >= (B_*L_*NC_)/4) return;
  int c  = (i4 & (NC_/4 - 1)) * 4;
  int bl = i4 >> 10;                 // b*L + l
  float v[4];
  if (*flag){ ushort4 u = ((const ushort4*)A)[i4];
    v[0]=bf2f(u.x); v[1]=bf2f(u.y); v[2]=bf2f(u.z); v[3]=bf2f(u.w); }
  else { float4 f = ((const float4*)A)[i4];
    v[0]=f.x; v[1]=f.y; v[2]=f.z; v[3]=f.w; }
  int nl = 0;
  unsigned rcb = ((unsigned)(bl >> 11) << 12) + c;   // b*NC + c
  #pragma unroll
  for (int j = 0; j < 4; j++)
    if (v[j] != 0.f){ atomicAdd(cnt_c + rcb + j, 1u); nl++; }
  if (nl) atomicAdd(cnt_l + bl, (unsigned)nl);
}

__global__ __launch_bounds__(256) void k_scan(unsigned* __restrict__ cnt,
    unsigned* __restrict__ off, int n){
  __shared__ unsigned ps[257];
  int t = threadIdx.x;
  int seg = n >> 8;
  int base = t*seg;
  unsigned s = 0;
  for (int i = 0; i < seg; i++) s += cnt[base+i];
  ps[t] = s;
  __syncthreads();
  if (t == 0){
    unsigned run = 0;
    for (int i = 0; i < 256; i++){ unsigned x = ps[i]; ps[i] = run; run += x; }
    ps[256] = run;
  }
  __syncthreads();
  unsigned run = ps[t];
  for (int i = 0; i < seg; i++){ off[base+i] = run; run += cnt[base+i]; cnt[base+i] = 0u; }
  if (t == 0) off[n] = ps[256];
}

__global__ __launch_bounds__(256) void k_fill(const void* __restrict__ A,
    const unsigned* __restrict__ off_c, const unsigned* __restrict__ off_l,
    unsigned* __restrict__ cur_c, unsigned* __restrict__ cur_l,
    u16* __restrict__ val_c, u16* __restrict__ val_l,
    const int* __restrict__ flag){
  int i4 = blockIdx.x*256 + threadIdx.x;
  if (i4 >= (B_*L_*NC_)/4) return;
  int c  = (i4 & (NC_/4 - 1)) * 4;
  int bl = i4 >> 10;
  int l  = bl & (L_-1);
  float v[4];
  if (*flag){ ushort4 u = ((const ushort4*)A)[i4];
    v[0]=bf2f(u.x); v[1]=bf2f(u.y); v[2]=bf2f(u.z); v[3]=bf2f(u.w); }
  else { float4 f = ((const float4*)A)[i4];
    v[0]=f.x; v[1]=f.y; v[2]=f.z; v[3]=f.w; }
  unsigned rcb = ((unsigned)(bl >> 11) << 12) + c;
  #pragma unroll
  for (int j = 0; j < 4; j++)
    if (v[j] != 0.f){
      unsigned rc = rcb + j;
      unsigned p = atomicAdd(cur_c + rc, 1u);
      val_c[off_c[rc] + p] = (u16)l;
      unsigned q = atomicAdd(cur_l + bl, 1u);
      val_l[off_l[bl] + q] = (u16)(c + j);
    }
}

// ---------------- SpMM: out[row,:] = sum over CSR row of M[mapped,:] ----------------
// sh1/sh2: row -> batch (row>>sh1), msg base row = batch<<sh2.
__global__ __launch_bounds__(256) void k_spmm(const unsigned* __restrict__ off,
    const u16* __restrict__ val, const float* __restrict__ M, float* __restrict__ out,
    int sh1, int sh2){
  int row  = blockIdx.x*4 + (threadIdx.x >> 6);
  int lane = threadIdx.x & 63;
  unsigned p0 = off[row], p1 = off[row+1];
  const float2* Mp = (const float2*)M + (((size_t)(row >> sh1) << sh2) * 64) + lane;
  float x = 0.f, y = 0.f;
  for (unsigned p = p0; p < p1; ++p){
    float2 v = Mp[(size_t)val[p] * 64];
    x += v.x; y += v.y;
  }
  float2 r; r.x = x; r.y = y;
  ((float2*)out)[(size_t)row*64 + lane] = r;
}

// ---------------- fused 3-layer MLP: Y = relu(relu(X@W1+b1)@W2+b2)@W3+b3 ----------------
// 64 rows/block, 256 threads (4 waves x 16 rows, lane covers cols {lane, lane+64}).
__global__ __launch_bounds__(256) void k_mlp3(const float* __restrict__ X,
    const float* __restrict__ W1, const float* __restrict__ b1,
    const float* __restrict__ W2, const float* __restrict__ b2,
    const float* __restrict__ W3, const float* __restrict__ b3,
    float* __restrict__ Y)
{
  __shared__ float Xs[64][129];
  __shared__ float Hs[64][129];
  __shared__ float Bs[16][132];
  const int tid = threadIdx.x;
  const int lane = tid & 63, wv = tid >> 6;
  const int r0 = blockIdx.x * 64;
  // stage X
  #pragma unroll
  for (int i = 0; i < 8; i++){
    int g = tid + i*256;
    int row = g >> 5, cg = (g & 31)*4;
    float4 v = *(const float4*)(X + (size_t)(r0+row)*128 + cg);
    Xs[row][cg] = v.x; Xs[row][cg+1] = v.y; Xs[row][cg+2] = v.z; Xs[row][cg+3] = v.w;
  }
  float (*src)[129] = Xs;
  float (*dst)[129] = Hs;
  const float* Ws[3] = {W1, W2, W3};
  const float* bs[3] = {b1, b2, b3};
  for (int layer = 0; layer < 3; layer++){
    const float* W = Ws[layer];
    float acc[16][2];
    #pragma unroll
    for (int i = 0; i < 16; i++){ acc[i][0] = 0.f; acc[i][1] = 0.f; }
    for (int k0 = 0; k0 < 128; k0 += 16){
      __syncthreads();
      #pragma unroll
      for (int i = 0; i < 2; i++){
        int g = tid + i*256;
        int kb = g >> 5, cb = (g & 31)*4;
        float4 v = *(const float4*)(W + (size_t)(k0+kb)*128 + cb);
        Bs[kb][cb] = v.x; Bs[kb][cb+1] = v.y; Bs[kb][cb+2] = v.z; Bs[kb][cb+3] = v.w;
      }
      __syncthreads();
      #pragma unroll
      for (int kk = 0; kk < 16; kk++){
        float b0 = Bs[kk][lane], bq = Bs[kk][lane+64];
        #pragma unroll
        for (int i = 0; i < 16; i++){
          float a = src[wv*16+i][k0+kk];
          acc[i][0] += a*b0; acc[i][1] += a*bq;
        }
      }
    }
    float bb0 = bs[layer][lane], bb1 = bs[layer][lane+64];
    __syncthreads();
    if (layer < 2){
      #pragma unroll
      for (int i = 0; i < 16; i++){
        dst[wv*16+i][lane]    = fmaxf(acc[i][0] + bb0, 0.f);
        dst[wv*16+i][lane+64] = fmaxf(acc[i][1] + bb1, 0.f);
      }
      float (*tmp)[129] = src; src = dst; dst = tmp;
    } else {
      #pragma unroll
      for (int i = 0; i < 16; i++){
        size_t r = (size_t)(r0 + wv*16 + i)*128;
        Y[r + lane]    = acc[i][0] + bb0;
        Y[r + lane+64] = acc[i][1] + bb1;
      }
    }
  }
}

// ---------------- mega-fused LN-LSTM ----------------
// gates1 = sum_{s<NSEG-1} A_s @ W_s  (LN w/ lni); gates2 = A_{NSEG-1} @ W_{NSEG-1} (LN w/ lnh)
// Each A_s is [R,128]; seg 1 may read rows XOR'd with flip1 (flip(Lh)).
// 32 rows/block, 256 threads (4 waves x 8 rows; lane covers 8 cols stride 64).
template<int NSEG>
__global__ __launch_bounds__(256) void k_lstm_fused(
    const float* __restrict__ A0, const float* __restrict__ A1, const float* __restrict__ A2,
    int flip1,
    const float* __restrict__ W0, const float* __restrict__ W1w, const float* __restrict__ W2w,
    const float* __restrict__ lni_g, const float* __restrict__ lni_b,
    const float* __restrict__ lnh_g, const float* __restrict__ lnh_b,
    const float* __restrict__ lnc_g, const float* __restrict__ lnc_b,
    const float* __restrict__ c_in, float* __restrict__ c_out,
    float* __restrict__ h_out)
{
  __shared__ float Bs[16][520];
  __shared__ float As[32][17];
  const int tid = threadIdx.x;
  const int lane = tid & 63, wv = tid >> 6;
  const int r0 = blockIdx.x * 32;
  const int ar = tid >> 3, ak = (tid & 7)*2;

  float acc1[8][8], acc2[8][8];
  #pragma unroll
  for (int i = 0; i < 8; i++)
    #pragma unroll
    for (int j = 0; j < 8; j++){ acc1[i][j] = 0.f; acc2[i][j] = 0.f; }

  #pragma unroll
  for (int s = 0; s < NSEG; ++s){
    const float* Ap = (s==0) ? A0 : ((s==1) ? A1 : A2);
    const float* Wp = (s==0) ? W0 : ((s==1) ? W1w : W2w);
    const int fm = (s==1) ? flip1 : 0;
    const int arow = (r0 + ar) ^ fm;
    for (int k0 = 0; k0 < 128; k0 += 16){
      __syncthreads();
      {
        float2 av = *(const float2*)(Ap + (size_t)arow*128 + k0 + ak);
        As[ar][ak] = av.x; As[ar][ak+1] = av.y;
        #pragma unroll
        for (int i = 0; i < 8; i++){
          int g = tid + i*256;
          int kb = g >> 7, cb = (g & 127)*4;
          float4 v = *(const float4*)(Wp + (size_t)(k0+kb)*512 + cb);
          Bs[kb][cb] = v.x; Bs[kb][cb+1] = v.y; Bs[kb][cb+2] = v.z; Bs[kb][cb+3] = v.w;
        }
      }
      __syncthreads();
      if (s == NSEG-1){
        #pragma unroll
        for (int kk = 0; kk < 16; kk++){
          float b[8], a[8];
          #pragma unroll
          for (int j = 0; j < 8; j++) b[j] = Bs[kk][lane + 64*j];
          #pragma unroll
          for (int i = 0; i < 8; i++) a[i] = As[wv*8+i][kk];
          #pragma unroll
          for (int i = 0; i < 8; i++)
            #pragma unroll
            for (int j = 0; j < 8; j++) acc2[i][j] += a[i]*b[j];
        }
      } else {
        #pragma unroll
        for (int kk = 0; kk < 16; kk++){
          float b[8], a[8];
          #pragma unroll
          for (int j = 0; j < 8; j++) b[j] = Bs[kk][lane + 64*j];
          #pragma unroll
          for (int i = 0; i < 8; i++) a[i] = As[wv*8+i][kk];
          #pragma unroll
          for (int i = 0; i < 8; i++)
            #pragma unroll
            for (int j = 0; j < 8; j++) acc1[i][j] += a[i]*b[j];
        }
      }
    }
  }

  // epilogue: per-row LN(512) x2, LSTM pointwise, LN(128) on cell
  float lig[8], lib[8], lhg[8], lhb[8];
  #pragma unroll
  for (int j = 0; j < 8; j++){
    int cl = lane + 64*j;
    lig[j] = lni_g[cl]; lib[j] = lni_b[cl];
    lhg[j] = lnh_g[cl]; lhb[j] = lnh_b[cl];
  }
  float lcg[2], lcb[2];
  #pragma unroll
  for (int jj = 0; jj < 2; jj++){ int cc = lane + 64*jj; lcg[jj] = lnc_g[cc]; lcb[jj] = lnc_b[cc]; }
  const float i512 = 1.f/512.f, i128 = 1.f/128.f;
  #pragma unroll
  for (int i = 0; i < 8; i++){
    int r = r0 + wv*8 + i;
    float s1=0.f, q1=0.f, s2=0.f, q2=0.f;
    #pragma unroll
    for (int j = 0; j < 8; j++){
      s1 += acc1[i][j]; q1 += acc1[i][j]*acc1[i][j];
      s2 += acc2[i][j]; q2 += acc2[i][j]*acc2[i][j];
    }
    #pragma unroll
    for (int m = 1; m < 64; m <<= 1){
      s1 += __shfl_xor(s1, m); q1 += __shfl_xor(q1, m);
      s2 += __shfl_xor(s2, m); q2 += __shfl_xor(q2, m);
    }
    float m1 = s1*i512, v1 = fmaxf(q1*i512 - m1*m1, 0.f), rs1 = rsqrtf(v1 + 1e-5f);
    float m2 = s2*i512, v2 = fmaxf(q2*i512 - m2*m2, 0.f), rs2 = rsqrtf(v2 + 1e-5f);
    float g[8];
    #pragma unroll
    for (int j = 0; j < 8; j++)
      g[j] = (acc1[i][j]-m1)*rs1*lig[j] + lib[j] + (acc2[i][j]-m2)*rs2*lhg[j] + lhb[j];
    float cpre[2], sc = 0.f, qc = 0.f;
    #pragma unroll
    for (int jj = 0; jj < 2; jj++){
      float iv = sigm(g[jj]), fv = sigm(g[jj+2]), gv = tanhf(g[jj+4]);
      float co = c_in[(size_t)r*128 + lane + 64*jj];
      cpre[jj] = fv*co + iv*gv;
      sc += cpre[jj]; qc += cpre[jj]*cpre[jj];
    }
    #pragma unroll
    for (int m = 1; m < 64; m <<= 1){ sc += __shfl_xor(sc, m); qc += __shfl_xor(qc, m); }
    float mc = sc*i128, vc = fmaxf(qc*i128 - mc*mc, 0.f), rsc = rsqrtf(vc + 1e-5f);
    #pragma unroll
    for (int jj = 0; jj < 2; jj++){
      float cy = (cpre[jj]-mc)*rsc*lcg[jj] + lcb[jj];
      c_out[(size_t)r*128 + lane + 64*jj] = cy;
      h_out[(size_t)r*128 + lane + 64*jj] = sigm(g[jj+6])*tanhf(cy);
    }
  }
}

// ------------- GEMM: C[M,N] = act(A_f32[M,K] @ W_f32[K,N] + bias) -------------
template<int ACT>
__global__ __launch_bounds__(256) void k_gemm_aw(const float* __restrict__ A,
    const float* __restrict__ W, const float* __restrict__ bias,
    float* __restrict__ C, int M, int N, int K)
{
  __shared__ float As[64][17];
  __shared__ float Ws[16][65];
  int tid = threadIdx.x;
  int bm = blockIdx.y*64, bn = blockIdx.x*64;
  int tx = tid & 15, ty = tid >> 4;
  int la_m = tid >> 2, la_k = (tid & 3)*4;
  int lw_k = tid >> 4, lw_n = (tid & 15)*4;
  float acc[4][4] = {};
  for (int k0 = 0; k0 < K; k0 += 16){
    float4 av = *(const float4*)(A + (size_t)(bm+la_m)*K + k0 + la_k);
    As[la_m][la_k+0]=av.x; As[la_m][la_k+1]=av.y; As[la_m][la_k+2]=av.z; As[la_m][la_k+3]=av.w;
    float4 wv = *(const float4*)(W + (size_t)(k0+lw_k)*N + bn + lw_n);
    Ws[lw_k][lw_n+0]=wv.x; Ws[lw_k][lw_n+1]=wv.y; Ws[lw_k][lw_n+2]=wv.z; Ws[lw_k][lw_n+3]=wv.w;
    __syncthreads();
    #pragma unroll
    for (int kk = 0; kk < 16; kk++){
      float a[4], b[4];
      #pragma unroll
      for (int i = 0; i < 4; i++) a[i] = As[ty*4+i][kk];
      #pragma unroll
      for (int j = 0; j < 4; j++) b[j] = Ws[kk][tx*4+j];
      #pragma unroll
      for (int i = 0; i < 4; i++)
        #pragma unroll
        for (int j = 0; j < 4; j++) acc[i][j] += a[i]*b[j];
    }
    __syncthreads();
  }
  #pragma unroll
  for (int i = 0; i < 4; i++){
    size_t m = bm + ty*4 + i;
    #pragma unroll
    for (int j = 0; j < 4; j++){
      int n = bn + tx*4 + j;
      float vv = acc[i][j];
      if (bias) vv += bias[n];
      if (ACT) vv = fmaxf(vv, 0.f);
      C[m*(size_t)N + n] = vv;
    }
  }
}

// --------- readout: read[b,t] = mask * [Lh[b,t] | Lh[b,t+T]] ---------
__global__ __launch_bounds__(256) void k_read(const float* __restrict__ Lh,
    const int* __restrict__ counts, float* __restrict__ rd)
{
  int i = blockIdx.x*256 + threadIdx.x;
  if (i >= B_*T_*D_) return;
  int d = i & (D_-1);
  int r = i >> 7;          // b*T + t
  int t = r & (T_-1);
  int b = r >> 10;
  int half = counts[b] / 2; if (half > T_) half = T_;
  float m = (t < half) ? 1.f : 0.f;
  rd[(size_t)r*C2_ + d]      = m * Lh[(size_t)(b*L_ + t)*D_ + d];
  rd[(size_t)r*C2_ + D_ + d] = m * Lh[(size_t)(b*L_ + t + T_)*D_ + d];
}

// --------- fused attention: one wave per (b, h, t) row ---------
__global__ __launch_bounds__(64) void k_attn(const float* __restrict__ q,
    const float* __restrict__ k, const float* __restrict__ v,
    const int* __restrict__ counts, float* __restrict__ y)
{
  int t = blockIdx.x, h = blockIdx.y, b = blockIdx.z, lane = threadIdx.x;
  int half = counts[b] / 2; if (half > T_) half = T_;
  float* yrow = y + ((size_t)(b*T_ + t)*C2_ + h*HD_);
  if (t >= half){ if (lane < HD_) yrow[lane] = 0.f; return; }
  __shared__ float sc[T_];
  __shared__ float qs[HD_];
  const float* qrow = q + ((size_t)(b*T_ + t)*C2_ + h*HD_);
  if (lane < HD_) qs[lane] = qrow[lane];
  __syncthreads();
  const float scale = 0.17677669529663687f;  // 1/sqrt(32)
  for (int s = lane; s < T_; s += 64){
    float d = -1e30f;
    if (s < half){
      const float* kr = k + ((size_t)(b*T_ + s)*C2_ + h*HD_);
      float acc = 0.f;
      #pragma unroll
      for (int j = 0; j < HD_; j++) acc += qs[j]*kr[j];
      d = acc*scale;
    }
    sc[s] = d;
  }
  float mx = -1e30f;
  for (int s = lane; s < T_; s += 64) mx = fmaxf(mx, sc[s]);
  #pragma unroll
  for (int off = 32; off > 0; off >>= 1) mx = fmaxf(mx, __shfl_down(mx, off));
  mx = __shfl(mx, 0);
  float sum = 0.f;
  for (int s = lane; s < T_; s += 64){
    float p = (sc[s] > -1e29f) ? expf(sc[s] - mx) : 0.f;
    sc[s] = p; sum += p;
  }
  #pragma unroll
  for (int off = 32; off > 0; off >>= 1) sum += __shfl_down(sum, off);
  sum = __shfl(sum, 0);
  __syncthreads();
  float inv = (sum > 0.f) ? 1.f/sum : 0.f;
  int d = lane & 31, part = lane >> 5;
  float acc = 0.f;
  for (int s = part; s < half; s += 2)
    acc += sc[s] * v[((size_t)(b*T_ + s)*C2_ + h*HD_) + d];
  acc += __shfl_down(acc, 32);
  if (lane < 32) yrow[d] = acc*inv;
}

// --------- final heads ---------
__global__ __launch_bounds__(128) void k_final(const float* __restrict__ ah,
    const float* __restrict__ vh,
    const float* __restrict__ aW2, const float* __restrict__ ab2,
    const float* __restrict__ vW2, const float* __restrict__ vb2,
    const int* __restrict__ counts, void* __restrict__ outv,
    float* __restrict__ vote_sum, const int* __restrict__ flag)
{
  int row = blockIdx.x, tid = threadIdx.x;
  int b = row / T_, t = row - b*T_;
  int half = counts[b] / 2; if (half > T_) half = T_;
  float pa = ah[(size_t)row*D_ + tid] * aW2[tid];
  float pv = vh[(size_t)row*D_ + tid] * vW2[tid];
  #pragma unroll
  for (int off = 32; off > 0; off >>= 1){ pa += __shfl_down(pa, off); pv += __shfl_down(pv, off); }
  __shared__ float r[2][2];
  int wid = tid >> 6, lane = tid & 63;
  if (lane == 0){ r[0][wid] = pa; r[1][wid] = pv; }
  __syncthreads();
  if (tid == 0){
    float a  = sigm(r[0][0] + r[0][1] + ab2[0]);
    float vv = sigm(r[1][0] + r[1][1] + vb2[0]);
    bool mk = (t < half);
    float av = mk ? a : 0.f;
    if (*flag) ((u16*)outv)[4 + row] = f2bf(av);
    else       ((float*)outv)[4 + row] = av;
    if (mk) atomicAdd(vote_sum + b, vv);
  }
}

__global__ void k_votes(const float* __restrict__ vote_sum, const int* __restrict__ counts,
                        void* __restrict__ outv, const int* __restrict__ flag){
  int b = threadIdx.x;
  if (b < B_){
    int half = counts[b] / 2; if (half > T_) half = T_;
    float den = (float)(half > 1 ? half : 1);
    float vv = vote_sum[b] / den;
    if (*flag) ((u16*)outv)[b] = f2bf(vv);
    else       ((float*)outv)[b] = vv;
  }
}

static void gemm_aw(const float* A, const float* W, const float* bias, float* C,
                    int M, int N, int K, int act, hipStream_t s){
  dim3 g(N/64, M/64);
  if (act) k_gemm_aw<1><<<g, 256, 0, s>>>(A, W, bias, C, M, N, K);
  else     k_gemm_aw<0><<<g, 256, 0, s>>>(A, W, bias, C, M, N, K);
}

extern "C" void kernel_launch(void* const* d_in, const int* in_sizes, int n_in,
                              void* d_out, int out_size, void* d_ws, size_t ws_size,
                              hipStream_t stream)
{
  const void* A_adj = d_in[0];
  const int* counts = (const int*)d_in[1];

  const size_t M1 = (size_t)1048576;
  // layout (words): R[5M] Lc[1M] Ch[2M] Cc[2M] wp[700416] off_c[16416] off_l[8224]
  //                 cnt_c[16384] cnt_l[8192] val_c[520000] val_l[520000] tail[32]
  const size_t NEED = (5*M1 + M1 + 2*M1 + 2*M1 + 700416 + 16416 + 8224
                       + 16384 + 8192 + 520000 + 520000 + 32) * sizeof(float);
  if (ws_size < NEED) return;  // out stays zero -> visible finite-absmax diagnostic

  float* ws = (float*)d_ws;
  float* R    = ws;              // 5 x 1M rotating region (Lh lives here)
  float* Lc   = R + 5*M1;
  float* Ch   = Lc + M1;
  float* Cc   = Ch + 2*M1;
  float* wp   = Cc + 2*M1;
  unsigned* off_c = (unsigned*)(wp + 700416);
  unsigned* off_l = off_c + 16416;
  unsigned* cnt_c = off_l + 8224;
  unsigned* cnt_l = cnt_c + 16384;
  u16* val_c = (u16*)(cnt_l + 8192);
  u16* val_l = (u16*)((float*)val_c + 520000);
  float* tail = (float*)val_l + 520000;
  float* vote_sum = tail;
  int* flag = (int*)(tail + 8);

  float* R0 = R, *R1 = R + M1, *R2 = R + 2*M1, *R3 = R + 3*M1, *R4 = R + 4*M1;

  // ---- detect dtype ----
  k_detect<<<1, 256, 0, stream>>>((const unsigned int*)A_adj, flag);

  // ---- weight conversion (one batched kernel) ----
  static const int wi[NJOBS_] = {2,3, 4,5,6,7,8,9, 10,11,12,13,14,15,
    16,17,18,19,20,21,22,23, 24,25,26,27,28,29,30,31,
    32,33,34,35,36,37, 38,39,40,41, 42,43,44,45};
  static const unsigned wn[NJOBS_] = {128,128, 16384,128,16384,128,16384,128,
    16384,128,16384,128,16384,128,
    131072,65536,512,512,512,512,128,128, 65536,65536,512,512,512,512,128,128,
    65536,256,65536,256,65536,256, 32768,128,128,1, 32768,128,128,1};
  Jobs jb;
  float* wptr[NJOBS_];
  {
    unsigned off = 0;
    for (int j = 0; j < NJOBS_; j++){
      jb.src[j] = d_in[wi[j]];
      jb.n[j] = wn[j];
      jb.off[j] = off;
      wptr[j] = wp + off;
      off += (wn[j] + 3u) & ~3u;
    }
  }
  { dim3 g(512, NJOBS_); k_cvt_all<<<g, 256, 0, stream>>>(jb, wp, flag); }

  float* Linit = wptr[0]; float* Cinit = wptr[1];
  float *LC_W1=wptr[2],*LC_b1=wptr[3],*LC_W2=wptr[4],*LC_b2=wptr[5],*LC_W3=wptr[6],*LC_b3=wptr[7];
  float *CL_W1=wptr[8],*CL_b1=wptr[9],*CL_W2=wptr[10],*CL_b2=wptr[11],*CL_W3=wptr[12],*CL_b3=wptr[13];
  float *Lu_Wih=wptr[14],*Lu_Whh=wptr[15];
  float *Lu_lni_g=wptr[16],*Lu_lni_b=wptr[17],*Lu_lnh_g=wptr[18],*Lu_lnh_b=wptr[19];
  float *Lu_lnc_g=wptr[20],*Lu_lnc_b=wptr[21];
  float *Cu_Wih=wptr[22],*Cu_Whh=wptr[23];
  float *Cu_lni_g=wptr[24],*Cu_lni_b=wptr[25],*Cu_lnh_g=wptr[26],*Cu_lnh_b=wptr[27];
  float *Cu_lnc_g=wptr[28],*Cu_lnc_b=wptr[29];
  float *att_Wk=wptr[30],*att_bk=wptr[31],*att_Wq=wptr[32],*att_bq=wptr[33];
  float *att_Wv=wptr[34],*att_bv=wptr[35];
  float *asn_W1=wptr[36],*asn_b1=wptr[37],*asn_W2=wptr[38],*asn_b2=wptr[39];
  float *vote_W1=wptr[40],*vote_b1=wptr[41],*vote_W2=wptr[42],*vote_b2=wptr[43];

  // ---- build CSR (both directions) ----
  k_zero_u<<<(16384+8192+255)/256, 256, 0, stream>>>(cnt_c, 16384+8192);
  k_count<<<(B_*L_*NC_/4)/256, 256, 0, stream>>>(A_adj, cnt_c, cnt_l, flag);
  k_scan<<<1, 256, 0, stream>>>(cnt_c, off_c, 16384);
  k_scan<<<1, 256, 0, stream>>>(cnt_l, off_l, 8192);
  k_fill<<<(B_*L_*NC_/4)/256, 256, 0, stream>>>(A_adj, off_c, off_l, cnt_c, cnt_l,
                                                val_c, val_l, flag);

  // ---- init states ----
  k_init<<<(BL_*D_)/256, 256, 0, stream>>>(R0, Lc, Linit, BL_*D_);
  k_init<<<(BNC_*D_)/256, 256, 0, stream>>>(Ch, Cc, Cinit, BNC_*D_);

  // ---- message passing ----
  for (int it = 0; it < ITERS_; ++it){
    bool ev = ((it & 1) == 0);
    float* cur  = ev ? R0 : R4;
    float* msgL = ev ? R1 : R0;
    float* LCb  = ev ? R2 : R1;   // 2M
    float* msgC = LCb;            // 2M (reuses LC region after clause LSTM)
    float* CLb  = ev ? R1 : R3;
    float* nxt  = ev ? R4 : R0;

    k_mlp3<<<BL_/64, 256, 0, stream>>>(cur, LC_W1, LC_b1, LC_W2, LC_b2, LC_W3, LC_b3, msgL);
    k_spmm<<<BNC_/4, 256, 0, stream>>>(off_c, val_c, msgL, LCb, 12, 11);
    k_lstm_fused<2><<<BNC_/32, 256, 0, stream>>>(LCb, Ch, nullptr, 0,
        Cu_Wih, Cu_Whh, nullptr,
        Cu_lni_g, Cu_lni_b, Cu_lnh_g, Cu_lnh_b, Cu_lnc_g, Cu_lnc_b, Cc, Cc, Ch);
    k_mlp3<<<BNC_/64, 256, 0, stream>>>(Ch, CL_W1, CL_b1, CL_W2, CL_b2, CL_W3, CL_b3, msgC);
    k_spmm<<<BL_/4, 256, 0, stream>>>(off_l, val_l, msgC, CLb, 11, 12);
    k_lstm_fused<3><<<BL_/32, 256, 0, stream>>>(CLb, cur, cur, 1024,
        Lu_Wih, Lu_Wih + 128*512, Lu_Whh,
        Lu_lni_g, Lu_lni_b, Lu_lnh_g, Lu_lnh_b, Lu_lnc_g, Lu_lnc_b, Lc, Lc, nxt);
  }
  float* Lh = R0;  // after 4 iters (ends odd), h lands back in R0

  // ---- readout + attention (reuse dead regions) ----
  float* readb = Ch;            // 1M
  float* qb    = Ch + M1;       // 1M
  float* kb    = Cc;            // 1M
  float* vb    = Cc + M1;       // 1M
  float* yb    = R1;            // 1M
  float* ah    = R2;            // 0.5M
  float* vh    = R2 + (size_t)(B_*T_)*D_;

  k_read<<<(B_*T_*D_)/256, 256, 0, stream>>>(Lh, counts, readb);
  gemm_aw(readb, att_Wq, att_bq, qb, B_*T_, C2_, C2_, 0, stream);
  gemm_aw(readb, att_Wk, att_bk, kb, B_*T_, C2_, C2_, 0, stream);
  gemm_aw(readb, att_Wv, att_bv, vb, B_*T_, C2_, C2_, 0, stream);
  { dim3 g(T_, NH_, B_); k_attn<<<g, 64, 0, stream>>>(qb, kb, vb, counts, yb); }
  gemm_aw(yb, asn_W1,  asn_b1,  ah, B_*T_, D_, C2_, 1, stream);
  gemm_aw(yb, vote_W1, vote_b1, vh, B_*T_, D_, C2_, 1, stream);
  k_zero<<<1, 64, 0, stream>>>(vote_sum, B_);
  k_final<<<B_*T_, 128, 0, stream>>>(ah, vh, asn_W2, asn_b2, vote_W2, vote_b2,
                                     counts, d_out, vote_sum, flag);
  k_votes<<<1, 64, 0, stream>>>(vote_sum, counts, d_out, flag);
}

// Round 5
// 3328.547 us; speedup vs baseline: 2.0481x; 1.2101x over previous
//
#include <hip/hip_runtime.h>

// NeuroSATAssign: B=4, L=2048, NC=4096, D=128, ITERS=4, NH=8, T=1024.
// Round 5: replace latency-bound k_attn (863us, VALUBusy 24%, 64 cache
// lines per load instr) with tiled flash attention: 64 q-rows/block,
// K tiles XOR-swizzled in LDS (conflict-free b128), S/softmax/PV fully
// wave-private (no barriers inside tile), V read coalesced from global
// (L1) to offload the shared per-CU DS pipe. Exact f32 math.
// Everything else unchanged from round 4 (sparse CSR + fused LSTM/MLP).

#define B_    4
#define L_    2048
#define NC_   4096
#define D_    128
#define ITERS_ 4
#define NH_   8
#define T_    1024
#define C2_   256
#define HD_   32
#define BL_   (B_*L_)    // 8192
#define BNC_  (B_*NC_)   // 16384

typedef unsigned short u16;

static __device__ __forceinline__ float bf2f(u16 u){
  union{unsigned int i; float f;} x; x.i = ((unsigned int)u) << 16; return x.f;
}
static __device__ __forceinline__ u16 f2bf(float f){
  union{float f; unsigned int i;} x; x.f = f;
  unsigned int r = x.i + 0x7fffu + ((x.i >> 16) & 1u);
  return (u16)(r >> 16);
}
static __device__ __forceinline__ float sigm(float x){ return 1.f/(1.f+expf(-x)); }

// ---- dtype detect: adjacency is exactly {0.0f,1.0f} iff stored as f32 ----
__global__ __launch_bounds__(256) void k_detect(const unsigned int* __restrict__ a,
                                                int* __restrict__ flag){
  int bad = 0;
  for (int i = threadIdx.x; i < 32768; i += 256){
    unsigned int w = a[i];
    if (w != 0u && w != 0x3F800000u) bad = 1;
  }
  __shared__ int s[256];
  s[threadIdx.x] = bad; __syncthreads();
  for (int o = 128; o > 0; o >>= 1){
    if (threadIdx.x < o) s[threadIdx.x] |= s[threadIdx.x + o];
    __syncthreads();
  }
  if (threadIdx.x == 0) *flag = s[0];   // 1 = bf16 inputs, 0 = f32 inputs
}

// ---- batch weight conversion into f32 pool ----
#define NJOBS_ 44
struct Jobs { const void* src[NJOBS_]; unsigned n[NJOBS_]; unsigned off[NJOBS_]; };

__global__ __launch_bounds__(256) void k_cvt_all(Jobs jb, float* __restrict__ pool,
                                                 const int* __restrict__ flag){
  int j = blockIdx.y;
  unsigned n = jb.n[j];
  unsigned i = blockIdx.x*256 + threadIdx.x;
  if (i >= n) return;
  float v;
  if (*flag) v = bf2f(((const u16*)jb.src[j])[i]);
  else       v = ((const float*)jb.src[j])[i];
  pool[jb.off[j] + i] = v;
}

// ---------------- init: h[i] = init[i%D], c[i] = 0 ----------------
__global__ __launch_bounds__(256) void k_init(float* __restrict__ h, float* __restrict__ c,
                                              const float* __restrict__ init, int n){
  int i = blockIdx.x*256 + threadIdx.x;
  if (i < n){ h[i] = init[i & (D_-1)]; c[i] = 0.f; }
}

__global__ void k_zero_u(unsigned* __restrict__ p, int n){
  int i = blockIdx.x*256 + threadIdx.x; if (i < n) p[i] = 0u;
}
__global__ void k_zero(float* p, int n){
  int i = blockIdx.x*64 + threadIdx.x; if (i < n) p[i] = 0.f;
}

// ---------------- sparse build: count / scan / fill ----------------
__global__ __launch_bounds__(256) void k_count(const void* __restrict__ A,
    unsigned* __restrict__ cnt_c, unsigned* __restrict__ cnt_l,
    const int* __restrict__ flag){
  int i4 = blockIdx.x*256 + threadIdx.x;
  if (i4 >= (B_*L_*NC_)/4) return;
  int c  = (i4 & (NC_/4 - 1)) * 4;
  int bl = i4 >> 10;                 // b*L + l
  float v[4];
  if (*flag){ ushort4 u = ((const ushort4*)A)[i4];
    v[0]=bf2f(u.x); v[1]=bf2f(u.y); v[2]=bf2f(u.z); v[3]=bf2f(u.w); }
  else { float4 f = ((const float4*)A)[i4];
    v[0]=f.x; v[1]=f.y; v[2]=f.z; v[3]=f.w; }
  int nl = 0;
  unsigned rcb = ((unsigned)(bl >> 11) << 12) + c;   // b*NC + c
  #pragma unroll
  for (int j = 0; j < 4; j++)
    if (v[j] != 0.f){ atomicAdd(cnt_c + rcb + j, 1u); nl++; }
  if (nl) atomicAdd(cnt_l + bl, (unsigned)nl);
}

__global__ __launch_bounds__(256) void k_scan(unsigned* __restrict__ cnt,
    unsigned* __restrict__ off, int n){
  __shared__ unsigned ps[257];
  int t = threadIdx.x;
  int seg = n >> 8;
  int base = t*seg;
  unsigned s = 0;
  for (int i = 0; i < seg; i++) s += cnt[base+i];
  ps[t] = s;
  __syncthreads();
  if (t == 0){
    unsigned run = 0;
    for (int i = 0; i < 256; i++){ unsigned x = ps[i]; ps[i] = run; run += x; }
    ps[256] = run;
  }
  __syncthreads();
  unsigned run = ps[t];
  for (int i = 0; i < seg; i++){ off[base+i] = run; run += cnt[base+i]; cnt[base+i] = 0u; }
  if (t == 0) off[n] = ps[256];
}

__global__ __launch_bounds__(256) void k_fill(const void* __restrict__ A,
    const unsigned* __restrict__ off_c, const unsigned* __restrict__ off_l,
    unsigned* __restrict__ cur_c, unsigned* __restrict__ cur_l,
    u16* __restrict__ val_c, u16* __restrict__ val_l,
    const int* __restrict__ flag){
  int i4 = blockIdx.x*256 + threadIdx.x;
  if (i4 >= (B_*L_*NC_)/4) return;
  int c  = (i4 & (NC_/4 - 1)) * 4;
  int bl = i4 >> 10;
  int l  = bl & (L_-1);
  float v[4];
  if (*flag){ ushort4 u = ((const ushort4*)A)[i4];
    v[0]=bf2f(u.x); v[1]=bf2f(u.y); v[2]=bf2f(u.z); v[3]=bf2f(u.w); }
  else { float4 f = ((const float4*)A)[i4];
    v[0]=f.x; v[1]=f.y; v[2]=f.z; v[3]=f.w; }
  unsigned rcb = ((unsigned)(bl >> 11) << 12) + c;
  #pragma unroll
  for (int j = 0; j < 4; j++)
    if (v[j] != 0.f){
      unsigned rc = rcb + j;
      unsigned p = atomicAdd(cur_c + rc, 1u);
      val_c[off_c[rc] + p] = (u16)l;
      unsigned q = atomicAdd(cur_l + bl, 1u);
      val_l[off_l[bl] + q] = (u16)(c + j);
    }
}

// ---------------- SpMM: out[row,:] = sum over CSR row of M[mapped,:] ----------------
__global__ __launch_bounds__(256) void k_spmm(const unsigned* __restrict__ off,
    const u16* __restrict__ val, const float* __restrict__ M, float* __restrict__ out,
    int sh1, int sh2){
  int row  = blockIdx.x*4 + (threadIdx.x >> 6);
  int lane = threadIdx.x & 63;
  unsigned p0 = off[row], p1 = off[row+1];
  const float2* Mp = (const float2*)M + (((size_t)(row >> sh1) << sh2) * 64) + lane;
  float x = 0.f, y = 0.f;
  for (unsigned p = p0; p < p1; ++p){
    float2 v = Mp[(size_t)val[p] * 64];
    x += v.x; y += v.y;
  }
  float2 r; r.x = x; r.y = y;
  ((float2*)out)[(size_t)row*64 + lane] = r;
}

// ---------------- fused 3-layer MLP ----------------
__global__ __launch_bounds__(256) void k_mlp3(const float* __restrict__ X,
    const float* __restrict__ W1, const float* __restrict__ b1,
    const float* __restrict__ W2, const float* __restrict__ b2,
    const float* __restrict__ W3, const float* __restrict__ b3,
    float* __restrict__ Y)
{
  __shared__ float Xs[64][129];
  __shared__ float Hs[64][129];
  __shared__ float Bs[16][132];
  const int tid = threadIdx.x;
  const int lane = tid & 63, wv = tid >> 6;
  const int r0 = blockIdx.x * 64;
  #pragma unroll
  for (int i = 0; i < 8; i++){
    int g = tid + i*256;
    int row = g >> 5, cg = (g & 31)*4;
    float4 v = *(const float4*)(X + (size_t)(r0+row)*128 + cg);
    Xs[row][cg] = v.x; Xs[row][cg+1] = v.y; Xs[row][cg+2] = v.z; Xs[row][cg+3] = v.w;
  }
  float (*src)[129] = Xs;
  float (*dst)[129] = Hs;
  const float* Ws[3] = {W1, W2, W3};
  const float* bs[3] = {b1, b2, b3};
  for (int layer = 0; layer < 3; layer++){
    const float* W = Ws[layer];
    float acc[16][2];
    #pragma unroll
    for (int i = 0; i < 16; i++){ acc[i][0] = 0.f; acc[i][1] = 0.f; }
    for (int k0 = 0; k0 < 128; k0 += 16){
      __syncthreads();
      #pragma unroll
      for (int i = 0; i < 2; i++){
        int g = tid + i*256;
        int kb = g >> 5, cb = (g & 31)*4;
        float4 v = *(const float4*)(W + (size_t)(k0+kb)*128 + cb);
        Bs[kb][cb] = v.x; Bs[kb][cb+1] = v.y; Bs[kb][cb+2] = v.z; Bs[kb][cb+3] = v.w;
      }
      __syncthreads();
      #pragma unroll
      for (int kk = 0; kk < 16; kk++){
        float b0 = Bs[kk][lane], bq = Bs[kk][lane+64];
        #pragma unroll
        for (int i = 0; i < 16; i++){
          float a = src[wv*16+i][k0+kk];
          acc[i][0] += a*b0; acc[i][1] += a*bq;
        }
      }
    }
    float bb0 = bs[layer][lane], bb1 = bs[layer][lane+64];
    __syncthreads();
    if (layer < 2){
      #pragma unroll
      for (int i = 0; i < 16; i++){
        dst[wv*16+i][lane]    = fmaxf(acc[i][0] + bb0, 0.f);
        dst[wv*16+i][lane+64] = fmaxf(acc[i][1] + bb1, 0.f);
      }
      float (*tmp)[129] = src; src = dst; dst = tmp;
    } else {
      #pragma unroll
      for (int i = 0; i < 16; i++){
        size_t r = (size_t)(r0 + wv*16 + i)*128;
        Y[r + lane]    = acc[i][0] + bb0;
        Y[r + lane+64] = acc[i][1] + bb1;
      }
    }
  }
}

// ---------------- mega-fused LN-LSTM ----------------
template<int NSEG>
__global__ __launch_bounds__(256) void k_lstm_fused(
    const float* __restrict__ A0, const float* __restrict__ A1, const float* __restrict__ A2,
    int flip1,
    const float* __restrict__ W0, const float* __restrict__ W1w, const float* __restrict__ W2w,
    const float* __restrict__ lni_g, const float* __restrict__ lni_b,
    const float* __restrict__ lnh_g, const float* __restrict__ lnh_b,
    const float* __restrict__ lnc_g, const float* __restrict__ lnc_b,
    const float* __restrict__ c_in, float* __restrict__ c_out,
    float* __restrict__ h_out)
{
  __shared__ float Bs[16][520];
  __shared__ float As[32][17];
  const int tid = threadIdx.x;
  const int lane = tid & 63, wv = tid >> 6;
  const int r0 = blockIdx.x * 32;
  const int ar = tid >> 3, ak = (tid & 7)*2;

  float acc1[8][8], acc2[8][8];
  #pragma unroll
  for (int i = 0; i < 8; i++)
    #pragma unroll
    for (int j = 0; j < 8; j++){ acc1[i][j] = 0.f; acc2[i][j] = 0.f; }

  #pragma unroll
  for (int s = 0; s < NSEG; ++s){
    const float* Ap = (s==0) ? A0 : ((s==1) ? A1 : A2);
    const float* Wp = (s==0) ? W0 : ((s==1) ? W1w : W2w);
    const int fm = (s==1) ? flip1 : 0;
    const int arow = (r0 + ar) ^ fm;
    for (int k0 = 0; k0 < 128; k0 += 16){
      __syncthreads();
      {
        float2 av = *(const float2*)(Ap + (size_t)arow*128 + k0 + ak);
        As[ar][ak] = av.x; As[ar][ak+1] = av.y;
        #pragma unroll
        for (int i = 0; i < 8; i++){
          int g = tid + i*256;
          int kb = g >> 7, cb = (g & 127)*4;
          float4 v = *(const float4*)(Wp + (size_t)(k0+kb)*512 + cb);
          Bs[kb][cb] = v.x; Bs[kb][cb+1] = v.y; Bs[kb][cb+2] = v.z; Bs[kb][cb+3] = v.w;
        }
      }
      __syncthreads();
      if (s == NSEG-1){
        #pragma unroll
        for (int kk = 0; kk < 16; kk++){
          float b[8], a[8];
          #pragma unroll
          for (int j = 0; j < 8; j++) b[j] = Bs[kk][lane + 64*j];
          #pragma unroll
          for (int i = 0; i < 8; i++) a[i] = As[wv*8+i][kk];
          #pragma unroll
          for (int i = 0; i < 8; i++)
            #pragma unroll
            for (int j = 0; j < 8; j++) acc2[i][j] += a[i]*b[j];
        }
      } else {
        #pragma unroll
        for (int kk = 0; kk < 16; kk++){
          float b[8], a[8];
          #pragma unroll
          for (int j = 0; j < 8; j++) b[j] = Bs[kk][lane + 64*j];
          #pragma unroll
          for (int i = 0; i < 8; i++) a[i] = As[wv*8+i][kk];
          #pragma unroll
          for (int i = 0; i < 8; i++)
            #pragma unroll
            for (int j = 0; j < 8; j++) acc1[i][j] += a[i]*b[j];
        }
      }
    }
  }

  float lig[8], lib[8], lhg[8], lhb[8];
  #pragma unroll
  for (int j = 0; j < 8; j++){
    int cl = lane + 64*j;
    lig[j] = lni_g[cl]; lib[j] = lni_b[cl];
    lhg[j] = lnh_g[cl]; lhb[j] = lnh_b[cl];
  }
  float lcg[2], lcb[2];
  #pragma unroll
  for (int jj = 0; jj < 2; jj++){ int cc = lane + 64*jj; lcg[jj] = lnc_g[cc]; lcb[jj] = lnc_b[cc]; }
  const float i512 = 1.f/512.f, i128 = 1.f/128.f;
  #pragma unroll
  for (int i = 0; i < 8; i++){
    int r = r0 + wv*8 + i;
    float s1=0.f, q1=0.f, s2=0.f, q2=0.f;
    #pragma unroll
    for (int j = 0; j < 8; j++){
      s1 += acc1[i][j]; q1 += acc1[i][j]*acc1[i][j];
      s2 += acc2[i][j]; q2 += acc2[i][j]*acc2[i][j];
    }
    #pragma unroll
    for (int m = 1; m < 64; m <<= 1){
      s1 += __shfl_xor(s1, m); q1 += __shfl_xor(q1, m);
      s2 += __shfl_xor(s2, m); q2 += __shfl_xor(q2, m);
    }
    float m1 = s1*i512, v1 = fmaxf(q1*i512 - m1*m1, 0.f), rs1 = rsqrtf(v1 + 1e-5f);
    float m2 = s2*i512, v2 = fmaxf(q2*i512 - m2*m2, 0.f), rs2 = rsqrtf(v2 + 1e-5f);
    float g[8];
    #pragma unroll
    for (int j = 0; j < 8; j++)
      g[j] = (acc1[i][j]-m1)*rs1*lig[j] + lib[j] + (acc2[i][j]-m2)*rs2*lhg[j] + lhb[j];
    float cpre[2], sc = 0.f, qc = 0.f;
    #pragma unroll
    for (int jj = 0; jj < 2; jj++){
      float iv = sigm(g[jj]), fv = sigm(g[jj+2]), gv = tanhf(g[jj+4]);
      float co = c_in[(size_t)r*128 + lane + 64*jj];
      cpre[jj] = fv*co + iv*gv;
      sc += cpre[jj]; qc += cpre[jj]*cpre[jj];
    }
    #pragma unroll
    for (int m = 1; m < 64; m <<= 1){ sc += __shfl_xor(sc, m); qc += __shfl_xor(qc, m); }
    float mc = sc*i128, vc = fmaxf(qc*i128 - mc*mc, 0.f), rsc = rsqrtf(vc + 1e-5f);
    #pragma unroll
    for (int jj = 0; jj < 2; jj++){
      float cy = (cpre[jj]-mc)*rsc*lcg[jj] + lcb[jj];
      c_out[(size_t)r*128 + lane + 64*jj] = cy;
      h_out[(size_t)r*128 + lane + 64*jj] = sigm(g[jj+6])*tanhf(cy);
    }
  }
}

// ------------- GEMM: C[M,N] = act(A_f32[M,K] @ W_f32[K,N] + bias) -------------
template<int ACT>
__global__ __launch_bounds__(256) void k_gemm_aw(const float* __restrict__ A,
    const float* __restrict__ W, const float* __restrict__ bias,
    float* __restrict__ C, int M, int N, int K)
{
  __shared__ float As[64][17];
  __shared__ float Ws[16][65];
  int tid = threadIdx.x;
  int bm = blockIdx.y*64, bn = blockIdx.x*64;
  int tx = tid & 15, ty = tid >> 4;
  int la_m = tid >> 2, la_k = (tid & 3)*4;
  int lw_k = tid >> 4, lw_n = (tid & 15)*4;
  float acc[4][4] = {};
  for (int k0 = 0; k0 < K; k0 += 16){
    float4 av = *(const float4*)(A + (size_t)(bm+la_m)*K + k0 + la_k);
    As[la_m][la_k+0]=av.x; As[la_m][la_k+1]=av.y; As[la_m][la_k+2]=av.z; As[la_m][la_k+3]=av.w;
    float4 wv = *(const float4*)(W + (size_t)(k0+lw_k)*N + bn + lw_n);
    Ws[lw_k][lw_n+0]=wv.x; Ws[lw_k][lw_n+1]=wv.y; Ws[lw_k][lw_n+2]=wv.z; Ws[lw_k][lw_n+3]=wv.w;
    __syncthreads();
    #pragma unroll
    for (int kk = 0; kk < 16; kk++){
      float a[4], b[4];
      #pragma unroll
      for (int i = 0; i < 4; i++) a[i] = As[ty*4+i][kk];
      #pragma unroll
      for (int j = 0; j < 4; j++) b[j] = Ws[kk][tx*4+j];
      #pragma unroll
      for (int i = 0; i < 4; i++)
        #pragma unroll
        for (int j = 0; j < 4; j++) acc[i][j] += a[i]*b[j];
    }
    __syncthreads();
  }
  #pragma unroll
  for (int i = 0; i < 4; i++){
    size_t m = bm + ty*4 + i;
    #pragma unroll
    for (int j = 0; j < 4; j++){
      int n = bn + tx*4 + j;
      float vv = acc[i][j];
      if (bias) vv += bias[n];
      if (ACT) vv = fmaxf(vv, 0.f);
      C[m*(size_t)N + n] = vv;
    }
  }
}

// --------- readout: read[b,t] = mask * [Lh[b,t] | Lh[b,t+T]] ---------
__global__ __launch_bounds__(256) void k_read(const float* __restrict__ Lh,
    const int* __restrict__ counts, float* __restrict__ rd)
{
  int i = blockIdx.x*256 + threadIdx.x;
  if (i >= B_*T_*D_) return;
  int d = i & (D_-1);
  int r = i >> 7;          // b*T + t
  int t = r & (T_-1);
  int b = r >> 10;
  int half = counts[b] / 2; if (half > T_) half = T_;
  float m = (t < half) ? 1.f : 0.f;
  rd[(size_t)r*C2_ + d]      = m * Lh[(size_t)(b*L_ + t)*D_ + d];
  rd[(size_t)r*C2_ + D_ + d] = m * Lh[(size_t)(b*L_ + t + T_)*D_ + d];
}

// --------- tiled flash attention: 64 q-rows per block, one (b,h) ---------
// 256 thr = 4 waves; wave wv owns score rows 16wv..16wv+15 (S, softmax, PV
// all wave-private -> barriers only around K staging). K LDS tile is
// XOR-swizzled at float4 granularity for conflict-free b128 reads.
// V is read directly from global (coalesced 128B lines, L1-resident).
__global__ __launch_bounds__(256) void k_attn_tile(const float* __restrict__ q,
    const float* __restrict__ k, const float* __restrict__ v,
    const int* __restrict__ counts, float* __restrict__ y)
{
  const int b = blockIdx.z, h = blockIdx.y, t0 = blockIdx.x*64;
  int half = counts[b] / 2; if (half > T_) half = T_; if (half < 0) half = 0;
  const int tid = threadIdx.x;
  const int lane = tid & 63, wv = tid >> 6;
  const int lr = tid >> 2, lc = (tid & 3)*8;    // staging map

  if (t0 >= half){
    float* yp = y + ((size_t)(b*T_ + t0 + lr)*C2_ + h*HD_ + lc);
    #pragma unroll
    for (int j = 0; j < 8; j++) yp[j] = 0.f;
    return;
  }

  __shared__ float Qs[64][36];
  __shared__ float Ks[64][32];   // XOR-swizzled chunks
  __shared__ float Ss[64][68];

  // stage Q tile once
  {
    const float* qp = q + ((size_t)(b*T_ + t0 + lr)*C2_ + h*HD_ + lc);
    float4 a0 = *(const float4*)qp;
    float4 a1 = *(const float4*)(qp+4);
    *(float4*)&Qs[lr][lc]   = a0;
    *(float4*)&Qs[lr][lc+4] = a1;
  }

  const int ty = tid >> 4, tx = tid & 15;          // S-phase map
  const int sr = wv*16 + (lane & 15);              // softmax row
  const int spart = (lane >> 4) * 16;              // softmax col segment
  const int rp = lane >> 3, cq = lane & 7;         // PV map
  const int r0 = wv*16 + rp*2;                     // PV rows r0, r0+1

  float4 acc0 = {0.f,0.f,0.f,0.f}, acc1 = {0.f,0.f,0.f,0.f};
  float mst = -3e38f, lst = 0.f;
  const float scale = 0.17677669529663687f;        // 1/sqrt(32)
  const int nt = (half + 63) >> 6;

  for (int st = 0; st < nt; ++st){
    const int s0 = st*64;
    __syncthreads();
    // stage K tile (swizzled: chunk c stored at c ^ ((row>>2)&7))
    {
      const float* kp = k + ((size_t)(b*T_ + s0 + lr)*C2_ + h*HD_ + lc);
      float4 k0 = *(const float4*)kp;
      float4 k1 = *(const float4*)(kp+4);
      int key = (lr >> 2) & 7;
      int c0 = lc >> 2;
      *(float4*)&Ks[lr][4*((c0  ) ^ key)] = k0;
      *(float4*)&Ks[lr][4*((c0+1) ^ key)] = k1;
    }
    __syncthreads();

    // ---- S = Q K^T (4x4 per thread, all b128) ----
    float s4[4][4];
    #pragma unroll
    for (int i = 0; i < 4; i++)
      #pragma unroll
      for (int j = 0; j < 4; j++) s4[i][j] = 0.f;
    const int xk = tx & 7;
    #pragma unroll
    for (int kk4 = 0; kk4 < 8; kk4++){
      float4 a4[4], b4[4];
      #pragma unroll
      for (int i = 0; i < 4; i++) a4[i] = *(const float4*)&Qs[ty*4+i][kk4*4];
      const int pk = 4*(kk4 ^ xk);
      #pragma unroll
      for (int j = 0; j < 4; j++) b4[j] = *(const float4*)&Ks[tx*4+j][pk];
      #pragma unroll
      for (int i = 0; i < 4; i++)
        #pragma unroll
        for (int j = 0; j < 4; j++)
          s4[i][j] += a4[i].x*b4[j].x + a4[i].y*b4[j].y + a4[i].z*b4[j].z + a4[i].w*b4[j].w;
    }
    // store (scaled + col-masked)
    #pragma unroll
    for (int i = 0; i < 4; i++){
      float4 w4;
      w4.x = (s0 + tx*4 + 0 < half) ? s4[i][0]*scale : -1e30f;
      w4.y = (s0 + tx*4 + 1 < half) ? s4[i][1]*scale : -1e30f;
      w4.z = (s0 + tx*4 + 2 < half) ? s4[i][2]*scale : -1e30f;
      w4.w = (s0 + tx*4 + 3 < half) ? s4[i][3]*scale : -1e30f;
      *(float4*)&Ss[ty*4+i][tx*4] = w4;
    }

    // ---- online softmax (wave-private) ----
    float pvv[16];
    float vmax = -3e38f;
    #pragma unroll
    for (int c4 = 0; c4 < 4; c4++){
      float4 t4 = *(const float4*)&Ss[sr][spart + c4*4];
      pvv[c4*4+0] = t4.x; pvv[c4*4+1] = t4.y; pvv[c4*4+2] = t4.z; pvv[c4*4+3] = t4.w;
      vmax = fmaxf(vmax, fmaxf(fmaxf(t4.x, t4.y), fmaxf(t4.z, t4.w)));
    }
    vmax = fmaxf(vmax, __shfl_xor(vmax, 16));
    vmax = fmaxf(vmax, __shfl_xor(vmax, 32));
    float nm = fmaxf(mst, vmax);
    float alpha = expf(mst - nm);
    float psum = 0.f;
    #pragma unroll
    for (int c = 0; c < 16; c++){
      float p = expf(pvv[c] - nm);
      pvv[c] = p; psum += p;
    }
    psum += __shfl_xor(psum, 16);
    psum += __shfl_xor(psum, 32);
    lst = lst*alpha + psum;
    mst = nm;
    #pragma unroll
    for (int c4 = 0; c4 < 4; c4++){
      float4 w4; w4.x = pvv[c4*4+0]; w4.y = pvv[c4*4+1]; w4.z = pvv[c4*4+2]; w4.w = pvv[c4*4+3];
      *(float4*)&Ss[sr][spart + c4*4] = w4;
    }
    float al0 = __shfl(alpha, 2*rp);
    float al1 = __shfl(alpha, 2*rp + 1);
    acc0.x *= al0; acc0.y *= al0; acc0.z *= al0; acc0.w *= al0;
    acc1.x *= al1; acc1.y *= al1; acc1.z *= al1; acc1.w *= al1;

    // ---- PV: P from LDS (b128), V from global (coalesced, L1) ----
    const float* vbase = v + ((size_t)(b*T_ + s0)*C2_ + h*HD_ + cq*4);
    #pragma unroll 4
    for (int kk4 = 0; kk4 < 16; kk4++){
      float4 p0 = *(const float4*)&Ss[r0  ][kk4*4];
      float4 p1 = *(const float4*)&Ss[r0+1][kk4*4];
      float4 v0 = *(const float4*)(vbase + (size_t)(kk4*4+0)*C2_);
      float4 v1 = *(const float4*)(vbase + (size_t)(kk4*4+1)*C2_);
      float4 v2 = *(const float4*)(vbase + (size_t)(kk4*4+2)*C2_);
      float4 v3 = *(const float4*)(vbase + (size_t)(kk4*4+3)*C2_);
      acc0.x += p0.x*v0.x + p0.y*v1.x + p0.z*v2.x + p0.w*v3.x;
      acc0.y += p0.x*v0.y + p0.y*v1.y + p0.z*v2.y + p0.w*v3.y;
      acc0.z += p0.x*v0.z + p0.y*v1.z + p0.z*v2.z + p0.w*v3.z;
      acc0.w += p0.x*v0.w + p0.y*v1.w + p0.z*v2.w + p0.w*v3.w;
      acc1.x += p1.x*v0.x + p1.y*v1.x + p1.z*v2.x + p1.w*v3.x;
      acc1.y += p1.x*v0.y + p1.y*v1.y + p1.z*v2.y + p1.w*v3.y;
      acc1.z += p1.x*v0.z + p1.y*v1.z + p1.z*v2.z + p1.w*v3.z;
      acc1.w += p1.x*v0.w + p1.y*v1.w + p1.z*v2.w + p1.w*v3.w;
    }
  }

  // ---- finalize ----
  float l0 = __shfl(lst, 2*rp);
  float l1 = __shfl(lst, 2*rp + 1);
  float m0 = (t0 + r0     < half && l0 > 0.f) ? 1.f/l0 : 0.f;
  float m1 = (t0 + r0 + 1 < half && l1 > 0.f) ? 1.f/l1 : 0.f;
  float4 o0, o1;
  o0.x = acc0.x*m0; o0.y = acc0.y*m0; o0.z = acc0.z*m0; o0.w = acc0.w*m0;
  o1.x = acc1.x*m1; o1.y = acc1.y*m1; o1.z = acc1.z*m1; o1.w = acc1.w*m1;
  *(float4*)(y + ((size_t)(b*T_ + t0 + r0    )*C2_ + h*HD_ + cq*4)) = o0;
  *(float4*)(y + ((size_t)(b*T_ + t0 + r0 + 1)*C2_ + h*HD_ + cq*4)) = o1;
}

// --------- final heads ---------
__global__ __launch_bounds__(128) void k_final(const float* __restrict__ ah,
    const float* __restrict__ vh,
    const float* __restrict__ aW2, const float* __restrict__ ab2,
    const float* __restrict__ vW2, const float* __restrict__ vb2,
    const int* __restrict__ counts, void* __restrict__ outv,
    float* __restrict__ vote_sum, const int* __restrict__ flag)
{
  int row = blockIdx.x, tid = threadIdx.x;
  int b = row / T_, t = row - b*T_;
  int half = counts[b] / 2; if (half > T_) half = T_;
  float pa = ah[(size_t)row*D_ + tid] * aW2[tid];
  float pv = vh[(size_t)row*D_ + tid] * vW2[tid];
  #pragma unroll
  for (int off = 32; off > 0; off >>= 1){ pa += __shfl_down(pa, off); pv += __shfl_down(pv, off); }
  __shared__ float r[2][2];
  int wid = tid >> 6, lane = tid & 63;
  if (lane == 0){ r[0][wid] = pa; r[1][wid] = pv; }
  __syncthreads();
  if (tid == 0){
    float a  = sigm(r[0][0] + r[0][1] + ab2[0]);
    float vv = sigm(r[1][0] + r[1][1] + vb2[0]);
    bool mk = (t < half);
    float av = mk ? a : 0.f;
    if (*flag) ((u16*)outv)[4 + row] = f2bf(av);
    else       ((float*)outv)[4 + row] = av;
    if (mk) atomicAdd(vote_sum + b, vv);
  }
}

__global__ void k_votes(const float* __restrict__ vote_sum, const int* __restrict__ counts,
                        void* __restrict__ outv, const int* __restrict__ flag){
  int b = threadIdx.x;
  if (b < B_){
    int half = counts[b] / 2; if (half > T_) half = T_;
    float den = (float)(half > 1 ? half : 1);
    float vv = vote_sum[b] / den;
    if (*flag) ((u16*)outv)[b] = f2bf(vv);
    else       ((float*)outv)[b] = vv;
  }
}

static void gemm_aw(const float* A, const float* W, const float* bias, float* C,
                    int M, int N, int K, int act, hipStream_t s){
  dim3 g(N/64, M/64);
  if (act) k_gemm_aw<1><<<g, 256, 0, s>>>(A, W, bias, C, M, N, K);
  else     k_gemm_aw<0><<<g, 256, 0, s>>>(A, W, bias, C, M, N, K);
}

extern "C" void kernel_launch(void* const* d_in, const int* in_sizes, int n_in,
                              void* d_out, int out_size, void* d_ws, size_t ws_size,
                              hipStream_t stream)
{
  const void* A_adj = d_in[0];
  const int* counts = (const int*)d_in[1];

  const size_t M1 = (size_t)1048576;
  const size_t NEED = (5*M1 + M1 + 2*M1 + 2*M1 + 700416 + 16416 + 8224
                       + 16384 + 8192 + 520000 + 520000 + 32) * sizeof(float);
  if (ws_size < NEED) return;

  float* ws = (float*)d_ws;
  float* R    = ws;              // 5 x 1M rotating region (Lh lives here)
  float* Lc   = R + 5*M1;
  float* Ch   = Lc + M1;
  float* Cc   = Ch + 2*M1;
  float* wp   = Cc + 2*M1;
  unsigned* off_c = (unsigned*)(wp + 700416);
  unsigned* off_l = off_c + 16416;
  unsigned* cnt_c = off_l + 8224;
  unsigned* cnt_l = cnt_c + 16384;
  u16* val_c = (u16*)(cnt_l + 8192);
  u16* val_l = (u16*)((float*)val_c + 520000);
  float* tail = (float*)val_l + 520000;
  float* vote_sum = tail;
  int* flag = (int*)(tail + 8);

  float* R0 = R, *R1 = R + M1, *R2 = R + 2*M1, *R3 = R + 3*M1, *R4 = R + 4*M1;

  k_detect<<<1, 256, 0, stream>>>((const unsigned int*)A_adj, flag);

  static const int wi[NJOBS_] = {2,3, 4,5,6,7,8,9, 10,11,12,13,14,15,
    16,17,18,19,20,21,22,23, 24,25,26,27,28,29,30,31,
    32,33,34,35,36,37, 38,39,40,41, 42,43,44,45};
  static const unsigned wn[NJOBS_] = {128,128, 16384,128,16384,128,16384,128,
    16384,128,16384,128,16384,128,
    131072,65536,512,512,512,512,128,128, 65536,65536,512,512,512,512,128,128,
    65536,256,65536,256,65536,256, 32768,128,128,1, 32768,128,128,1};
  Jobs jb;
  float* wptr[NJOBS_];
  {
    unsigned off = 0;
    for (int j = 0; j < NJOBS_; j++){
      jb.src[j] = d_in[wi[j]];
      jb.n[j] = wn[j];
      jb.off[j] = off;
      wptr[j] = wp + off;
      off += (wn[j] + 3u) & ~3u;
    }
  }
  { dim3 g(512, NJOBS_); k_cvt_all<<<g, 256, 0, stream>>>(jb, wp, flag); }

  float* Linit = wptr[0]; float* Cinit = wptr[1];
  float *LC_W1=wptr[2],*LC_b1=wptr[3],*LC_W2=wptr[4],*LC_b2=wptr[5],*LC_W3=wptr[6],*LC_b3=wptr[7];
  float *CL_W1=wptr[8],*CL_b1=wptr[9],*CL_W2=wptr[10],*CL_b2=wptr[11],*CL_W3=wptr[12],*CL_b3=wptr[13];
  float *Lu_Wih=wptr[14],*Lu_Whh=wptr[15];
  float *Lu_lni_g=wptr[16],*Lu_lni_b=wptr[17],*Lu_lnh_g=wptr[18],*Lu_lnh_b=wptr[19];
  float *Lu_lnc_g=wptr[20],*Lu_lnc_b=wptr[21];
  float *Cu_Wih=wptr[22],*Cu_Whh=wptr[23];
  float *Cu_lni_g=wptr[24],*Cu_lni_b=wptr[25],*Cu_lnh_g=wptr[26],*Cu_lnh_b=wptr[27];
  float *Cu_lnc_g=wptr[28],*Cu_lnc_b=wptr[29];
  float *att_Wk=wptr[30],*att_bk=wptr[31],*att_Wq=wptr[32],*att_bq=wptr[33];
  float *att_Wv=wptr[34],*att_bv=wptr[35];
  float *asn_W1=wptr[36],*asn_b1=wptr[37],*asn_W2=wptr[38],*asn_b2=wptr[39];
  float *vote_W1=wptr[40],*vote_b1=wptr[41],*vote_W2=wptr[42],*vote_b2=wptr[43];

  k_zero_u<<<(16384+8192+255)/256, 256, 0, stream>>>(cnt_c, 16384+8192);
  k_count<<<(B_*L_*NC_/4)/256, 256, 0, stream>>>(A_adj, cnt_c, cnt_l, flag);
  k_scan<<<1, 256, 0, stream>>>(cnt_c, off_c, 16384);
  k_scan<<<1, 256, 0, stream>>>(cnt_l, off_l, 8192);
  k_fill<<<(B_*L_*NC_/4)/256, 256, 0, stream>>>(A_adj, off_c, off_l, cnt_c, cnt_l,
                                                val_c, val_l, flag);

  k_init<<<(BL_*D_)/256, 256, 0, stream>>>(R0, Lc, Linit, BL_*D_);
  k_init<<<(BNC_*D_)/256, 256, 0, stream>>>(Ch, Cc, Cinit, BNC_*D_);

  for (int it = 0; it < ITERS_; ++it){
    bool ev = ((it & 1) == 0);
    float* cur  = ev ? R0 : R4;
    float* msgL = ev ? R1 : R0;
    float* LCb  = ev ? R2 : R1;
    float* msgC = LCb;
    float* CLb  = ev ? R1 : R3;
    float* nxt  = ev ? R4 : R0;

    k_mlp3<<<BL_/64, 256, 0, stream>>>(cur, LC_W1, LC_b1, LC_W2, LC_b2, LC_W3, LC_b3, msgL);
    k_spmm<<<BNC_/4, 256, 0, stream>>>(off_c, val_c, msgL, LCb, 12, 11);
    k_lstm_fused<2><<<BNC_/32, 256, 0, stream>>>(LCb, Ch, nullptr, 0,
        Cu_Wih, Cu_Whh, nullptr,
        Cu_lni_g, Cu_lni_b, Cu_lnh_g, Cu_lnh_b, Cu_lnc_g, Cu_lnc_b, Cc, Cc, Ch);
    k_mlp3<<<BNC_/64, 256, 0, stream>>>(Ch, CL_W1, CL_b1, CL_W2, CL_b2, CL_W3, CL_b3, msgC);
    k_spmm<<<BL_/4, 256, 0, stream>>>(off_l, val_l, msgC, CLb, 11, 12);
    k_lstm_fused<3><<<BL_/32, 256, 0, stream>>>(CLb, cur, cur, 1024,
        Lu_Wih, Lu_Wih + 128*512, Lu_Whh,
        Lu_lni_g, Lu_lni_b, Lu_lnh_g, Lu_lnh_b, Lu_lnc_g, Lu_lnc_b, Lc, Lc, nxt);
  }
  float* Lh = R0;

  float* readb = Ch;            // 1M
  float* qb    = Ch + M1;       // 1M
  float* kb    = Cc;            // 1M
  float* vb    = Cc + M1;       // 1M
  float* yb    = R1;            // 1M
  float* ah    = R2;            // 0.5M
  float* vh    = R2 + (size_t)(B_*T_)*D_;

  k_read<<<(B_*T_*D_)/256, 256, 0, stream>>>(Lh, counts, readb);
  gemm_aw(readb, att_Wq, att_bq, qb, B_*T_, C2_, C2_, 0, stream);
  gemm_aw(readb, att_Wk, att_bk, kb, B_*T_, C2_, C2_, 0, stream);
  gemm_aw(readb, att_Wv, att_bv, vb, B_*T_, C2_, C2_, 0, stream);
  { dim3 g(T_/64, NH_, B_); k_attn_tile<<<g, 256, 0, stream>>>(qb, kb, vb, counts, yb); }
  gemm_aw(yb, asn_W1,  asn_b1,  ah, B_*T_, D_, C2_, 1, stream);
  gemm_aw(yb, vote_W1, vote_b1, vh, B_*T_, D_, C2_, 1, stream);
  k_zero<<<1, 64, 0, stream>>>(vote_sum, B_);
  k_final<<<B_*T_, 128, 0, stream>>>(ah, vh, asn_W2, asn_b2, vote_W2, vote_b2,
                                     counts, d_out, vote_sum, flag);
  k_votes<<<1, 64, 0, stream>>>(vote_sum, counts, d_out, flag);
}

// Round 6
// 2896.639 us; speedup vs baseline: 2.3535x; 1.1491x over previous
//
#include <hip/hip_runtime.h>

// NeuroSATAssign: B=4, L=2048, NC=4096, D=128, ITERS=4, NH=8, T=1024.
// Round 6: CSR build rework — old k_count/k_fill had 64-lane same-address
// atomicAdd (serialized; k_count showed a 31ms stall replay) and read the
// 128MB dense matrix twice. New: k_pack (1 dense read -> 4MB bitmask +
// popcount row counts, no atomics) + k_fill_l (LDS scan, sorted val_l,
// distinct-address cnt_c histogram) + k_fill_c (bitmask only). Bitmask
// aliases the dead R region. Also: QKV fused into one [4096,768,256] GEMM
// and asn/vote head MLPs into one [4096,256,256] GEMM via strided
// weight-placement in the cvt kernel. Flash attention reads qkv stride 768.

#define B_    4
#define L_    2048
#define NC_   4096
#define D_    128
#define ITERS_ 4
#define NH_   8
#define T_    1024
#define C2_   256
#define HD_   32
#define BL_   (B_*L_)    // 8192
#define BNC_  (B_*NC_)   // 16384
#define QS_   768        // fused qkv row stride

typedef unsigned short u16;

static __device__ __forceinline__ float bf2f(u16 u){
  union{unsigned int i; float f;} x; x.i = ((unsigned int)u) << 16; return x.f;
}
static __device__ __forceinline__ u16 f2bf(float f){
  union{float f; unsigned int i;} x; x.f = f;
  unsigned int r = x.i + 0x7fffu + ((x.i >> 16) & 1u);
  return (u16)(r >> 16);
}
static __device__ __forceinline__ float sigm(float x){ return 1.f/(1.f+expf(-x)); }

// ---- dtype detect: adjacency is exactly {0.0f,1.0f} iff stored as f32 ----
__global__ __launch_bounds__(256) void k_detect(const unsigned int* __restrict__ a,
                                                int* __restrict__ flag){
  int bad = 0;
  for (int i = threadIdx.x; i < 32768; i += 256){
    unsigned int w = a[i];
    if (w != 0u && w != 0x3F800000u) bad = 1;
  }
  __shared__ int s[256];
  s[threadIdx.x] = bad; __syncthreads();
  for (int o = 128; o > 0; o >>= 1){
    if (threadIdx.x < o) s[threadIdx.x] |= s[threadIdx.x + o];
    __syncthreads();
  }
  if (threadIdx.x == 0) *flag = s[0];   // 1 = bf16 inputs, 0 = f32 inputs
}

// ---- batch weight conversion into f32 pool (strided placement capable) ----
#define NJOBS_ 44
struct Jobs {
  const void* src[NJOBS_];
  unsigned n[NJOBS_], off[NJOBS_], sh[NJOBS_], stride[NJOBS_];
};

__global__ __launch_bounds__(256) void k_cvt_all(Jobs jb, float* __restrict__ pool,
                                                 const int* __restrict__ flag){
  int j = blockIdx.y;
  unsigned n = jb.n[j];
  unsigned i = blockIdx.x*256 + threadIdx.x;
  if (i >= n) return;
  float v;
  if (*flag) v = bf2f(((const u16*)jb.src[j])[i]);
  else       v = ((const float*)jb.src[j])[i];
  unsigned sh = jb.sh[j];
  unsigned dst = jb.off[j] + (i >> sh)*jb.stride[j] + (i & ((1u << sh) - 1u));
  pool[dst] = v;
}

// ---------------- init: h[i] = init[i%D], c[i] = 0 ----------------
__global__ __launch_bounds__(256) void k_init(float* __restrict__ h, float* __restrict__ c,
                                              const float* __restrict__ init, int n){
  int i = blockIdx.x*256 + threadIdx.x;
  if (i < n){ h[i] = init[i & (D_-1)]; c[i] = 0.f; }
}

__global__ void k_zero_u(unsigned* __restrict__ p, int n){
  int i = blockIdx.x*256 + threadIdx.x; if (i < n) p[i] = 0u;
}
__global__ void k_zero(float* p, int n){
  int i = blockIdx.x*64 + threadIdx.x; if (i < n) p[i] = 0.f;
}

// ---------------- CSR build: pack / scan / fill ----------------
// k_pack: dense row -> 128 u32 bitmask words + row popcount (no atomics).
__global__ __launch_bounds__(128) void k_pack(const void* __restrict__ A,
    unsigned* __restrict__ bits, unsigned* __restrict__ cnt_l,
    const int* __restrict__ flag){
  const int row = blockIdx.x, w = threadIdx.x;
  unsigned m = 0;
  if (*flag){
    const ushort4* p = (const ushort4*)A + (size_t)row*(NC_/4) + w*8;
    #pragma unroll
    for (int i = 0; i < 8; i++){
      ushort4 u = p[i];
      m |= (unsigned)(u.x != 0) << (i*4);
      m |= (unsigned)(u.y != 0) << (i*4+1);
      m |= (unsigned)(u.z != 0) << (i*4+2);
      m |= (unsigned)(u.w != 0) << (i*4+3);
    }
  } else {
    const float4* p = (const float4*)A + (size_t)row*(NC_/4) + w*8;
    #pragma unroll
    for (int i = 0; i < 8; i++){
      float4 v = p[i];
      m |= (unsigned)(v.x != 0.f) << (i*4);
      m |= (unsigned)(v.y != 0.f) << (i*4+1);
      m |= (unsigned)(v.z != 0.f) << (i*4+2);
      m |= (unsigned)(v.w != 0.f) << (i*4+3);
    }
  }
  bits[(size_t)row*128 + w] = m;
  unsigned pc = __popc(m);
  #pragma unroll
  for (int o = 1; o < 64; o <<= 1) pc += __shfl_xor(pc, o);
  __shared__ unsigned ss[2];
  if ((w & 63) == 0) ss[w >> 6] = pc;
  __syncthreads();
  if (w == 0) cnt_l[row] = ss[0] + ss[1];
}

__global__ __launch_bounds__(256) void k_scan(unsigned* __restrict__ cnt,
    unsigned* __restrict__ off, int n){
  __shared__ unsigned ps[257];
  int t = threadIdx.x;
  int seg = n >> 8;
  int base = t*seg;
  unsigned s = 0;
  for (int i = 0; i < seg; i++) s += cnt[base+i];
  ps[t] = s;
  __syncthreads();
  if (t == 0){
    unsigned run = 0;
    for (int i = 0; i < 256; i++){ unsigned x = ps[i]; ps[i] = run; run += x; }
    ps[256] = run;
  }
  __syncthreads();
  unsigned run = ps[t];
  for (int i = 0; i < seg; i++){ off[base+i] = run; run += cnt[base+i]; cnt[base+i] = 0u; }
  if (t == 0) off[n] = ps[256];
}

// k_fill_l: per-row LDS scan -> sorted val_l; histogram cnt_c (distinct addrs).
__global__ __launch_bounds__(128) void k_fill_l(const unsigned* __restrict__ bits,
    const unsigned* __restrict__ off_l, u16* __restrict__ val_l,
    unsigned* __restrict__ cnt_c){
  const int row = blockIdx.x, w = threadIdx.x;
  const int b = row >> 11;
  unsigned m = bits[(size_t)row*128 + w];
  unsigned pc = __popc(m);
  __shared__ unsigned s[128];
  s[w] = pc; __syncthreads();
  #pragma unroll
  for (int o = 1; o < 128; o <<= 1){
    unsigned v = (w >= o) ? s[w-o] : 0u;
    __syncthreads();
    s[w] += v;
    __syncthreads();
  }
  unsigned base = off_l[row] + s[w] - pc;
  unsigned cb = ((unsigned)b << 12) + w*32;
  while (m){
    int j = __ffs(m) - 1; m &= m - 1;
    val_l[base++] = (u16)(w*32 + j);
    atomicAdd(cnt_c + cb + j, 1u);
  }
}

// k_fill_c: bitmask -> clause-direction entries via cursor atomics.
__global__ __launch_bounds__(256) void k_fill_c(const unsigned* __restrict__ bits,
    const unsigned* __restrict__ off_c, unsigned* __restrict__ cur_c,
    u16* __restrict__ val_c){
  int g = blockIdx.x*256 + threadIdx.x;     // word index, 0..1M
  unsigned m = bits[g];
  int row = g >> 7, w = g & 127;
  int b = row >> 11, l = row & (L_-1);
  unsigned cb = ((unsigned)b << 12) + w*32;
  while (m){
    int j = __ffs(m) - 1; m &= m - 1;
    unsigned idx = cb + j;
    unsigned pos = atomicAdd(cur_c + idx, 1u);
    val_c[off_c[idx] + pos] = (u16)l;
  }
}

// ---------------- SpMM: out[row,:] = sum over CSR row of M[mapped,:] ----------------
__global__ __launch_bounds__(256) void k_spmm(const unsigned* __restrict__ off,
    const u16* __restrict__ val, const float* __restrict__ M, float* __restrict__ out,
    int sh1, int sh2){
  int row  = blockIdx.x*4 + (threadIdx.x >> 6);
  int lane = threadIdx.x & 63;
  unsigned p0 = off[row], p1 = off[row+1];
  const float2* Mp = (const float2*)M + (((size_t)(row >> sh1) << sh2) * 64) + lane;
  float x = 0.f, y = 0.f;
  for (unsigned p = p0; p < p1; ++p){
    float2 v = Mp[(size_t)val[p] * 64];
    x += v.x; y += v.y;
  }
  float2 r; r.x = x; r.y = y;
  ((float2*)out)[(size_t)row*64 + lane] = r;
}

// ---------------- fused 3-layer MLP ----------------
__global__ __launch_bounds__(256) void k_mlp3(const float* __restrict__ X,
    const float* __restrict__ W1, const float* __restrict__ b1,
    const float* __restrict__ W2, const float* __restrict__ b2,
    const float* __restrict__ W3, const float* __restrict__ b3,
    float* __restrict__ Y)
{
  __shared__ float Xs[64][129];
  __shared__ float Hs[64][129];
  __shared__ float Bs[16][132];
  const int tid = threadIdx.x;
  const int lane = tid & 63, wv = tid >> 6;
  const int r0 = blockIdx.x * 64;
  #pragma unroll
  for (int i = 0; i < 8; i++){
    int g = tid + i*256;
    int row = g >> 5, cg = (g & 31)*4;
    float4 v = *(const float4*)(X + (size_t)(r0+row)*128 + cg);
    Xs[row][cg] = v.x; Xs[row][cg+1] = v.y; Xs[row][cg+2] = v.z; Xs[row][cg+3] = v.w;
  }
  float (*src)[129] = Xs;
  float (*dst)[129] = Hs;
  const float* Ws[3] = {W1, W2, W3};
  const float* bs[3] = {b1, b2, b3};
  for (int layer = 0; layer < 3; layer++){
    const float* W = Ws[layer];
    float acc[16][2];
    #pragma unroll
    for (int i = 0; i < 16; i++){ acc[i][0] = 0.f; acc[i][1] = 0.f; }
    for (int k0 = 0; k0 < 128; k0 += 16){
      __syncthreads();
      #pragma unroll
      for (int i = 0; i < 2; i++){
        int g = tid + i*256;
        int kb = g >> 5, cb = (g & 31)*4;
        float4 v = *(const float4*)(W + (size_t)(k0+kb)*128 + cb);
        Bs[kb][cb] = v.x; Bs[kb][cb+1] = v.y; Bs[kb][cb+2] = v.z; Bs[kb][cb+3] = v.w;
      }
      __syncthreads();
      #pragma unroll
      for (int kk = 0; kk < 16; kk++){
        float b0 = Bs[kk][lane], bq = Bs[kk][lane+64];
        #pragma unroll
        for (int i = 0; i < 16; i++){
          float a = src[wv*16+i][k0+kk];
          acc[i][0] += a*b0; acc[i][1] += a*bq;
        }
      }
    }
    float bb0 = bs[layer][lane], bb1 = bs[layer][lane+64];
    __syncthreads();
    if (layer < 2){
      #pragma unroll
      for (int i = 0; i < 16; i++){
        dst[wv*16+i][lane]    = fmaxf(acc[i][0] + bb0, 0.f);
        dst[wv*16+i][lane+64] = fmaxf(acc[i][1] + bb1, 0.f);
      }
      float (*tmp)[129] = src; src = dst; dst = tmp;
    } else {
      #pragma unroll
      for (int i = 0; i < 16; i++){
        size_t r = (size_t)(r0 + wv*16 + i)*128;
        Y[r + lane]    = acc[i][0] + bb0;
        Y[r + lane+64] = acc[i][1] + bb1;
      }
    }
  }
}

// ---------------- mega-fused LN-LSTM ----------------
template<int NSEG>
__global__ __launch_bounds__(256) void k_lstm_fused(
    const float* __restrict__ A0, const float* __restrict__ A1, const float* __restrict__ A2,
    int flip1,
    const float* __restrict__ W0, const float* __restrict__ W1w, const float* __restrict__ W2w,
    const float* __restrict__ lni_g, const float* __restrict__ lni_b,
    const float* __restrict__ lnh_g, const float* __restrict__ lnh_b,
    const float* __restrict__ lnc_g, const float* __restrict__ lnc_b,
    const float* __restrict__ c_in, float* __restrict__ c_out,
    float* __restrict__ h_out)
{
  __shared__ float Bs[16][520];
  __shared__ float As[32][17];
  const int tid = threadIdx.x;
  const int lane = tid & 63, wv = tid >> 6;
  const int r0 = blockIdx.x * 32;
  const int ar = tid >> 3, ak = (tid & 7)*2;

  float acc1[8][8], acc2[8][8];
  #pragma unroll
  for (int i = 0; i < 8; i++)
    #pragma unroll
    for (int j = 0; j < 8; j++){ acc1[i][j] = 0.f; acc2[i][j] = 0.f; }

  #pragma unroll
  for (int s = 0; s < NSEG; ++s){
    const float* Ap = (s==0) ? A0 : ((s==1) ? A1 : A2);
    const float* Wp = (s==0) ? W0 : ((s==1) ? W1w : W2w);
    const int fm = (s==1) ? flip1 : 0;
    const int arow = (r0 + ar) ^ fm;
    for (int k0 = 0; k0 < 128; k0 += 16){
      __syncthreads();
      {
        float2 av = *(const float2*)(Ap + (size_t)arow*128 + k0 + ak);
        As[ar][ak] = av.x; As[ar][ak+1] = av.y;
        #pragma unroll
        for (int i = 0; i < 8; i++){
          int g = tid + i*256;
          int kb = g >> 7, cb = (g & 127)*4;
          float4 v = *(const float4*)(Wp + (size_t)(k0+kb)*512 + cb);
          Bs[kb][cb] = v.x; Bs[kb][cb+1] = v.y; Bs[kb][cb+2] = v.z; Bs[kb][cb+3] = v.w;
        }
      }
      __syncthreads();
      if (s == NSEG-1){
        #pragma unroll
        for (int kk = 0; kk < 16; kk++){
          float b[8], a[8];
          #pragma unroll
          for (int j = 0; j < 8; j++) b[j] = Bs[kk][lane + 64*j];
          #pragma unroll
          for (int i = 0; i < 8; i++) a[i] = As[wv*8+i][kk];
          #pragma unroll
          for (int i = 0; i < 8; i++)
            #pragma unroll
            for (int j = 0; j < 8; j++) acc2[i][j] += a[i]*b[j];
        }
      } else {
        #pragma unroll
        for (int kk = 0; kk < 16; kk++){
          float b[8], a[8];
          #pragma unroll
          for (int j = 0; j < 8; j++) b[j] = Bs[kk][lane + 64*j];
          #pragma unroll
          for (int i = 0; i < 8; i++) a[i] = As[wv*8+i][kk];
          #pragma unroll
          for (int i = 0; i < 8; i++)
            #pragma unroll
            for (int j = 0; j < 8; j++) acc1[i][j] += a[i]*b[j];
        }
      }
    }
  }

  float lig[8], lib[8], lhg[8], lhb[8];
  #pragma unroll
  for (int j = 0; j < 8; j++){
    int cl = lane + 64*j;
    lig[j] = lni_g[cl]; lib[j] = lni_b[cl];
    lhg[j] = lnh_g[cl]; lhb[j] = lnh_b[cl];
  }
  float lcg[2], lcb[2];
  #pragma unroll
  for (int jj = 0; jj < 2; jj++){ int cc = lane + 64*jj; lcg[jj] = lnc_g[cc]; lcb[jj] = lnc_b[cc]; }
  const float i512 = 1.f/512.f, i128 = 1.f/128.f;
  #pragma unroll
  for (int i = 0; i < 8; i++){
    int r = r0 + wv*8 + i;
    float s1=0.f, q1=0.f, s2=0.f, q2=0.f;
    #pragma unroll
    for (int j = 0; j < 8; j++){
      s1 += acc1[i][j]; q1 += acc1[i][j]*acc1[i][j];
      s2 += acc2[i][j]; q2 += acc2[i][j]*acc2[i][j];
    }
    #pragma unroll
    for (int m = 1; m < 64; m <<= 1){
      s1 += __shfl_xor(s1, m); q1 += __shfl_xor(q1, m);
      s2 += __shfl_xor(s2, m); q2 += __shfl_xor(q2, m);
    }
    float m1 = s1*i512, v1 = fmaxf(q1*i512 - m1*m1, 0.f), rs1 = rsqrtf(v1 + 1e-5f);
    float m2 = s2*i512, v2 = fmaxf(q2*i512 - m2*m2, 0.f), rs2 = rsqrtf(v2 + 1e-5f);
    float g[8];
    #pragma unroll
    for (int j = 0; j < 8; j++)
      g[j] = (acc1[i][j]-m1)*rs1*lig[j] + lib[j] + (acc2[i][j]-m2)*rs2*lhg[j] + lhb[j];
    float cpre[2], sc = 0.f, qc = 0.f;
    #pragma unroll
    for (int jj = 0; jj < 2; jj++){
      float iv = sigm(g[jj]), fv = sigm(g[jj+2]), gv = tanhf(g[jj+4]);
      float co = c_in[(size_t)r*128 + lane + 64*jj];
      cpre[jj] = fv*co + iv*gv;
      sc += cpre[jj]; qc += cpre[jj]*cpre[jj];
    }
    #pragma unroll
    for (int m = 1; m < 64; m <<= 1){ sc += __shfl_xor(sc, m); qc += __shfl_xor(qc, m); }
    float mc = sc*i128, vc = fmaxf(qc*i128 - mc*mc, 0.f), rsc = rsqrtf(vc + 1e-5f);
    #pragma unroll
    for (int jj = 0; jj < 2; jj++){
      float cy = (cpre[jj]-mc)*rsc*lcg[jj] + lcb[jj];
      c_out[(size_t)r*128 + lane + 64*jj] = cy;
      h_out[(size_t)r*128 + lane + 64*jj] = sigm(g[jj+6])*tanhf(cy);
    }
  }
}

// ------------- GEMM: C[M,N] = act(A_f32[M,K] @ W_f32[K,N] + bias) -------------
template<int ACT>
__global__ __launch_bounds__(256) void k_gemm_aw(const float* __restrict__ A,
    const float* __restrict__ W, const float* __restrict__ bias,
    float* __restrict__ C, int M, int N, int K)
{
  __shared__ float As[64][17];
  __shared__ float Ws[16][65];
  int tid = threadIdx.x;
  int bm = blockIdx.y*64, bn = blockIdx.x*64;
  int tx = tid & 15, ty = tid >> 4;
  int la_m = tid >> 2, la_k = (tid & 3)*4;
  int lw_k = tid >> 4, lw_n = (tid & 15)*4;
  float acc[4][4] = {};
  for (int k0 = 0; k0 < K; k0 += 16){
    float4 av = *(const float4*)(A + (size_t)(bm+la_m)*K + k0 + la_k);
    As[la_m][la_k+0]=av.x; As[la_m][la_k+1]=av.y; As[la_m][la_k+2]=av.z; As[la_m][la_k+3]=av.w;
    float4 wv = *(const float4*)(W + (size_t)(k0+lw_k)*N + bn + lw_n);
    Ws[lw_k][lw_n+0]=wv.x; Ws[lw_k][lw_n+1]=wv.y; Ws[lw_k][lw_n+2]=wv.z; Ws[lw_k][lw_n+3]=wv.w;
    __syncthreads();
    #pragma unroll
    for (int kk = 0; kk < 16; kk++){
      float a[4], b[4];
      #pragma unroll
      for (int i = 0; i < 4; i++) a[i] = As[ty*4+i][kk];
      #pragma unroll
      for (int j = 0; j < 4; j++) b[j] = Ws[kk][tx*4+j];
      #pragma unroll
      for (int i = 0; i < 4; i++)
        #pragma unroll
        for (int j = 0; j < 4; j++) acc[i][j] += a[i]*b[j];
    }
    __syncthreads();
  }
  #pragma unroll
  for (int i = 0; i < 4; i++){
    size_t m = bm + ty*4 + i;
    #pragma unroll
    for (int j = 0; j < 4; j++){
      int n = bn + tx*4 + j;
      float vv = acc[i][j];
      if (bias) vv += bias[n];
      if (ACT) vv = fmaxf(vv, 0.f);
      C[m*(size_t)N + n] = vv;
    }
  }
}

// --------- readout: read[b,t] = mask * [Lh[b,t] | Lh[b,t+T]] ---------
__global__ __launch_bounds__(256) void k_read(const float* __restrict__ Lh,
    const int* __restrict__ counts, float* __restrict__ rd)
{
  int i = blockIdx.x*256 + threadIdx.x;
  if (i >= B_*T_*D_) return;
  int d = i & (D_-1);
  int r = i >> 7;          // b*T + t
  int t = r & (T_-1);
  int b = r >> 10;
  int half = counts[b] / 2; if (half > T_) half = T_;
  float m = (t < half) ? 1.f : 0.f;
  rd[(size_t)r*C2_ + d]      = m * Lh[(size_t)(b*L_ + t)*D_ + d];
  rd[(size_t)r*C2_ + D_ + d] = m * Lh[(size_t)(b*L_ + t + T_)*D_ + d];
}

// --------- tiled flash attention over fused qkv [4096, 768] ---------
// q at +0, k at +256, v at +512 within each row. y output [4096, 256].
__global__ __launch_bounds__(256) void k_attn_tile(const float* __restrict__ qkv,
    const int* __restrict__ counts, float* __restrict__ y)
{
  const int b = blockIdx.z, h = blockIdx.y, t0 = blockIdx.x*64;
  int half = counts[b] / 2; if (half > T_) half = T_; if (half < 0) half = 0;
  const int tid = threadIdx.x;
  const int lane = tid & 63, wv = tid >> 6;
  const int lr = tid >> 2, lc = (tid & 3)*8;    // staging map

  if (t0 >= half){
    float* yp = y + ((size_t)(b*T_ + t0 + lr)*C2_ + h*HD_ + lc);
    #pragma unroll
    for (int j = 0; j < 8; j++) yp[j] = 0.f;
    return;
  }

  __shared__ float Qs[64][36];
  __shared__ float Ks[64][32];   // XOR-swizzled chunks
  __shared__ float Ss[64][68];

  // stage Q tile once
  {
    const float* qp = qkv + (size_t)(b*T_ + t0 + lr)*QS_ + h*HD_ + lc;
    float4 a0 = *(const float4*)qp;
    float4 a1 = *(const float4*)(qp+4);
    *(float4*)&Qs[lr][lc]   = a0;
    *(float4*)&Qs[lr][lc+4] = a1;
  }

  const int ty = tid >> 4, tx = tid & 15;          // S-phase map
  const int sr = wv*16 + (lane & 15);              // softmax row
  const int spart = (lane >> 4) * 16;              // softmax col segment
  const int rp = lane >> 3, cq = lane & 7;         // PV map
  const int r0 = wv*16 + rp*2;                     // PV rows r0, r0+1

  float4 acc0 = {0.f,0.f,0.f,0.f}, acc1 = {0.f,0.f,0.f,0.f};
  float mst = -3e38f, lst = 0.f;
  const float scale = 0.17677669529663687f;        // 1/sqrt(32)
  const int nt = (half + 63) >> 6;

  for (int st = 0; st < nt; ++st){
    const int s0 = st*64;
    __syncthreads();
    // stage K tile (swizzled: chunk c stored at c ^ ((row>>2)&7))
    {
      const float* kp = qkv + (size_t)(b*T_ + s0 + lr)*QS_ + 256 + h*HD_ + lc;
      float4 k0 = *(const float4*)kp;
      float4 k1 = *(const float4*)(kp+4);
      int key = (lr >> 2) & 7;
      int c0 = lc >> 2;
      *(float4*)&Ks[lr][4*((c0  ) ^ key)] = k0;
      *(float4*)&Ks[lr][4*((c0+1) ^ key)] = k1;
    }
    __syncthreads();

    // ---- S = Q K^T (4x4 per thread, all b128) ----
    float s4[4][4];
    #pragma unroll
    for (int i = 0; i < 4; i++)
      #pragma unroll
      for (int j = 0; j < 4; j++) s4[i][j] = 0.f;
    const int xk = tx & 7;
    #pragma unroll
    for (int kk4 = 0; kk4 < 8; kk4++){
      float4 a4[4], b4[4];
      #pragma unroll
      for (int i = 0; i < 4; i++) a4[i] = *(const float4*)&Qs[ty*4+i][kk4*4];
      const int pk = 4*(kk4 ^ xk);
      #pragma unroll
      for (int j = 0; j < 4; j++) b4[j] = *(const float4*)&Ks[tx*4+j][pk];
      #pragma unroll
      for (int i = 0; i < 4; i++)
        #pragma unroll
        for (int j = 0; j < 4; j++)
          s4[i][j] += a4[i].x*b4[j].x + a4[i].y*b4[j].y + a4[i].z*b4[j].z + a4[i].w*b4[j].w;
    }
    #pragma unroll
    for (int i = 0; i < 4; i++){
      float4 w4;
      w4.x = (s0 + tx*4 + 0 < half) ? s4[i][0]*scale : -1e30f;
      w4.y = (s0 + tx*4 + 1 < half) ? s4[i][1]*scale : -1e30f;
      w4.z = (s0 + tx*4 + 2 < half) ? s4[i][2]*scale : -1e30f;
      w4.w = (s0 + tx*4 + 3 < half) ? s4[i][3]*scale : -1e30f;
      *(float4*)&Ss[ty*4+i][tx*4] = w4;
    }

    // ---- online softmax (wave-private) ----
    float pvv[16];
    float vmax = -3e38f;
    #pragma unroll
    for (int c4 = 0; c4 < 4; c4++){
      float4 t4 = *(const float4*)&Ss[sr][spart + c4*4];
      pvv[c4*4+0] = t4.x; pvv[c4*4+1] = t4.y; pvv[c4*4+2] = t4.z; pvv[c4*4+3] = t4.w;
      vmax = fmaxf(vmax, fmaxf(fmaxf(t4.x, t4.y), fmaxf(t4.z, t4.w)));
    }
    vmax = fmaxf(vmax, __shfl_xor(vmax, 16));
    vmax = fmaxf(vmax, __shfl_xor(vmax, 32));
    float nm = fmaxf(mst, vmax);
    float alpha = expf(mst - nm);
    float psum = 0.f;
    #pragma unroll
    for (int c = 0; c < 16; c++){
      float p = expf(pvv[c] - nm);
      pvv[c] = p; psum += p;
    }
    psum += __shfl_xor(psum, 16);
    psum += __shfl_xor(psum, 32);
    lst = lst*alpha + psum;
    mst = nm;
    #pragma unroll
    for (int c4 = 0; c4 < 4; c4++){
      float4 w4; w4.x = pvv[c4*4+0]; w4.y = pvv[c4*4+1]; w4.z = pvv[c4*4+2]; w4.w = pvv[c4*4+3];
      *(float4*)&Ss[sr][spart + c4*4] = w4;
    }
    float al0 = __shfl(alpha, 2*rp);
    float al1 = __shfl(alpha, 2*rp + 1);
    acc0.x *= al0; acc0.y *= al0; acc0.z *= al0; acc0.w *= al0;
    acc1.x *= al1; acc1.y *= al1; acc1.z *= al1; acc1.w *= al1;

    // ---- PV: P from LDS (b128), V from global (coalesced, L1) ----
    const float* vbase = qkv + (size_t)(b*T_ + s0)*QS_ + 512 + h*HD_ + cq*4;
    #pragma unroll 4
    for (int kk4 = 0; kk4 < 16; kk4++){
      float4 p0 = *(const float4*)&Ss[r0  ][kk4*4];
      float4 p1 = *(const float4*)&Ss[r0+1][kk4*4];
      float4 v0 = *(const float4*)(vbase + (size_t)(kk4*4+0)*QS_);
      float4 v1 = *(const float4*)(vbase + (size_t)(kk4*4+1)*QS_);
      float4 v2 = *(const float4*)(vbase + (size_t)(kk4*4+2)*QS_);
      float4 v3 = *(const float4*)(vbase + (size_t)(kk4*4+3)*QS_);
      acc0.x += p0.x*v0.x + p0.y*v1.x + p0.z*v2.x + p0.w*v3.x;
      acc0.y += p0.x*v0.y + p0.y*v1.y + p0.z*v2.y + p0.w*v3.y;
      acc0.z += p0.x*v0.z + p0.y*v1.z + p0.z*v2.z + p0.w*v3.z;
      acc0.w += p0.x*v0.w + p0.y*v1.w + p0.z*v2.w + p0.w*v3.w;
      acc1.x += p1.x*v0.x + p1.y*v1.x + p1.z*v2.x + p1.w*v3.x;
      acc1.y += p1.x*v0.y + p1.y*v1.y + p1.z*v2.y + p1.w*v3.y;
      acc1.z += p1.x*v0.z + p1.y*v1.z + p1.z*v2.z + p1.w*v3.z;
      acc1.w += p1.x*v0.w + p1.y*v1.w + p1.z*v2.w + p1.w*v3.w;
    }
  }

  // ---- finalize ----
  float l0 = __shfl(lst, 2*rp);
  float l1 = __shfl(lst, 2*rp + 1);
  float m0 = (t0 + r0     < half && l0 > 0.f) ? 1.f/l0 : 0.f;
  float m1 = (t0 + r0 + 1 < half && l1 > 0.f) ? 1.f/l1 : 0.f;
  float4 o0, o1;
  o0.x = acc0.x*m0; o0.y = acc0.y*m0; o0.z = acc0.z*m0; o0.w = acc0.w*m0;
  o1.x = acc1.x*m1; o1.y = acc1.y*m1; o1.z = acc1.z*m1; o1.w = acc1.w*m1;
  *(float4*)(y + ((size_t)(b*T_ + t0 + r0    )*C2_ + h*HD_ + cq*4)) = o0;
  *(float4*)(y + ((size_t)(b*T_ + t0 + r0 + 1)*C2_ + h*HD_ + cq*4)) = o1;
}

// --------- final heads: hv = [asn_hidden(128) | vote_hidden(128)] per row ---------
__global__ __launch_bounds__(128) void k_final(const float* __restrict__ hv,
    const float* __restrict__ aW2, const float* __restrict__ ab2,
    const float* __restrict__ vW2, const float* __restrict__ vb2,
    const int* __restrict__ counts, void* __restrict__ outv,
    float* __restrict__ vote_sum, const int* __restrict__ flag)
{
  int row = blockIdx.x, tid = threadIdx.x;
  int b = row / T_, t = row - b*T_;
  int half = counts[b] / 2; if (half > T_) half = T_;
  float pa = hv[(size_t)row*256 + tid]       * aW2[tid];
  float pv = hv[(size_t)row*256 + 128 + tid] * vW2[tid];
  #pragma unroll
  for (int off = 32; off > 0; off >>= 1){ pa += __shfl_down(pa, off); pv += __shfl_down(pv, off); }
  __shared__ float r[2][2];
  int wid = tid >> 6, lane = tid & 63;
  if (lane == 0){ r[0][wid] = pa; r[1][wid] = pv; }
  __syncthreads();
  if (tid == 0){
    float a  = sigm(r[0][0] + r[0][1] + ab2[0]);
    float vv = sigm(r[1][0] + r[1][1] + vb2[0]);
    bool mk = (t < half);
    float av = mk ? a : 0.f;
    if (*flag) ((u16*)outv)[4 + row] = f2bf(av);
    else       ((float*)outv)[4 + row] = av;
    if (mk) atomicAdd(vote_sum + b, vv);
  }
}

__global__ void k_votes(const float* __restrict__ vote_sum, const int* __restrict__ counts,
                        void* __restrict__ outv, const int* __restrict__ flag){
  int b = threadIdx.x;
  if (b < B_){
    int half = counts[b] / 2; if (half > T_) half = T_;
    float den = (float)(half > 1 ? half : 1);
    float vv = vote_sum[b] / den;
    if (*flag) ((u16*)outv)[b] = f2bf(vv);
    else       ((float*)outv)[b] = vv;
  }
}

static void gemm_aw(const float* A, const float* W, const float* bias, float* C,
                    int M, int N, int K, int act, hipStream_t s){
  dim3 g(N/64, M/64);
  if (act) k_gemm_aw<1><<<g, 256, 0, s>>>(A, W, bias, C, M, N, K);
  else     k_gemm_aw<0><<<g, 256, 0, s>>>(A, W, bias, C, M, N, K);
}

extern "C" void kernel_launch(void* const* d_in, const int* in_sizes, int n_in,
                              void* d_out, int out_size, void* d_ws, size_t ws_size,
                              hipStream_t stream)
{
  const void* A_adj = d_in[0];
  const int* counts = (const int*)d_in[1];

  const size_t M1 = (size_t)1048576;
  const size_t NEED = (5*M1 + M1 + 2*M1 + 2*M1 + 700416 + 16416 + 8224
                       + 16384 + 8192 + 520000 + 520000 + 32) * sizeof(float);
  if (ws_size < NEED) return;

  float* ws = (float*)d_ws;
  float* R    = ws;              // 5 x 1M rotating region (Lh lives here)
  float* Lc   = R + 5*M1;
  float* Ch   = Lc + M1;
  float* Cc   = Ch + 2*M1;
  float* wp   = Cc + 2*M1;
  unsigned* off_c = (unsigned*)(wp + 700416);
  unsigned* off_l = off_c + 16416;
  unsigned* cnt_c = off_l + 8224;
  unsigned* cnt_l = cnt_c + 16384;
  u16* val_c = (u16*)(cnt_l + 8192);
  u16* val_l = (u16*)((float*)val_c + 520000);
  float* tail = (float*)val_l + 520000;
  float* vote_sum = tail;
  int* flag = (int*)(tail + 8);
  unsigned* bits = (unsigned*)R;   // 1M words; dead before k_init writes R0

  float* R0 = R, *R1 = R + M1, *R2 = R + 2*M1, *R3 = R + 3*M1, *R4 = R + 4*M1;

  k_detect<<<1, 256, 0, stream>>>((const unsigned int*)A_adj, flag);

  // ---- weight conversion jobs (incl. fused qkv / head-mlp placement) ----
  Jobs jb;
  int nj = 0;
  unsigned off = 0;
  auto add = [&](int idx, unsigned n, unsigned dst, unsigned sh, unsigned stride){
    jb.src[nj] = d_in[idx]; jb.n[nj] = n; jb.off[nj] = dst;
    jb.sh[nj] = sh; jb.stride[nj] = stride; nj++;
  };
  auto plain = [&](int idx, unsigned n)->float*{
    float* p = wp + off; add(idx, n, off, 30, 0); off += (n + 3u) & ~3u; return p;
  };
  float* Linit = plain(2, 128);
  float* Cinit = plain(3, 128);
  float *LC_W1=plain(4,16384),  *LC_b1=plain(5,128);
  float *LC_W2=plain(6,16384),  *LC_b2=plain(7,128);
  float *LC_W3=plain(8,16384),  *LC_b3=plain(9,128);
  float *CL_W1=plain(10,16384), *CL_b1=plain(11,128);
  float *CL_W2=plain(12,16384), *CL_b2=plain(13,128);
  float *CL_W3=plain(14,16384), *CL_b3=plain(15,128);
  float *Lu_Wih=plain(16,131072), *Lu_Whh=plain(17,65536);
  float *Lu_lni_g=plain(18,512), *Lu_lni_b=plain(19,512);
  float *Lu_lnh_g=plain(20,512), *Lu_lnh_b=plain(21,512);
  float *Lu_lnc_g=plain(22,128), *Lu_lnc_b=plain(23,128);
  float *Cu_Wih=plain(24,65536), *Cu_Whh=plain(25,65536);
  float *Cu_lni_g=plain(26,512), *Cu_lni_b=plain(27,512);
  float *Cu_lnh_g=plain(28,512), *Cu_lnh_b=plain(29,512);
  float *Cu_lnc_g=plain(30,128), *Cu_lnc_b=plain(31,128);
  float *asn_W2=plain(40,128),  *asn_b2=plain(41,1);
  float *vote_W2=plain(44,128), *vote_b2=plain(45,1);
  // fused qkv weight [256 x 768] = [Wq | Wk | Wv] column blocks
  float* Wqkv = wp + off;
  add(34, 65536, off+0,   8, 768);   // att_Wq
  add(32, 65536, off+256, 8, 768);   // att_Wk
  add(36, 65536, off+512, 8, 768);   // att_Wv
  off += 196608;
  float* bqkv = wp + off;
  add(35, 256, off+0,   8, 0);
  add(33, 256, off+256, 8, 0);
  add(37, 256, off+512, 8, 0);
  off += 768;
  // fused head-mlp weight [256 x 256] = [asn_W1 | vote_W1]
  float* Whv = wp + off;
  add(38, 32768, off+0,   7, 256);
  add(42, 32768, off+128, 7, 256);
  off += 65536;
  float* bhv = wp + off;
  add(39, 128, off+0,   7, 0);
  add(43, 128, off+128, 7, 0);
  off += 256;
  { dim3 g(512, NJOBS_); k_cvt_all<<<g, 256, 0, stream>>>(jb, wp, flag); }

  // ---- CSR build: pack -> scan -> fill (atomic-light, one dense read) ----
  k_zero_u<<<(16384+255)/256, 256, 0, stream>>>(cnt_c, 16384);
  k_pack<<<BL_, 128, 0, stream>>>(A_adj, bits, cnt_l, flag);
  k_scan<<<1, 256, 0, stream>>>(cnt_l, off_l, 8192);
  k_fill_l<<<BL_, 128, 0, stream>>>(bits, off_l, val_l, cnt_c);
  k_scan<<<1, 256, 0, stream>>>(cnt_c, off_c, 16384);
  k_fill_c<<<4096, 256, 0, stream>>>(bits, off_c, cnt_c, val_c);

  // ---- init states (overwrites bits region — build is complete) ----
  k_init<<<(BL_*D_)/256, 256, 0, stream>>>(R0, Lc, Linit, BL_*D_);
  k_init<<<(BNC_*D_)/256, 256, 0, stream>>>(Ch, Cc, Cinit, BNC_*D_);

  for (int it = 0; it < ITERS_; ++it){
    bool ev = ((it & 1) == 0);
    float* cur  = ev ? R0 : R4;
    float* msgL = ev ? R1 : R0;
    float* LCb  = ev ? R2 : R1;
    float* msgC = LCb;
    float* CLb  = ev ? R1 : R3;
    float* nxt  = ev ? R4 : R0;

    k_mlp3<<<BL_/64, 256, 0, stream>>>(cur, LC_W1, LC_b1, LC_W2, LC_b2, LC_W3, LC_b3, msgL);
    k_spmm<<<BNC_/4, 256, 0, stream>>>(off_c, val_c, msgL, LCb, 12, 11);
    k_lstm_fused<2><<<BNC_/32, 256, 0, stream>>>(LCb, Ch, nullptr, 0,
        Cu_Wih, Cu_Whh, nullptr,
        Cu_lni_g, Cu_lni_b, Cu_lnh_g, Cu_lnh_b, Cu_lnc_g, Cu_lnc_b, Cc, Cc, Ch);
    k_mlp3<<<BNC_/64, 256, 0, stream>>>(Ch, CL_W1, CL_b1, CL_W2, CL_b2, CL_W3, CL_b3, msgC);
    k_spmm<<<BL_/4, 256, 0, stream>>>(off_l, val_l, msgC, CLb, 11, 12);
    k_lstm_fused<3><<<BL_/32, 256, 0, stream>>>(CLb, cur, cur, 1024,
        Lu_Wih, Lu_Wih + 128*512, Lu_Whh,
        Lu_lni_g, Lu_lni_b, Lu_lnh_g, Lu_lnh_b, Lu_lnc_g, Lu_lnc_b, Lc, Lc, nxt);
  }
  float* Lh = R0;

  // ---- readout + attention (reuse dead regions) ----
  float* readb = Lc;            // 1M (literal cell state dead)
  float* qkvb  = Ch;            // 3M spans Ch + first 1M of Cc
  float* yb    = R1;            // 1M
  float* hv    = R2;            // 1M: [4096][256] = [asn_h | vote_h]

  k_read<<<(B_*T_*D_)/256, 256, 0, stream>>>(Lh, counts, readb);
  gemm_aw(readb, Wqkv, bqkv, qkvb, B_*T_, 768, 256, 0, stream);
  { dim3 g(T_/64, NH_, B_); k_attn_tile<<<g, 256, 0, stream>>>(qkvb, counts, yb); }
  gemm_aw(yb, Whv, bhv, hv, B_*T_, 256, 256, 1, stream);
  k_zero<<<1, 64, 0, stream>>>(vote_sum, B_);
  k_final<<<B_*T_, 128, 0, stream>>>(hv, asn_W2, asn_b2, vote_W2, vote_b2,
                                     counts, d_out, vote_sum, flag);
  k_votes<<<1, 64, 0, stream>>>(vote_sum, counts, d_out, flag);
}

// Round 7
// 1908.664 us; speedup vs baseline: 3.5718x; 1.5176x over previous
//
#include <hip/hip_runtime.h>

// NeuroSATAssign: B=4, L=2048, NC=4096, D=128, ITERS=4, NH=8, T=1024.
// Round 7: all dense GEMMs -> matrix cores via SPLIT-F32 bf16 MFMA
// (a = ah+al bf16; a*b ~= ah*bh + ah*bl + al*bh, ~2^-15 relative error --
// plain bf16 would risk the 1.3e-2 threshold over 16 chained GEMMs).
// Weights pre-transformed once into frag-linear hi/lo bf16 (B-frags read
// straight from global, L2-hot; no B staging barriers). New kernels:
// k_lstm_mfma (gates+2xLN+pointwise+cellLN), k_mlp3m (3 chained layers),
// k_gemm_mfma (fused QKV N=768, fused head-MLP N=256). f32 weight copies
// dropped from the pool to pay for the u16 frag arrays: ws size UNCHANGED.
// CSR build / spmm / flash-attn / heads unchanged from round 6.

#define B_    4
#define L_    2048
#define NC_   4096
#define D_    128
#define ITERS_ 4
#define NH_   8
#define T_    1024
#define C2_   256
#define HD_   32
#define BL_   (B_*L_)    // 8192
#define BNC_  (B_*NC_)   // 16384
#define QS_   768        // fused qkv row stride

typedef unsigned short u16;
typedef __attribute__((ext_vector_type(8))) short b16x8;
typedef __attribute__((ext_vector_type(4))) float f32x4;

static __device__ __forceinline__ float bf2f(u16 u){
  union{unsigned int i; float f;} x; x.i = ((unsigned int)u) << 16; return x.f;
}
static __device__ __forceinline__ u16 f2bf(float f){
  union{float f; unsigned int i;} x; x.f = f;
  unsigned int r = x.i + 0x7fffu + ((x.i >> 16) & 1u);
  return (u16)(r >> 16);
}
static __device__ __forceinline__ float sigm(float x){ return 1.f/(1.f+expf(-x)); }
// split f32 -> hi (truncated bf16) + lo (bf16 of residual); hi+lo ~ v to 2^-16
static __device__ __forceinline__ void split2(float v, u16& h, u16& l){
  unsigned bits = __float_as_uint(v);
  u16 hb = (u16)(bits >> 16);
  float hf = __uint_as_float(((unsigned)hb) << 16);
  h = hb; l = f2bf(v - hf);
}

// ---- dtype detect: adjacency is exactly {0.0f,1.0f} iff stored as f32 ----
__global__ __launch_bounds__(256) void k_detect(const unsigned int* __restrict__ a,
                                                int* __restrict__ flag){
  int bad = 0;
  for (int i = threadIdx.x; i < 32768; i += 256){
    unsigned int w = a[i];
    if (w != 0u && w != 0x3F800000u) bad = 1;
  }
  __shared__ int s[256];
  s[threadIdx.x] = bad; __syncthreads();
  for (int o = 128; o > 0; o >>= 1){
    if (threadIdx.x < o) s[threadIdx.x] |= s[threadIdx.x + o];
    __syncthreads();
  }
  if (threadIdx.x == 0) *flag = s[0];   // 1 = bf16 inputs, 0 = f32 inputs
}

// ---- small f32 param conversion into pool ----
#define NCJ_ 29
struct CJobs { const void* src[NCJ_]; unsigned n[NCJ_]; unsigned off[NCJ_]; };

__global__ __launch_bounds__(256) void k_cvt_all(CJobs jb, float* __restrict__ pool,
                                                 const int* __restrict__ flag){
  int j = blockIdx.y;
  unsigned n = jb.n[j];
  unsigned i = blockIdx.x*256 + threadIdx.x;
  if (i >= n) return;
  float v;
  if (*flag) v = bf2f(((const u16*)jb.src[j])[i]);
  else       v = ((const float*)jb.src[j])[i];
  pool[jb.off[j] + i] = v;
}

// ---- weight prep: frag-linear split bf16. dst element g:
// j=g&7, lane=(g>>3)&63, ks=(g>>9)&(2^ksb-1), nt=g>>(9+ksb);
// n=nt*16+(lane&15), k=koff+ks*32+(lane>>4)*8+j, src=k*N+n. ----
#define NPJ_ 16
struct PJobs { const void* src[NPJ_]; unsigned n[NPJ_], N[NPJ_], koff[NPJ_],
               ksb[NPJ_], dh[NPJ_], dl[NPJ_]; };

__global__ __launch_bounds__(256) void k_prep(PJobs pj, u16* __restrict__ up,
                                              const int* __restrict__ flag){
  int jj = blockIdx.y;
  unsigned n = pj.n[jj];
  unsigned g = blockIdx.x*256 + threadIdx.x;
  if (g >= n) return;
  unsigned j = g & 7, lane = (g>>3)&63;
  unsigned ksb = pj.ksb[jj];
  unsigned ks = (g>>9) & ((1u<<ksb)-1u);
  unsigned nt = g >> (9+ksb);
  unsigned ncol = nt*16 + (lane&15);
  unsigned k = pj.koff[jj] + ks*32 + ((lane>>4)&3)*8 + j;
  unsigned si = k*pj.N[jj] + ncol;
  float v;
  if (*flag) v = bf2f(((const u16*)pj.src[jj])[si]);
  else       v = ((const float*)pj.src[jj])[si];
  u16 h,l; split2(v, h, l);
  up[pj.dh[jj] + g] = h;
  up[pj.dl[jj] + g] = l;
}

// ---------------- init: h[i] = init[i%D], c[i] = 0 ----------------
__global__ __launch_bounds__(256) void k_init(float* __restrict__ h, float* __restrict__ c,
                                              const float* __restrict__ init, int n){
  int i = blockIdx.x*256 + threadIdx.x;
  if (i < n){ h[i] = init[i & (D_-1)]; c[i] = 0.f; }
}

__global__ void k_zero_u(unsigned* __restrict__ p, int n){
  int i = blockIdx.x*256 + threadIdx.x; if (i < n) p[i] = 0u;
}
__global__ void k_zero(float* p, int n){
  int i = blockIdx.x*64 + threadIdx.x; if (i < n) p[i] = 0.f;
}

// ---------------- CSR build: pack / scan / fill ----------------
__global__ __launch_bounds__(128) void k_pack(const void* __restrict__ A,
    unsigned* __restrict__ bits, unsigned* __restrict__ cnt_l,
    const int* __restrict__ flag){
  const int row = blockIdx.x, w = threadIdx.x;
  unsigned m = 0;
  if (*flag){
    const ushort4* p = (const ushort4*)A + (size_t)row*(NC_/4) + w*8;
    #pragma unroll
    for (int i = 0; i < 8; i++){
      ushort4 u = p[i];
      m |= (unsigned)(u.x != 0) << (i*4);
      m |= (unsigned)(u.y != 0) << (i*4+1);
      m |= (unsigned)(u.z != 0) << (i*4+2);
      m |= (unsigned)(u.w != 0) << (i*4+3);
    }
  } else {
    const float4* p = (const float4*)A + (size_t)row*(NC_/4) + w*8;
    #pragma unroll
    for (int i = 0; i < 8; i++){
      float4 v = p[i];
      m |= (unsigned)(v.x != 0.f) << (i*4);
      m |= (unsigned)(v.y != 0.f) << (i*4+1);
      m |= (unsigned)(v.z != 0.f) << (i*4+2);
      m |= (unsigned)(v.w != 0.f) << (i*4+3);
    }
  }
  bits[(size_t)row*128 + w] = m;
  unsigned pc = __popc(m);
  #pragma unroll
  for (int o = 1; o < 64; o <<= 1) pc += __shfl_xor(pc, o);
  __shared__ unsigned ss[2];
  if ((w & 63) == 0) ss[w >> 6] = pc;
  __syncthreads();
  if (w == 0) cnt_l[row] = ss[0] + ss[1];
}

__global__ __launch_bounds__(256) void k_scan(unsigned* __restrict__ cnt,
    unsigned* __restrict__ off, int n){
  __shared__ unsigned ps[257];
  int t = threadIdx.x;
  int seg = n >> 8;
  int base = t*seg;
  unsigned s = 0;
  for (int i = 0; i < seg; i++) s += cnt[base+i];
  ps[t] = s;
  __syncthreads();
  if (t == 0){
    unsigned run = 0;
    for (int i = 0; i < 256; i++){ unsigned x = ps[i]; ps[i] = run; run += x; }
    ps[256] = run;
  }
  __syncthreads();
  unsigned run = ps[t];
  for (int i = 0; i < seg; i++){ off[base+i] = run; run += cnt[base+i]; cnt[base+i] = 0u; }
  if (t == 0) off[n] = ps[256];
}

__global__ __launch_bounds__(128) void k_fill_l(const unsigned* __restrict__ bits,
    const unsigned* __restrict__ off_l, u16* __restrict__ val_l,
    unsigned* __restrict__ cnt_c){
  const int row = blockIdx.x, w = threadIdx.x;
  const int b = row >> 11;
  unsigned m = bits[(size_t)row*128 + w];
  unsigned pc = __popc(m);
  __shared__ unsigned s[128];
  s[w] = pc; __syncthreads();
  #pragma unroll
  for (int o = 1; o < 128; o <<= 1){
    unsigned v = (w >= o) ? s[w-o] : 0u;
    __syncthreads();
    s[w] += v;
    __syncthreads();
  }
  unsigned base = off_l[row] + s[w] - pc;
  unsigned cb = ((unsigned)b << 12) + w*32;
  while (m){
    int j = __ffs(m) - 1; m &= m - 1;
    val_l[base++] = (u16)(w*32 + j);
    atomicAdd(cnt_c + cb + j, 1u);
  }
}

__global__ __launch_bounds__(256) void k_fill_c(const unsigned* __restrict__ bits,
    const unsigned* __restrict__ off_c, unsigned* __restrict__ cur_c,
    u16* __restrict__ val_c){
  int g = blockIdx.x*256 + threadIdx.x;
  unsigned m = bits[g];
  int row = g >> 7, w = g & 127;
  int b = row >> 11, l = row & (L_-1);
  unsigned cb = ((unsigned)b << 12) + w*32;
  while (m){
    int j = __ffs(m) - 1; m &= m - 1;
    unsigned idx = cb + j;
    unsigned pos = atomicAdd(cur_c + idx, 1u);
    val_c[off_c[idx] + pos] = (u16)l;
  }
}

// ---------------- SpMM (f32, exact) ----------------
__global__ __launch_bounds__(256) void k_spmm(const unsigned* __restrict__ off,
    const u16* __restrict__ val, const float* __restrict__ M, float* __restrict__ out,
    int sh1, int sh2){
  int row  = blockIdx.x*4 + (threadIdx.x >> 6);
  int lane = threadIdx.x & 63;
  unsigned p0 = off[row], p1 = off[row+1];
  const float2* Mp = (const float2*)M + (((size_t)(row >> sh1) << sh2) * 64) + lane;
  float x = 0.f, y = 0.f;
  for (unsigned p = p0; p < p1; ++p){
    float2 v = Mp[(size_t)val[p] * 64];
    x += v.x; y += v.y;
  }
  float2 r; r.x = x; r.y = y;
  ((float2*)out)[(size_t)row*64 + lane] = r;
}

// ---------------- MFMA 3-layer MLP: 32 rows/block, wave owns 32 cols ----------------
__global__ __launch_bounds__(256) void k_mlp3m(const float* __restrict__ X,
    const u16* __restrict__ W1h, const u16* __restrict__ W1l,
    const u16* __restrict__ W2h, const u16* __restrict__ W2l,
    const u16* __restrict__ W3h, const u16* __restrict__ W3l,
    const float* __restrict__ b1, const float* __restrict__ b2,
    const float* __restrict__ b3, float* __restrict__ Y)
{
  __shared__ __align__(16) u16 Ah[32*136];
  __shared__ __align__(16) u16 Al[32*136];
  const int tid = threadIdx.x, lane = tid & 63, wv = tid >> 6;
  const int quad = lane >> 4, l15 = lane & 15;
  const int r0 = blockIdx.x * 32;
  { // stage X: 16 f32/thread
    int row = tid >> 3, c0 = (tid & 7)*16;
    const float4* src = (const float4*)(X + (size_t)(r0+row)*128 + c0);
    #pragma unroll
    for (int q4 = 0; q4 < 4; q4++){
      float4 v = src[q4]; int k = c0 + q4*4;
      u16 h,l;
      split2(v.x,h,l); Ah[row*136+k]  =h; Al[row*136+k]  =l;
      split2(v.y,h,l); Ah[row*136+k+1]=h; Al[row*136+k+1]=l;
      split2(v.z,h,l); Ah[row*136+k+2]=h; Al[row*136+k+2]=l;
      split2(v.w,h,l); Ah[row*136+k+3]=h; Al[row*136+k+3]=l;
    }
  }
  __syncthreads();
  const u16* Whs[3] = {W1h, W2h, W3h};
  const u16* Wls[3] = {W1l, W2l, W3l};
  const float* bs[3] = {b1, b2, b3};
  #pragma unroll
  for (int layer = 0; layer < 3; layer++){
    f32x4 acc[2][2] = {};
    #pragma unroll
    for (int ks = 0; ks < 4; ks++){
      b16x8 a_h[2], a_l[2];
      #pragma unroll
      for (int mt = 0; mt < 2; mt++){
        int ao = (mt*16 + l15)*136 + ks*32 + quad*8;
        a_h[mt] = *(const b16x8*)(Ah + ao);
        a_l[mt] = *(const b16x8*)(Al + ao);
      }
      #pragma unroll
      for (int ntl = 0; ntl < 2; ntl++){
        int nt = wv*2 + ntl;
        size_t bo = (size_t)((nt*4 + ks)*64 + lane)*8;
        b16x8 bh = *(const b16x8*)(Whs[layer] + bo);
        b16x8 bl = *(const b16x8*)(Wls[layer] + bo);
        #pragma unroll
        for (int mt = 0; mt < 2; mt++){
          acc[mt][ntl] = __builtin_amdgcn_mfma_f32_16x16x32_bf16(a_h[mt], bh, acc[mt][ntl],0,0,0);
          acc[mt][ntl] = __builtin_amdgcn_mfma_f32_16x16x32_bf16(a_h[mt], bl, acc[mt][ntl],0,0,0);
          acc[mt][ntl] = __builtin_amdgcn_mfma_f32_16x16x32_bf16(a_l[mt], bh, acc[mt][ntl],0,0,0);
        }
      }
    }
    if (layer < 2){
      __syncthreads();
      #pragma unroll
      for (int mt = 0; mt < 2; mt++)
        #pragma unroll
        for (int ntl = 0; ntl < 2; ntl++){
          int col = wv*32 + ntl*16 + l15;
          float bb = bs[layer][col];
          #pragma unroll
          for (int r = 0; r < 4; r++){
            int row = mt*16 + quad*4 + r;
            float v = fmaxf(acc[mt][ntl][r] + bb, 0.f);
            u16 h,l; split2(v,h,l);
            Ah[row*136 + col] = h; Al[row*136 + col] = l;
          }
        }
      __syncthreads();
    } else {
      #pragma unroll
      for (int mt = 0; mt < 2; mt++)
        #pragma unroll
        for (int ntl = 0; ntl < 2; ntl++){
          int col = wv*32 + ntl*16 + l15;
          float bb = bs[2][col];
          #pragma unroll
          for (int r = 0; r < 4; r++){
            int row = mt*16 + quad*4 + r;
            Y[(size_t)(r0+row)*128 + col] = acc[mt][ntl][r] + bb;
          }
        }
    }
  }
}

// ---------------- MFMA mega-fused LN-LSTM: 32 rows/block ----------------
// acc1 = sum_{s<NSEG-1} A_s @ W_s (lni LN); acc2 = A_{NSEG-1} @ W_{NSEG-1} (lnh LN).
template<int NSEG>
__global__ __launch_bounds__(256) void k_lstm_mfma(
    const float* __restrict__ A0, const float* __restrict__ A1, const float* __restrict__ A2,
    int flip1,
    const u16* __restrict__ W0h, const u16* __restrict__ W0l,
    const u16* __restrict__ W1h, const u16* __restrict__ W1l,
    const u16* __restrict__ W2h, const u16* __restrict__ W2l,
    const float* __restrict__ lni_g, const float* __restrict__ lni_b,
    const float* __restrict__ lnh_g, const float* __restrict__ lnh_b,
    const float* __restrict__ lnc_g, const float* __restrict__ lnc_b,
    const float* __restrict__ c_in, float* __restrict__ c_out,
    float* __restrict__ h_out)
{
  __shared__ __align__(16) float G[32*516];    // 66KB; phase1 aliases Ah/Al
  __shared__ float red[4][32][4];
  __shared__ float st[32][4];
  u16* Ah = (u16*)G;                            // 32*136 u16
  u16* Al = Ah + 32*136;
  const int tid = threadIdx.x, lane = tid & 63, wv = tid >> 6;
  const int quad = lane >> 4, l15 = lane & 15;
  const int r0 = blockIdx.x * 32;

  f32x4 acc1[2][8] = {}, acc2[2][8] = {};

  #pragma unroll
  for (int s = 0; s < NSEG; ++s){
    const float* Ap = (s==0) ? A0 : ((s==1) ? A1 : A2);
    const u16* Wh = (s==0) ? W0h : ((s==1) ? W1h : W2h);
    const u16* Wl = (s==0) ? W0l : ((s==1) ? W1l : W2l);
    const int fm = (s==1) ? flip1 : 0;
    __syncthreads();
    { // stage A segment, split hi/lo
      int row = tid >> 3, c0 = (tid & 7)*16;
      int arow = (r0 + row) ^ fm;
      const float4* src = (const float4*)(Ap + (size_t)arow*128 + c0);
      #pragma unroll
      for (int q4 = 0; q4 < 4; q4++){
        float4 v = src[q4]; int k = c0 + q4*4;
        u16 h,l;
        split2(v.x,h,l); Ah[row*136+k]  =h; Al[row*136+k]  =l;
        split2(v.y,h,l); Ah[row*136+k+1]=h; Al[row*136+k+1]=l;
        split2(v.z,h,l); Ah[row*136+k+2]=h; Al[row*136+k+2]=l;
        split2(v.w,h,l); Ah[row*136+k+3]=h; Al[row*136+k+3]=l;
      }
    }
    __syncthreads();
    f32x4 (*accp)[8] = (s == NSEG-1) ? acc2 : acc1;
    #pragma unroll
    for (int ks = 0; ks < 4; ks++){
      b16x8 a_h[2], a_l[2];
      #pragma unroll
      for (int mt = 0; mt < 2; mt++){
        int ao = (mt*16 + l15)*136 + ks*32 + quad*8;
        a_h[mt] = *(const b16x8*)(Ah + ao);
        a_l[mt] = *(const b16x8*)(Al + ao);
      }
      #pragma unroll
      for (int ntl = 0; ntl < 8; ntl++){
        int nt = wv*8 + ntl;
        size_t bo = (size_t)((nt*4 + ks)*64 + lane)*8;
        b16x8 bh = *(const b16x8*)(Wh + bo);
        b16x8 bl = *(const b16x8*)(Wl + bo);
        #pragma unroll
        for (int mt = 0; mt < 2; mt++){
          accp[mt][ntl] = __builtin_amdgcn_mfma_f32_16x16x32_bf16(a_h[mt], bh, accp[mt][ntl],0,0,0);
          accp[mt][ntl] = __builtin_amdgcn_mfma_f32_16x16x32_bf16(a_h[mt], bl, accp[mt][ntl],0,0,0);
          accp[mt][ntl] = __builtin_amdgcn_mfma_f32_16x16x32_bf16(a_l[mt], bh, accp[mt][ntl],0,0,0);
        }
      }
    }
  }

  // ---- per-wave row partial sums (over this wave's 128 cols) ----
  #pragma unroll
  for (int mt = 0; mt < 2; mt++)
    #pragma unroll
    for (int r = 0; r < 4; r++){
      float s1=0.f, q1=0.f, s2=0.f, q2=0.f;
      #pragma unroll
      for (int ntl = 0; ntl < 8; ntl++){
        float v1 = acc1[mt][ntl][r]; s1 += v1; q1 += v1*v1;
        float v2 = acc2[mt][ntl][r]; s2 += v2; q2 += v2*v2;
      }
      #pragma unroll
      for (int m = 1; m < 16; m <<= 1){
        s1 += __shfl_xor(s1, m); q1 += __shfl_xor(q1, m);
        s2 += __shfl_xor(s2, m); q2 += __shfl_xor(q2, m);
      }
      if (l15 == 0){
        int row = mt*16 + quad*4 + r;
        red[wv][row][0]=s1; red[wv][row][1]=q1; red[wv][row][2]=s2; red[wv][row][3]=q2;
      }
    }
  __syncthreads();
  if (tid < 32){
    int row = tid;
    float s1 = red[0][row][0]+red[1][row][0]+red[2][row][0]+red[3][row][0];
    float q1 = red[0][row][1]+red[1][row][1]+red[2][row][1]+red[3][row][1];
    float s2 = red[0][row][2]+red[1][row][2]+red[2][row][2]+red[3][row][2];
    float q2 = red[0][row][3]+red[1][row][3]+red[2][row][3]+red[3][row][3];
    const float i512 = 1.f/512.f;
    float m1 = s1*i512, v1 = fmaxf(q1*i512 - m1*m1, 0.f);
    float m2 = s2*i512, v2 = fmaxf(q2*i512 - m2*m2, 0.f);
    st[row][0] = m1; st[row][1] = rsqrtf(v1 + 1e-5f);
    st[row][2] = m2; st[row][3] = rsqrtf(v2 + 1e-5f);
  }
  __syncthreads();

  // ---- write normalized+affine gates to G (acc regs -> LDS; frees Ah/Al alias) ----
  #pragma unroll
  for (int mt = 0; mt < 2; mt++)
    #pragma unroll
    for (int ntl = 0; ntl < 8; ntl++){
      int col = wv*128 + ntl*16 + l15;
      float gi = lni_g[col], bi = lni_b[col];
      float gh = lnh_g[col], bh = lnh_b[col];
      #pragma unroll
      for (int r = 0; r < 4; r++){
        int row = mt*16 + quad*4 + r;
        float v = (acc1[mt][ntl][r] - st[row][0])*st[row][1]*gi + bi
                + (acc2[mt][ntl][r] - st[row][2])*st[row][3]*gh + bh;
        G[row*516 + col] = v;
      }
    }
  __syncthreads();

  // ---- pointwise LSTM + cell LN(128); wave wv owns rows wv*8..wv*8+7 ----
  float lcg0 = lnc_g[lane], lcb0 = lnc_b[lane];
  float lcg1 = lnc_g[lane+64], lcb1 = lnc_b[lane+64];
  const float i128 = 1.f/128.f;
  #pragma unroll
  for (int i = 0; i < 8; i++){
    int row = wv*8 + i;
    int rg = r0 + row;
    float cp[2], sc = 0.f, qc = 0.f;
    #pragma unroll
    for (int jj = 0; jj < 2; jj++){
      int c = lane + 64*jj;
      float iv = sigm(G[row*516 + c]);
      float fv = sigm(G[row*516 + 128 + c]);
      float gv = tanhf(G[row*516 + 256 + c]);
      cp[jj] = fv * c_in[(size_t)rg*128 + c] + iv*gv;
      sc += cp[jj]; qc += cp[jj]*cp[jj];
    }
    #pragma unroll
    for (int m = 1; m < 64; m <<= 1){ sc += __shfl_xor(sc, m); qc += __shfl_xor(qc, m); }
    float mc = sc*i128, vc = fmaxf(qc*i128 - mc*mc, 0.f), rsc = rsqrtf(vc + 1e-5f);
    #pragma unroll
    for (int jj = 0; jj < 2; jj++){
      int c = lane + 64*jj;
      float cy = (cp[jj]-mc)*rsc*(jj ? lcg1 : lcg0) + (jj ? lcb1 : lcb0);
      c_out[(size_t)rg*128 + c] = cy;
      float ov = sigm(G[row*516 + 384 + c]);
      h_out[(size_t)rg*128 + c] = ov*tanhf(cy);
    }
  }
}

// ---------------- generic MFMA GEMM: Y[M,N] = act(A[M,K] @ W + bias) ----------------
// NT tiles of 16 cols per wave (N = NT*64); K = KK32*32.
template<int NT, int KK32, int ACT>
__global__ __launch_bounds__(256) void k_gemm_mfma(const float* __restrict__ A,
    const u16* __restrict__ Wh, const u16* __restrict__ Wl,
    const float* __restrict__ bias, float* __restrict__ Y)
{
  const int N = NT*64;
  const int LDA = KK32*32 + 8;
  __shared__ __align__(16) u16 Ah[32*(KK32*32+8)];
  __shared__ __align__(16) u16 Al[32*(KK32*32+8)];
  const int tid = threadIdx.x, lane = tid & 63, wv = tid >> 6;
  const int quad = lane >> 4, l15 = lane & 15;
  const int r0 = blockIdx.x * 32;
  { // stage A
    int row = tid >> 3, c0 = (tid & 7)*(KK32*4);
    const float4* src = (const float4*)(A + (size_t)(r0+row)*(KK32*32) + c0);
    #pragma unroll
    for (int q4 = 0; q4 < KK32; q4++){
      float4 v = src[q4]; int k = c0 + q4*4;
      u16 h,l;
      split2(v.x,h,l); Ah[row*LDA+k]  =h; Al[row*LDA+k]  =l;
      split2(v.y,h,l); Ah[row*LDA+k+1]=h; Al[row*LDA+k+1]=l;
      split2(v.z,h,l); Ah[row*LDA+k+2]=h; Al[row*LDA+k+2]=l;
      split2(v.w,h,l); Ah[row*LDA+k+3]=h; Al[row*LDA+k+3]=l;
    }
  }
  __syncthreads();
  f32x4 acc[2][NT] = {};
  #pragma unroll
  for (int ks = 0; ks < KK32; ks++){
    b16x8 a_h[2], a_l[2];
    #pragma unroll
    for (int mt = 0; mt < 2; mt++){
      int ao = (mt*16 + l15)*LDA + ks*32 + quad*8;
      a_h[mt] = *(const b16x8*)(Ah + ao);
      a_l[mt] = *(const b16x8*)(Al + ao);
    }
    #pragma unroll
    for (int ntl = 0; ntl < NT; ntl++){
      int nt = wv*NT + ntl;
      size_t bo = (size_t)((nt*KK32 + ks)*64 + lane)*8;
      b16x8 bh = *(const b16x8*)(Wh + bo);
      b16x8 bl = *(const b16x8*)(Wl + bo);
      #pragma unroll
      for (int mt = 0; mt < 2; mt++){
        acc[mt][ntl] = __builtin_amdgcn_mfma_f32_16x16x32_bf16(a_h[mt], bh, acc[mt][ntl],0,0,0);
        acc[mt][ntl] = __builtin_amdgcn_mfma_f32_16x16x32_bf16(a_h[mt], bl, acc[mt][ntl],0,0,0);
        acc[mt][ntl] = __builtin_amdgcn_mfma_f32_16x16x32_bf16(a_l[mt], bh, acc[mt][ntl],0,0,0);
      }
    }
  }
  #pragma unroll
  for (int mt = 0; mt < 2; mt++)
    #pragma unroll
    for (int ntl = 0; ntl < NT; ntl++){
      int col = wv*(NT*16) + ntl*16 + l15;
      float bb = bias[col];
      #pragma unroll
      for (int r = 0; r < 4; r++){
        int row = mt*16 + quad*4 + r;
        float v = acc[mt][ntl][r] + bb;
        if (ACT) v = fmaxf(v, 0.f);
        Y[(size_t)(r0+row)*N + col] = v;
      }
    }
}

// --------- readout: read[b,t] = mask * [Lh[b,t] | Lh[b,t+T]] ---------
__global__ __launch_bounds__(256) void k_read(const float* __restrict__ Lh,
    const int* __restrict__ counts, float* __restrict__ rd)
{
  int i = blockIdx.x*256 + threadIdx.x;
  if (i >= B_*T_*D_) return;
  int d = i & (D_-1);
  int r = i >> 7;
  int t = r & (T_-1);
  int b = r >> 10;
  int half = counts[b] / 2; if (half > T_) half = T_;
  float m = (t < half) ? 1.f : 0.f;
  rd[(size_t)r*C2_ + d]      = m * Lh[(size_t)(b*L_ + t)*D_ + d];
  rd[(size_t)r*C2_ + D_ + d] = m * Lh[(size_t)(b*L_ + t + T_)*D_ + d];
}

// --------- tiled flash attention over fused qkv [4096, 768] ---------
__global__ __launch_bounds__(256) void k_attn_tile(const float* __restrict__ qkv,
    const int* __restrict__ counts, float* __restrict__ y)
{
  const int b = blockIdx.z, h = blockIdx.y, t0 = blockIdx.x*64;
  int half = counts[b] / 2; if (half > T_) half = T_; if (half < 0) half = 0;
  const int tid = threadIdx.x;
  const int lane = tid & 63, wv = tid >> 6;
  const int lr = tid >> 2, lc = (tid & 3)*8;

  if (t0 >= half){
    float* yp = y + ((size_t)(b*T_ + t0 + lr)*C2_ + h*HD_ + lc);
    #pragma unroll
    for (int j = 0; j < 8; j++) yp[j] = 0.f;
    return;
  }

  __shared__ float Qs[64][36];
  __shared__ float Ks[64][32];
  __shared__ float Ss[64][68];

  {
    const float* qp = qkv + (size_t)(b*T_ + t0 + lr)*QS_ + h*HD_ + lc;
    float4 a0 = *(const float4*)qp;
    float4 a1 = *(const float4*)(qp+4);
    *(float4*)&Qs[lr][lc]   = a0;
    *(float4*)&Qs[lr][lc+4] = a1;
  }

  const int ty = tid >> 4, tx = tid & 15;
  const int sr = wv*16 + (lane & 15);
  const int spart = (lane >> 4) * 16;
  const int rp = lane >> 3, cq = lane & 7;
  const int r0 = wv*16 + rp*2;

  float4 acc0 = {0.f,0.f,0.f,0.f}, acc1 = {0.f,0.f,0.f,0.f};
  float mst = -3e38f, lst = 0.f;
  const float scale = 0.17677669529663687f;
  const int nt = (half + 63) >> 6;

  for (int st = 0; st < nt; ++st){
    const int s0 = st*64;
    __syncthreads();
    {
      const float* kp = qkv + (size_t)(b*T_ + s0 + lr)*QS_ + 256 + h*HD_ + lc;
      float4 k0 = *(const float4*)kp;
      float4 k1 = *(const float4*)(kp+4);
      int key = (lr >> 2) & 7;
      int c0 = lc >> 2;
      *(float4*)&Ks[lr][4*((c0  ) ^ key)] = k0;
      *(float4*)&Ks[lr][4*((c0+1) ^ key)] = k1;
    }
    __syncthreads();

    float s4[4][4];
    #pragma unroll
    for (int i = 0; i < 4; i++)
      #pragma unroll
      for (int j = 0; j < 4; j++) s4[i][j] = 0.f;
    const int xk = tx & 7;
    #pragma unroll
    for (int kk4 = 0; kk4 < 8; kk4++){
      float4 a4[4], b4[4];
      #pragma unroll
      for (int i = 0; i < 4; i++) a4[i] = *(const float4*)&Qs[ty*4+i][kk4*4];
      const int pk = 4*(kk4 ^ xk);
      #pragma unroll
      for (int j = 0; j < 4; j++) b4[j] = *(const float4*)&Ks[tx*4+j][pk];
      #pragma unroll
      for (int i = 0; i < 4; i++)
        #pragma unroll
        for (int j = 0; j < 4; j++)
          s4[i][j] += a4[i].x*b4[j].x + a4[i].y*b4[j].y + a4[i].z*b4[j].z + a4[i].w*b4[j].w;
    }
    #pragma unroll
    for (int i = 0; i < 4; i++){
      float4 w4;
      w4.x = (s0 + tx*4 + 0 < half) ? s4[i][0]*scale : -1e30f;
      w4.y = (s0 + tx*4 + 1 < half) ? s4[i][1]*scale : -1e30f;
      w4.z = (s0 + tx*4 + 2 < half) ? s4[i][2]*scale : -1e30f;
      w4.w = (s0 + tx*4 + 3 < half) ? s4[i][3]*scale : -1e30f;
      *(float4*)&Ss[ty*4+i][tx*4] = w4;
    }

    float pvv[16];
    float vmax = -3e38f;
    #pragma unroll
    for (int c4 = 0; c4 < 4; c4++){
      float4 t4 = *(const float4*)&Ss[sr][spart + c4*4];
      pvv[c4*4+0] = t4.x; pvv[c4*4+1] = t4.y; pvv[c4*4+2] = t4.z; pvv[c4*4+3] = t4.w;
      vmax = fmaxf(vmax, fmaxf(fmaxf(t4.x, t4.y), fmaxf(t4.z, t4.w)));
    }
    vmax = fmaxf(vmax, __shfl_xor(vmax, 16));
    vmax = fmaxf(vmax, __shfl_xor(vmax, 32));
    float nm = fmaxf(mst, vmax);
    float alpha = expf(mst - nm);
    float psum = 0.f;
    #pragma unroll
    for (int c = 0; c < 16; c++){
      float p = expf(pvv[c] - nm);
      pvv[c] = p; psum += p;
    }
    psum += __shfl_xor(psum, 16);
    psum += __shfl_xor(psum, 32);
    lst = lst*alpha + psum;
    mst = nm;
    #pragma unroll
    for (int c4 = 0; c4 < 4; c4++){
      float4 w4; w4.x = pvv[c4*4+0]; w4.y = pvv[c4*4+1]; w4.z = pvv[c4*4+2]; w4.w = pvv[c4*4+3];
      *(float4*)&Ss[sr][spart + c4*4] = w4;
    }
    float al0 = __shfl(alpha, 2*rp);
    float al1 = __shfl(alpha, 2*rp + 1);
    acc0.x *= al0; acc0.y *= al0; acc0.z *= al0; acc0.w *= al0;
    acc1.x *= al1; acc1.y *= al1; acc1.z *= al1; acc1.w *= al1;

    const float* vbase = qkv + (size_t)(b*T_ + s0)*QS_ + 512 + h*HD_ + cq*4;
    #pragma unroll 4
    for (int kk4 = 0; kk4 < 16; kk4++){
      float4 p0 = *(const float4*)&Ss[r0  ][kk4*4];
      float4 p1 = *(const float4*)&Ss[r0+1][kk4*4];
      float4 v0 = *(const float4*)(vbase + (size_t)(kk4*4+0)*QS_);
      float4 v1 = *(const float4*)(vbase + (size_t)(kk4*4+1)*QS_);
      float4 v2 = *(const float4*)(vbase + (size_t)(kk4*4+2)*QS_);
      float4 v3 = *(const float4*)(vbase + (size_t)(kk4*4+3)*QS_);
      acc0.x += p0.x*v0.x + p0.y*v1.x + p0.z*v2.x + p0.w*v3.x;
      acc0.y += p0.x*v0.y + p0.y*v1.y + p0.z*v2.y + p0.w*v3.y;
      acc0.z += p0.x*v0.z + p0.y*v1.z + p0.z*v2.z + p0.w*v3.z;
      acc0.w += p0.x*v0.w + p0.y*v1.w + p0.z*v2.w + p0.w*v3.w;
      acc1.x += p1.x*v0.x + p1.y*v1.x + p1.z*v2.x + p1.w*v3.x;
      acc1.y += p1.x*v0.y + p1.y*v1.y + p1.z*v2.y + p1.w*v3.y;
      acc1.z += p1.x*v0.z + p1.y*v1.z + p1.z*v2.z + p1.w*v3.z;
      acc1.w += p1.x*v0.w + p1.y*v1.w + p1.z*v2.w + p1.w*v3.w;
    }
  }

  float l0 = __shfl(lst, 2*rp);
  float l1 = __shfl(lst, 2*rp + 1);
  float m0 = (t0 + r0     < half && l0 > 0.f) ? 1.f/l0 : 0.f;
  float m1 = (t0 + r0 + 1 < half && l1 > 0.f) ? 1.f/l1 : 0.f;
  float4 o0, o1;
  o0.x = acc0.x*m0; o0.y = acc0.y*m0; o0.z = acc0.z*m0; o0.w = acc0.w*m0;
  o1.x = acc1.x*m1; o1.y = acc1.y*m1; o1.z = acc1.z*m1; o1.w = acc1.w*m1;
  *(float4*)(y + ((size_t)(b*T_ + t0 + r0    )*C2_ + h*HD_ + cq*4)) = o0;
  *(float4*)(y + ((size_t)(b*T_ + t0 + r0 + 1)*C2_ + h*HD_ + cq*4)) = o1;
}

// --------- final heads: hv = [asn_hidden(128) | vote_hidden(128)] per row ---------
__global__ __launch_bounds__(128) void k_final(const float* __restrict__ hv,
    const float* __restrict__ aW2, const float* __restrict__ ab2,
    const float* __restrict__ vW2, const float* __restrict__ vb2,
    const int* __restrict__ counts, void* __restrict__ outv,
    float* __restrict__ vote_sum, const int* __restrict__ flag)
{
  int row = blockIdx.x, tid = threadIdx.x;
  int b = row / T_, t = row - b*T_;
  int half = counts[b] / 2; if (half > T_) half = T_;
  float pa = hv[(size_t)row*256 + tid]       * aW2[tid];
  float pv = hv[(size_t)row*256 + 128 + tid] * vW2[tid];
  #pragma unroll
  for (int off = 32; off > 0; off >>= 1){ pa += __shfl_down(pa, off); pv += __shfl_down(pv, off); }
  __shared__ float r[2][2];
  int wid = tid >> 6, lane = tid & 63;
  if (lane == 0){ r[0][wid] = pa; r[1][wid] = pv; }
  __syncthreads();
  if (tid == 0){
    float a  = sigm(r[0][0] + r[0][1] + ab2[0]);
    float vv = sigm(r[1][0] + r[1][1] + vb2[0]);
    bool mk = (t < half);
    float av = mk ? a : 0.f;
    if (*flag) ((u16*)outv)[4 + row] = f2bf(av);
    else       ((float*)outv)[4 + row] = av;
    if (mk) atomicAdd(vote_sum + b, vv);
  }
}

__global__ void k_votes(const float* __restrict__ vote_sum, const int* __restrict__ counts,
                        void* __restrict__ outv, const int* __restrict__ flag){
  int b = threadIdx.x;
  if (b < B_){
    int half = counts[b] / 2; if (half > T_) half = T_;
    float den = (float)(half > 1 ? half : 1);
    float vv = vote_sum[b] / den;
    if (*flag) ((u16*)outv)[b] = f2bf(vv);
    else       ((float*)outv)[b] = vv;
  }
}

extern "C" void kernel_launch(void* const* d_in, const int* in_sizes, int n_in,
                              void* d_out, int out_size, void* d_ws, size_t ws_size,
                              hipStream_t stream)
{
  const void* A_adj = d_in[0];
  const int* counts = (const int*)d_in[1];

  const size_t M1 = (size_t)1048576;
  const size_t NEED = (5*M1 + M1 + 2*M1 + 2*M1 + 700416 + 16416 + 8224
                       + 16384 + 8192 + 520000 + 520000 + 32) * sizeof(float);
  if (ws_size < NEED) return;

  float* ws = (float*)d_ws;
  float* R    = ws;              // 5 x 1M rotating region (Lh lives here)
  float* Lc   = R + 5*M1;
  float* Ch   = Lc + M1;
  float* Cc   = Ch + 2*M1;
  float* wp   = Cc + 2*M1;       // 700416 words: f32 pool + u16 frag pool
  unsigned* off_c = (unsigned*)(wp + 700416);
  unsigned* off_l = off_c + 16416;
  unsigned* cnt_c = off_l + 8224;
  unsigned* cnt_l = cnt_c + 16384;
  u16* val_c = (u16*)(cnt_l + 8192);
  u16* val_l = (u16*)((float*)val_c + 520000);
  float* tail = (float*)val_l + 520000;
  float* vote_sum = tail;
  int* flag = (int*)(tail + 8);
  unsigned* bits = (unsigned*)R;

  float* R0 = R, *R1 = R + M1, *R2 = R + 2*M1, *R3 = R + 3*M1, *R4 = R + 4*M1;

  k_detect<<<1, 256, 0, stream>>>((const unsigned int*)A_adj, flag);

  // ---- f32 param conversion jobs (small tensors only) ----
  CJobs cj;
  int ncj = 0;
  unsigned off = 0;
  auto cadd = [&](int idx, unsigned n)->float*{
    cj.src[ncj] = d_in[idx]; cj.n[ncj] = n; cj.off[ncj] = off;
    float* p = wp + off; off += (n + 3u) & ~3u; ncj++; return p;
  };
  float* Linit = cadd(2, 128);
  float* Cinit = cadd(3, 128);
  float *LC_b1 = cadd(5, 128), *LC_b2 = cadd(7, 128), *LC_b3 = cadd(9, 128);
  float *CL_b1 = cadd(11,128), *CL_b2 = cadd(13,128), *CL_b3 = cadd(15,128);
  float *Lu_lni_g = cadd(18,512), *Lu_lni_b = cadd(19,512);
  float *Lu_lnh_g = cadd(20,512), *Lu_lnh_b = cadd(21,512);
  float *Lu_lnc_g = cadd(22,128), *Lu_lnc_b = cadd(23,128);
  float *Cu_lni_g = cadd(26,512), *Cu_lni_b = cadd(27,512);
  float *Cu_lnh_g = cadd(28,512), *Cu_lnh_b = cadd(29,512);
  float *Cu_lnc_g = cadd(30,128), *Cu_lnc_b = cadd(31,128);
  float *asn_W2 = cadd(40,128), *asn_b2 = cadd(41,1);
  float *vote_W2 = cadd(44,128), *vote_b2 = cadd(45,1);
  // fused qkv bias [768] = [bq | bk | bv]
  float* bqkv = wp + off;
  cj.src[ncj]=d_in[35]; cj.n[ncj]=256; cj.off[ncj]=off;       ncj++;
  cj.src[ncj]=d_in[33]; cj.n[ncj]=256; cj.off[ncj]=off+256;   ncj++;
  cj.src[ncj]=d_in[37]; cj.n[ncj]=256; cj.off[ncj]=off+512;   ncj++;
  off += 768;
  // fused head bias [256] = [asn_b1 | vote_b1]
  float* bhv = wp + off;
  cj.src[ncj]=d_in[39]; cj.n[ncj]=128; cj.off[ncj]=off;       ncj++;
  cj.src[ncj]=d_in[43]; cj.n[ncj]=128; cj.off[ncj]=off+128;   ncj++;
  off += 256;
  { dim3 g(2, NCJ_); k_cvt_all<<<g, 256, 0, stream>>>(cj, wp, flag); }

  // ---- frag-linear split-bf16 weight prep ----
  u16* up = (u16*)(wp + ((off + 3u) & ~3u));
  PJobs pj;
  int npj = 0;
  unsigned uoff = 0;
  auto padd = [&](int idx, unsigned n, unsigned Nw, unsigned koff, unsigned ksb,
                  unsigned dsth, unsigned dstl){
    pj.src[npj]=d_in[idx]; pj.n[npj]=n; pj.N[npj]=Nw; pj.koff[npj]=koff;
    pj.ksb[npj]=ksb; pj.dh[npj]=dsth; pj.dl[npj]=dstl; npj++;
  };
  auto solo = [&](int idx, unsigned n, unsigned Nw, unsigned koff, unsigned ksb,
                  const u16** h, const u16** l){
    padd(idx, n, Nw, koff, ksb, uoff, uoff + n);
    *h = up + uoff; *l = up + uoff + n; uoff += 2*n;
  };
  const u16 *lc1h,*lc1l,*lc2h,*lc2l,*lc3h,*lc3l,*cl1h,*cl1l,*cl2h,*cl2l,*cl3h,*cl3l;
  const u16 *cwih_h,*cwih_l,*cwhh_h,*cwhh_l;
  const u16 *lwa_h,*lwa_l,*lwb_h,*lwb_l,*lwhh_h,*lwhh_l;
  solo(4, 16384,128,0,2,&lc1h,&lc1l);  solo(6, 16384,128,0,2,&lc2h,&lc2l);
  solo(8, 16384,128,0,2,&lc3h,&lc3l);  solo(10,16384,128,0,2,&cl1h,&cl1l);
  solo(12,16384,128,0,2,&cl2h,&cl2l);  solo(14,16384,128,0,2,&cl3h,&cl3l);
  solo(24,65536,512,0,2,&cwih_h,&cwih_l);
  solo(25,65536,512,0,2,&cwhh_h,&cwhh_l);
  solo(16,65536,512,0,  2,&lwa_h,&lwa_l);
  solo(16,65536,512,128,2,&lwb_h,&lwb_l);
  solo(17,65536,512,0,2,&lwhh_h,&lwhh_l);
  // fused qkv W: nt chunks q(0-15) k(16-31) v(32-47); hi block then lo block
  const u16* wqkv_h = up + uoff;
  const u16* wqkv_l = up + uoff + 196608;
  padd(34, 65536, 256, 0, 3, uoff,           uoff+196608);
  padd(32, 65536, 256, 0, 3, uoff+65536,     uoff+196608+65536);
  padd(36, 65536, 256, 0, 3, uoff+131072,    uoff+196608+131072);
  uoff += 393216;
  // fused head W: asn nt 0-7, vote nt 8-15
  const u16* whv_h = up + uoff;
  const u16* whv_l = up + uoff + 65536;
  padd(38, 32768, 128, 0, 3, uoff,        uoff+65536);
  padd(42, 32768, 128, 0, 3, uoff+32768,  uoff+65536+32768);
  uoff += 131072;
  { dim3 g(256, NPJ_); k_prep<<<g, 256, 0, stream>>>(pj, up, flag); }

  // ---- CSR build ----
  k_zero_u<<<(16384+255)/256, 256, 0, stream>>>(cnt_c, 16384);
  k_pack<<<BL_, 128, 0, stream>>>(A_adj, bits, cnt_l, flag);
  k_scan<<<1, 256, 0, stream>>>(cnt_l, off_l, 8192);
  k_fill_l<<<BL_, 128, 0, stream>>>(bits, off_l, val_l, cnt_c);
  k_scan<<<1, 256, 0, stream>>>(cnt_c, off_c, 16384);
  k_fill_c<<<4096, 256, 0, stream>>>(bits, off_c, cnt_c, val_c);

  // ---- init states (overwrites bits region) ----
  k_init<<<(BL_*D_)/256, 256, 0, stream>>>(R0, Lc, Linit, BL_*D_);
  k_init<<<(BNC_*D_)/256, 256, 0, stream>>>(Ch, Cc, Cinit, BNC_*D_);

  for (int it = 0; it < ITERS_; ++it){
    bool ev = ((it & 1) == 0);
    float* cur  = ev ? R0 : R4;
    float* msgL = ev ? R1 : R0;
    float* LCb  = ev ? R2 : R1;
    float* msgC = LCb;
    float* CLb  = ev ? R1 : R3;
    float* nxt  = ev ? R4 : R0;

    k_mlp3m<<<BL_/32, 256, 0, stream>>>(cur, lc1h,lc1l, lc2h,lc2l, lc3h,lc3l,
                                        LC_b1, LC_b2, LC_b3, msgL);
    k_spmm<<<BNC_/4, 256, 0, stream>>>(off_c, val_c, msgL, LCb, 12, 11);
    k_lstm_mfma<2><<<BNC_/32, 256, 0, stream>>>(LCb, Ch, nullptr, 0,
        cwih_h, cwih_l, cwhh_h, cwhh_l, nullptr, nullptr,
        Cu_lni_g, Cu_lni_b, Cu_lnh_g, Cu_lnh_b, Cu_lnc_g, Cu_lnc_b, Cc, Cc, Ch);
    k_mlp3m<<<BNC_/32, 256, 0, stream>>>(Ch, cl1h,cl1l, cl2h,cl2l, cl3h,cl3l,
                                         CL_b1, CL_b2, CL_b3, msgC);
    k_spmm<<<BL_/4, 256, 0, stream>>>(off_l, val_l, msgC, CLb, 11, 12);
    k_lstm_mfma<3><<<BL_/32, 256, 0, stream>>>(CLb, cur, cur, 1024,
        lwa_h, lwa_l, lwb_h, lwb_l, lwhh_h, lwhh_l,
        Lu_lni_g, Lu_lni_b, Lu_lnh_g, Lu_lnh_b, Lu_lnc_g, Lu_lnc_b, Lc, Lc, nxt);
  }
  float* Lh = R0;

  // ---- readout + attention (reuse dead regions) ----
  float* readb = Lc;            // 1M
  float* qkvb  = Ch;            // 3M spans Ch + first 1M of Cc
  float* yb    = R1;            // 1M
  float* hv    = R2;            // 1M: [4096][256]

  k_read<<<(B_*T_*D_)/256, 256, 0, stream>>>(Lh, counts, readb);
  k_gemm_mfma<12,8,0><<<(B_*T_)/32, 256, 0, stream>>>(readb, wqkv_h, wqkv_l, bqkv, qkvb);
  { dim3 g(T_/64, NH_, B_); k_attn_tile<<<g, 256, 0, stream>>>(qkvb, counts, yb); }
  k_gemm_mfma<4,8,1><<<(B_*T_)/32, 256, 0, stream>>>(yb, whv_h, whv_l, bhv, hv);
  k_zero<<<1, 64, 0, stream>>>(vote_sum, B_);
  k_final<<<B_*T_, 128, 0, stream>>>(hv, asn_W2, asn_b2, vote_W2, vote_b2,
                                     counts, d_out, vote_sum, flag);
  k_votes<<<1, 64, 0, stream>>>(vote_sum, counts, d_out, flag);
}

// Round 8
// 1692.363 us; speedup vs baseline: 4.0283x; 1.1278x over previous
//
#include <hip/hip_runtime.h>

// NeuroSATAssign: B=4, L=2048, NC=4096, D=128, ITERS=4, NH=8, T=1024.
// Round 8: occupancy round. (1) attention flash-decoding K-split (2 parts,
// 1024 blocks) + exact online-softmax combine kernel (partials in dead
// R3/R4/Lc); (2) k_lstm_mfma / k_mlp3m at 512 threads (8 waves/block,
// 2x resident waves/CU, same MFMA count); (3) QKV/head GEMMs: 512 thr,
// N-split grids (128x2), k_read fused into QKV staging (gather+flip+mask
// from Lh). Split-f32 MFMA math unchanged from round 7.

#define B_    4
#define L_    2048
#define NC_   4096
#define D_    128
#define ITERS_ 4
#define NH_   8
#define T_    1024
#define C2_   256
#define HD_   32
#define BL_   (B_*L_)    // 8192
#define BNC_  (B_*NC_)   // 16384
#define QS_   768        // fused qkv row stride

typedef unsigned short u16;
typedef __attribute__((ext_vector_type(8))) short b16x8;
typedef __attribute__((ext_vector_type(4))) float f32x4;

static __device__ __forceinline__ float bf2f(u16 u){
  union{unsigned int i; float f;} x; x.i = ((unsigned int)u) << 16; return x.f;
}
static __device__ __forceinline__ u16 f2bf(float f){
  union{float f; unsigned int i;} x; x.f = f;
  unsigned int r = x.i + 0x7fffu + ((x.i >> 16) & 1u);
  return (u16)(r >> 16);
}
static __device__ __forceinline__ float sigm(float x){ return 1.f/(1.f+expf(-x)); }
static __device__ __forceinline__ void split2(float v, u16& h, u16& l){
  unsigned bits = __float_as_uint(v);
  u16 hb = (u16)(bits >> 16);
  float hf = __uint_as_float(((unsigned)hb) << 16);
  h = hb; l = f2bf(v - hf);
}

// ---- dtype detect ----
__global__ __launch_bounds__(256) void k_detect(const unsigned int* __restrict__ a,
                                                int* __restrict__ flag){
  int bad = 0;
  for (int i = threadIdx.x; i < 32768; i += 256){
    unsigned int w = a[i];
    if (w != 0u && w != 0x3F800000u) bad = 1;
  }
  __shared__ int s[256];
  s[threadIdx.x] = bad; __syncthreads();
  for (int o = 128; o > 0; o >>= 1){
    if (threadIdx.x < o) s[threadIdx.x] |= s[threadIdx.x + o];
    __syncthreads();
  }
  if (threadIdx.x == 0) *flag = s[0];
}

// ---- small f32 param conversion ----
#define NCJ_ 29
struct CJobs { const void* src[NCJ_]; unsigned n[NCJ_]; unsigned off[NCJ_]; };

__global__ __launch_bounds__(256) void k_cvt_all(CJobs jb, float* __restrict__ pool,
                                                 const int* __restrict__ flag){
  int j = blockIdx.y;
  unsigned n = jb.n[j];
  unsigned i = blockIdx.x*256 + threadIdx.x;
  if (i >= n) return;
  float v;
  if (*flag) v = bf2f(((const u16*)jb.src[j])[i]);
  else       v = ((const float*)jb.src[j])[i];
  pool[jb.off[j] + i] = v;
}

// ---- weight prep: frag-linear split bf16 ----
#define NPJ_ 16
struct PJobs { const void* src[NPJ_]; unsigned n[NPJ_], N[NPJ_], koff[NPJ_],
               ksb[NPJ_], dh[NPJ_], dl[NPJ_]; };

__global__ __launch_bounds__(256) void k_prep(PJobs pj, u16* __restrict__ up,
                                              const int* __restrict__ flag){
  int jj = blockIdx.y;
  unsigned n = pj.n[jj];
  unsigned g = blockIdx.x*256 + threadIdx.x;
  if (g >= n) return;
  unsigned j = g & 7, lane = (g>>3)&63;
  unsigned ksb = pj.ksb[jj];
  unsigned ks = (g>>9) & ((1u<<ksb)-1u);
  unsigned nt = g >> (9+ksb);
  unsigned ncol = nt*16 + (lane&15);
  unsigned k = pj.koff[jj] + ks*32 + ((lane>>4)&3)*8 + j;
  unsigned si = k*pj.N[jj] + ncol;
  float v;
  if (*flag) v = bf2f(((const u16*)pj.src[jj])[si]);
  else       v = ((const float*)pj.src[jj])[si];
  u16 h,l; split2(v, h, l);
  up[pj.dh[jj] + g] = h;
  up[pj.dl[jj] + g] = l;
}

// ---------------- init ----------------
__global__ __launch_bounds__(256) void k_init(float* __restrict__ h, float* __restrict__ c,
                                              const float* __restrict__ init, int n){
  int i = blockIdx.x*256 + threadIdx.x;
  if (i < n){ h[i] = init[i & (D_-1)]; c[i] = 0.f; }
}

__global__ void k_zero_u(unsigned* __restrict__ p, int n){
  int i = blockIdx.x*256 + threadIdx.x; if (i < n) p[i] = 0u;
}
__global__ void k_zero(float* p, int n){
  int i = blockIdx.x*64 + threadIdx.x; if (i < n) p[i] = 0.f;
}

// ---------------- CSR build ----------------
__global__ __launch_bounds__(128) void k_pack(const void* __restrict__ A,
    unsigned* __restrict__ bits, unsigned* __restrict__ cnt_l,
    const int* __restrict__ flag){
  const int row = blockIdx.x, w = threadIdx.x;
  unsigned m = 0;
  if (*flag){
    const ushort4* p = (const ushort4*)A + (size_t)row*(NC_/4) + w*8;
    #pragma unroll
    for (int i = 0; i < 8; i++){
      ushort4 u = p[i];
      m |= (unsigned)(u.x != 0) << (i*4);
      m |= (unsigned)(u.y != 0) << (i*4+1);
      m |= (unsigned)(u.z != 0) << (i*4+2);
      m |= (unsigned)(u.w != 0) << (i*4+3);
    }
  } else {
    const float4* p = (const float4*)A + (size_t)row*(NC_/4) + w*8;
    #pragma unroll
    for (int i = 0; i < 8; i++){
      float4 v = p[i];
      m |= (unsigned)(v.x != 0.f) << (i*4);
      m |= (unsigned)(v.y != 0.f) << (i*4+1);
      m |= (unsigned)(v.z != 0.f) << (i*4+2);
      m |= (unsigned)(v.w != 0.f) << (i*4+3);
    }
  }
  bits[(size_t)row*128 + w] = m;
  unsigned pc = __popc(m);
  #pragma unroll
  for (int o = 1; o < 64; o <<= 1) pc += __shfl_xor(pc, o);
  __shared__ unsigned ss[2];
  if ((w & 63) == 0) ss[w >> 6] = pc;
  __syncthreads();
  if (w == 0) cnt_l[row] = ss[0] + ss[1];
}

__global__ __launch_bounds__(256) void k_scan(unsigned* __restrict__ cnt,
    unsigned* __restrict__ off, int n){
  __shared__ unsigned ps[257];
  int t = threadIdx.x;
  int seg = n >> 8;
  int base = t*seg;
  unsigned s = 0;
  for (int i = 0; i < seg; i++) s += cnt[base+i];
  ps[t] = s;
  __syncthreads();
  if (t == 0){
    unsigned run = 0;
    for (int i = 0; i < 256; i++){ unsigned x = ps[i]; ps[i] = run; run += x; }
    ps[256] = run;
  }
  __syncthreads();
  unsigned run = ps[t];
  for (int i = 0; i < seg; i++){ off[base+i] = run; run += cnt[base+i]; cnt[base+i] = 0u; }
  if (t == 0) off[n] = ps[256];
}

__global__ __launch_bounds__(128) void k_fill_l(const unsigned* __restrict__ bits,
    const unsigned* __restrict__ off_l, u16* __restrict__ val_l,
    unsigned* __restrict__ cnt_c){
  const int row = blockIdx.x, w = threadIdx.x;
  const int b = row >> 11;
  unsigned m = bits[(size_t)row*128 + w];
  unsigned pc = __popc(m);
  __shared__ unsigned s[128];
  s[w] = pc; __syncthreads();
  #pragma unroll
  for (int o = 1; o < 128; o <<= 1){
    unsigned v = (w >= o) ? s[w-o] : 0u;
    __syncthreads();
    s[w] += v;
    __syncthreads();
  }
  unsigned base = off_l[row] + s[w] - pc;
  unsigned cb = ((unsigned)b << 12) + w*32;
  while (m){
    int j = __ffs(m) - 1; m &= m - 1;
    val_l[base++] = (u16)(w*32 + j);
    atomicAdd(cnt_c + cb + j, 1u);
  }
}

__global__ __launch_bounds__(256) void k_fill_c(const unsigned* __restrict__ bits,
    const unsigned* __restrict__ off_c, unsigned* __restrict__ cur_c,
    u16* __restrict__ val_c){
  int g = blockIdx.x*256 + threadIdx.x;
  unsigned m = bits[g];
  int row = g >> 7, w = g & 127;
  int b = row >> 11, l = row & (L_-1);
  unsigned cb = ((unsigned)b << 12) + w*32;
  while (m){
    int j = __ffs(m) - 1; m &= m - 1;
    unsigned idx = cb + j;
    unsigned pos = atomicAdd(cur_c + idx, 1u);
    val_c[off_c[idx] + pos] = (u16)l;
  }
}

// ---------------- SpMM (f32, exact) ----------------
__global__ __launch_bounds__(256) void k_spmm(const unsigned* __restrict__ off,
    const u16* __restrict__ val, const float* __restrict__ M, float* __restrict__ out,
    int sh1, int sh2){
  int row  = blockIdx.x*4 + (threadIdx.x >> 6);
  int lane = threadIdx.x & 63;
  unsigned p0 = off[row], p1 = off[row+1];
  const float2* Mp = (const float2*)M + (((size_t)(row >> sh1) << sh2) * 64) + lane;
  float x = 0.f, y = 0.f;
  for (unsigned p = p0; p < p1; ++p){
    float2 v = Mp[(size_t)val[p] * 64];
    x += v.x; y += v.y;
  }
  float2 r; r.x = x; r.y = y;
  ((float2*)out)[(size_t)row*64 + lane] = r;
}

// ---------------- MFMA 3-layer MLP: 32 rows/block, 512 thr (8 waves) ----------------
__global__ __launch_bounds__(512) void k_mlp3m(const float* __restrict__ X,
    const u16* __restrict__ W1h, const u16* __restrict__ W1l,
    const u16* __restrict__ W2h, const u16* __restrict__ W2l,
    const u16* __restrict__ W3h, const u16* __restrict__ W3l,
    const float* __restrict__ b1, const float* __restrict__ b2,
    const float* __restrict__ b3, float* __restrict__ Y)
{
  __shared__ __align__(16) u16 Ah[32*136];
  __shared__ __align__(16) u16 Al[32*136];
  const int tid = threadIdx.x, lane = tid & 63, wv = tid >> 6;
  const int quad = lane >> 4, l15 = lane & 15;
  const int r0 = blockIdx.x * 32;
  { // stage X: 8 f32/thread
    int row = tid >> 4, c0 = (tid & 15)*8;
    const float4* src = (const float4*)(X + (size_t)(r0+row)*128 + c0);
    float4 v0 = src[0], v1 = src[1];
    u16 h,l;
    split2(v0.x,h,l); Ah[row*136+c0]  =h; Al[row*136+c0]  =l;
    split2(v0.y,h,l); Ah[row*136+c0+1]=h; Al[row*136+c0+1]=l;
    split2(v0.z,h,l); Ah[row*136+c0+2]=h; Al[row*136+c0+2]=l;
    split2(v0.w,h,l); Ah[row*136+c0+3]=h; Al[row*136+c0+3]=l;
    split2(v1.x,h,l); Ah[row*136+c0+4]=h; Al[row*136+c0+4]=l;
    split2(v1.y,h,l); Ah[row*136+c0+5]=h; Al[row*136+c0+5]=l;
    split2(v1.z,h,l); Ah[row*136+c0+6]=h; Al[row*136+c0+6]=l;
    split2(v1.w,h,l); Ah[row*136+c0+7]=h; Al[row*136+c0+7]=l;
  }
  __syncthreads();
  const u16* Whs[3] = {W1h, W2h, W3h};
  const u16* Wls[3] = {W1l, W2l, W3l};
  const float* bs[3] = {b1, b2, b3};
  #pragma unroll
  for (int layer = 0; layer < 3; layer++){
    f32x4 acc[2] = {};
    #pragma unroll
    for (int ks = 0; ks < 4; ks++){
      b16x8 a_h[2], a_l[2];
      #pragma unroll
      for (int mt = 0; mt < 2; mt++){
        int ao = (mt*16 + l15)*136 + ks*32 + quad*8;
        a_h[mt] = *(const b16x8*)(Ah + ao);
        a_l[mt] = *(const b16x8*)(Al + ao);
      }
      size_t bo = (size_t)((wv*4 + ks)*64 + lane)*8;
      b16x8 bh = *(const b16x8*)(Whs[layer] + bo);
      b16x8 bl = *(const b16x8*)(Wls[layer] + bo);
      #pragma unroll
      for (int mt = 0; mt < 2; mt++){
        acc[mt] = __builtin_amdgcn_mfma_f32_16x16x32_bf16(a_h[mt], bh, acc[mt],0,0,0);
        acc[mt] = __builtin_amdgcn_mfma_f32_16x16x32_bf16(a_h[mt], bl, acc[mt],0,0,0);
        acc[mt] = __builtin_amdgcn_mfma_f32_16x16x32_bf16(a_l[mt], bh, acc[mt],0,0,0);
      }
    }
    int col = wv*16 + l15;
    if (layer < 2){
      float bb = bs[layer][col];
      __syncthreads();
      #pragma unroll
      for (int mt = 0; mt < 2; mt++)
        #pragma unroll
        for (int r = 0; r < 4; r++){
          int row = mt*16 + quad*4 + r;
          float v = fmaxf(acc[mt][r] + bb, 0.f);
          u16 h,l; split2(v,h,l);
          Ah[row*136 + col] = h; Al[row*136 + col] = l;
        }
      __syncthreads();
    } else {
      float bb = bs[2][col];
      #pragma unroll
      for (int mt = 0; mt < 2; mt++)
        #pragma unroll
        for (int r = 0; r < 4; r++){
          int row = mt*16 + quad*4 + r;
          Y[(size_t)(r0+row)*128 + col] = acc[mt][r] + bb;
        }
    }
  }
}

// ---------------- MFMA mega-fused LN-LSTM: 32 rows/block, 512 thr ----------------
template<int NSEG>
__global__ __launch_bounds__(512) void k_lstm_mfma(
    const float* __restrict__ A0, const float* __restrict__ A1, const float* __restrict__ A2,
    int flip1,
    const u16* __restrict__ W0h, const u16* __restrict__ W0l,
    const u16* __restrict__ W1h, const u16* __restrict__ W1l,
    const u16* __restrict__ W2h, const u16* __restrict__ W2l,
    const float* __restrict__ lni_g, const float* __restrict__ lni_b,
    const float* __restrict__ lnh_g, const float* __restrict__ lnh_b,
    const float* __restrict__ lnc_g, const float* __restrict__ lnc_b,
    const float* __restrict__ c_in, float* __restrict__ c_out,
    float* __restrict__ h_out)
{
  __shared__ __align__(16) float G[32*516];    // 66KB; phase1 aliases Ah/Al
  __shared__ float red[8][32][4];
  __shared__ float st[32][4];
  u16* Ah = (u16*)G;
  u16* Al = Ah + 32*136;
  const int tid = threadIdx.x, lane = tid & 63, wv = tid >> 6;
  const int quad = lane >> 4, l15 = lane & 15;
  const int r0 = blockIdx.x * 32;

  f32x4 acc1[2][4] = {}, acc2[2][4] = {};

  #pragma unroll
  for (int s = 0; s < NSEG; ++s){
    const float* Ap = (s==0) ? A0 : ((s==1) ? A1 : A2);
    const u16* Wh = (s==0) ? W0h : ((s==1) ? W1h : W2h);
    const u16* Wl = (s==0) ? W0l : ((s==1) ? W1l : W2l);
    const int fm = (s==1) ? flip1 : 0;
    __syncthreads();
    { // stage A segment, 8 floats/thread
      int row = tid >> 4, c0 = (tid & 15)*8;
      int arow = (r0 + row) ^ fm;
      const float4* src = (const float4*)(Ap + (size_t)arow*128 + c0);
      float4 v0 = src[0], v1 = src[1];
      u16 h,l;
      split2(v0.x,h,l); Ah[row*136+c0]  =h; Al[row*136+c0]  =l;
      split2(v0.y,h,l); Ah[row*136+c0+1]=h; Al[row*136+c0+1]=l;
      split2(v0.z,h,l); Ah[row*136+c0+2]=h; Al[row*136+c0+2]=l;
      split2(v0.w,h,l); Ah[row*136+c0+3]=h; Al[row*136+c0+3]=l;
      split2(v1.x,h,l); Ah[row*136+c0+4]=h; Al[row*136+c0+4]=l;
      split2(v1.y,h,l); Ah[row*136+c0+5]=h; Al[row*136+c0+5]=l;
      split2(v1.z,h,l); Ah[row*136+c0+6]=h; Al[row*136+c0+6]=l;
      split2(v1.w,h,l); Ah[row*136+c0+7]=h; Al[row*136+c0+7]=l;
    }
    __syncthreads();
    f32x4 (*accp)[4] = (s == NSEG-1) ? acc2 : acc1;
    #pragma unroll
    for (int ks = 0; ks < 4; ks++){
      b16x8 a_h[2], a_l[2];
      #pragma unroll
      for (int mt = 0; mt < 2; mt++){
        int ao = (mt*16 + l15)*136 + ks*32 + quad*8;
        a_h[mt] = *(const b16x8*)(Ah + ao);
        a_l[mt] = *(const b16x8*)(Al + ao);
      }
      #pragma unroll
      for (int ntl = 0; ntl < 4; ntl++){
        int nt = wv*4 + ntl;
        size_t bo = (size_t)((nt*4 + ks)*64 + lane)*8;
        b16x8 bh = *(const b16x8*)(Wh + bo);
        b16x8 bl = *(const b16x8*)(Wl + bo);
        #pragma unroll
        for (int mt = 0; mt < 2; mt++){
          accp[mt][ntl] = __builtin_amdgcn_mfma_f32_16x16x32_bf16(a_h[mt], bh, accp[mt][ntl],0,0,0);
          accp[mt][ntl] = __builtin_amdgcn_mfma_f32_16x16x32_bf16(a_h[mt], bl, accp[mt][ntl],0,0,0);
          accp[mt][ntl] = __builtin_amdgcn_mfma_f32_16x16x32_bf16(a_l[mt], bh, accp[mt][ntl],0,0,0);
        }
      }
    }
  }

  // ---- per-wave row partial sums (this wave's 64 cols) ----
  #pragma unroll
  for (int mt = 0; mt < 2; mt++)
    #pragma unroll
    for (int r = 0; r < 4; r++){
      float s1=0.f, q1=0.f, s2=0.f, q2=0.f;
      #pragma unroll
      for (int ntl = 0; ntl < 4; ntl++){
        float v1 = acc1[mt][ntl][r]; s1 += v1; q1 += v1*v1;
        float v2 = acc2[mt][ntl][r]; s2 += v2; q2 += v2*v2;
      }
      #pragma unroll
      for (int m = 1; m < 16; m <<= 1){
        s1 += __shfl_xor(s1, m); q1 += __shfl_xor(q1, m);
        s2 += __shfl_xor(s2, m); q2 += __shfl_xor(q2, m);
      }
      if (l15 == 0){
        int row = mt*16 + quad*4 + r;
        red[wv][row][0]=s1; red[wv][row][1]=q1; red[wv][row][2]=s2; red[wv][row][3]=q2;
      }
    }
  __syncthreads();
  if (tid < 32){
    int row = tid;
    float s1=0.f,q1=0.f,s2=0.f,q2=0.f;
    #pragma unroll
    for (int w = 0; w < 8; w++){
      s1 += red[w][row][0]; q1 += red[w][row][1];
      s2 += red[w][row][2]; q2 += red[w][row][3];
    }
    const float i512 = 1.f/512.f;
    float m1 = s1*i512, v1 = fmaxf(q1*i512 - m1*m1, 0.f);
    float m2 = s2*i512, v2 = fmaxf(q2*i512 - m2*m2, 0.f);
    st[row][0] = m1; st[row][1] = rsqrtf(v1 + 1e-5f);
    st[row][2] = m2; st[row][3] = rsqrtf(v2 + 1e-5f);
  }
  __syncthreads();

  // ---- normalized+affine gates -> G ----
  #pragma unroll
  for (int mt = 0; mt < 2; mt++)
    #pragma unroll
    for (int ntl = 0; ntl < 4; ntl++){
      int col = wv*64 + ntl*16 + l15;
      float gi = lni_g[col], bi = lni_b[col];
      float gh = lnh_g[col], bh = lnh_b[col];
      #pragma unroll
      for (int r = 0; r < 4; r++){
        int row = mt*16 + quad*4 + r;
        float v = (acc1[mt][ntl][r] - st[row][0])*st[row][1]*gi + bi
                + (acc2[mt][ntl][r] - st[row][2])*st[row][3]*gh + bh;
        G[row*516 + col] = v;
      }
    }
  __syncthreads();

  // ---- pointwise LSTM + cell LN(128); wave owns 4 rows ----
  float lcg0 = lnc_g[lane], lcb0 = lnc_b[lane];
  float lcg1 = lnc_g[lane+64], lcb1 = lnc_b[lane+64];
  const float i128 = 1.f/128.f;
  #pragma unroll
  for (int i = 0; i < 4; i++){
    int row = wv*4 + i;
    int rg = r0 + row;
    float cp[2], sc = 0.f, qc = 0.f;
    #pragma unroll
    for (int jj = 0; jj < 2; jj++){
      int c = lane + 64*jj;
      float iv = sigm(G[row*516 + c]);
      float fv = sigm(G[row*516 + 128 + c]);
      float gv = tanhf(G[row*516 + 256 + c]);
      cp[jj] = fv * c_in[(size_t)rg*128 + c] + iv*gv;
      sc += cp[jj]; qc += cp[jj]*cp[jj];
    }
    #pragma unroll
    for (int m = 1; m < 64; m <<= 1){ sc += __shfl_xor(sc, m); qc += __shfl_xor(qc, m); }
    float mc = sc*i128, vc = fmaxf(qc*i128 - mc*mc, 0.f), rsc = rsqrtf(vc + 1e-5f);
    #pragma unroll
    for (int jj = 0; jj < 2; jj++){
      int c = lane + 64*jj;
      float cy = (cp[jj]-mc)*rsc*(jj ? lcg1 : lcg0) + (jj ? lcb1 : lcb0);
      c_out[(size_t)rg*128 + c] = cy;
      float ov = sigm(G[row*516 + 384 + c]);
      h_out[(size_t)rg*128 + c] = ov*tanhf(cy);
    }
  }
}

// ---------------- MFMA GEMM, 512 thr, N-split grid.y; optional readout gather ----------------
// Block: 32 rows x (8*NT*16) cols at col-offset blockIdx.y*8*NT*16. NTOT = NSPLIT*8*NT*16.
template<int NT, int NSPLIT, int KK32, int ACT, int GATHER>
__global__ __launch_bounds__(512) void k_gemm_mfma(const float* __restrict__ A,
    const u16* __restrict__ Wh, const u16* __restrict__ Wl,
    const float* __restrict__ bias, float* __restrict__ Y,
    const int* __restrict__ counts)
{
  const int NTOT = NSPLIT*8*NT*16;
  const int LDA = KK32*32 + 8;
  __shared__ __align__(16) u16 Ah[32*(KK32*32+8)];
  __shared__ __align__(16) u16 Al[32*(KK32*32+8)];
  const int tid = threadIdx.x, lane = tid & 63, wv = tid >> 6;
  const int quad = lane >> 4, l15 = lane & 15;
  const int r0 = blockIdx.x * 32, by = blockIdx.y;
  { // stage A: 32 x KK32*32 floats, KK32*2 per thread
    int row = tid >> 4, c0 = (tid & 15)*(KK32*2);
    if (GATHER){
      // A == Lh [B,L,D]; logical row r -> [mask*Lh[b,t] | mask*Lh[b,t+T]]
      int r = r0 + row; int b = r >> 10; int t = r & 1023;
      int half = counts[b] / 2; if (half > T_) half = T_;
      float msk = (t < half) ? 1.f : 0.f;
      #pragma unroll
      for (int q4 = 0; q4 < KK32/2; q4++){
        int c = c0 + q4*4;
        const float* src = A + ((size_t)(b*L_ + t + ((c >= 128) ? T_ : 0))*128 + (c & 127));
        float4 v = *(const float4*)src;
        u16 h,l;
        split2(v.x*msk,h,l); Ah[row*LDA+c]  =h; Al[row*LDA+c]  =l;
        split2(v.y*msk,h,l); Ah[row*LDA+c+1]=h; Al[row*LDA+c+1]=l;
        split2(v.z*msk,h,l); Ah[row*LDA+c+2]=h; Al[row*LDA+c+2]=l;
        split2(v.w*msk,h,l); Ah[row*LDA+c+3]=h; Al[row*LDA+c+3]=l;
      }
    } else {
      const float4* src = (const float4*)(A + (size_t)(r0+row)*(KK32*32) + c0);
      #pragma unroll
      for (int q4 = 0; q4 < KK32/2; q4++){
        float4 v = src[q4]; int c = c0 + q4*4;
        u16 h,l;
        split2(v.x,h,l); Ah[row*LDA+c]  =h; Al[row*LDA+c]  =l;
        split2(v.y,h,l); Ah[row*LDA+c+1]=h; Al[row*LDA+c+1]=l;
        split2(v.z,h,l); Ah[row*LDA+c+2]=h; Al[row*LDA+c+2]=l;
        split2(v.w,h,l); Ah[row*LDA+c+3]=h; Al[row*LDA+c+3]=l;
      }
    }
  }
  __syncthreads();
  f32x4 acc[2][NT] = {};
  #pragma unroll
  for (int ks = 0; ks < KK32; ks++){
    b16x8 a_h[2], a_l[2];
    #pragma unroll
    for (int mt = 0; mt < 2; mt++){
      int ao = (mt*16 + l15)*LDA + ks*32 + quad*8;
      a_h[mt] = *(const b16x8*)(Ah + ao);
      a_l[mt] = *(const b16x8*)(Al + ao);
    }
    #pragma unroll
    for (int ntl = 0; ntl < NT; ntl++){
      int nt = by*(8*NT) + wv*NT + ntl;
      size_t bo = (size_t)((nt*KK32 + ks)*64 + lane)*8;
      b16x8 bh = *(const b16x8*)(Wh + bo);
      b16x8 bl = *(const b16x8*)(Wl + bo);
      #pragma unroll
      for (int mt = 0; mt < 2; mt++){
        acc[mt][ntl] = __builtin_amdgcn_mfma_f32_16x16x32_bf16(a_h[mt], bh, acc[mt][ntl],0,0,0);
        acc[mt][ntl] = __builtin_amdgcn_mfma_f32_16x16x32_bf16(a_h[mt], bl, acc[mt][ntl],0,0,0);
        acc[mt][ntl] = __builtin_amdgcn_mfma_f32_16x16x32_bf16(a_l[mt], bh, acc[mt][ntl],0,0,0);
      }
    }
  }
  #pragma unroll
  for (int mt = 0; mt < 2; mt++)
    #pragma unroll
    for (int ntl = 0; ntl < NT; ntl++){
      int colg = by*(8*NT*16) + wv*(NT*16) + ntl*16 + l15;
      float bb = bias[colg];
      #pragma unroll
      for (int r = 0; r < 4; r++){
        int row = mt*16 + quad*4 + r;
        float v = acc[mt][ntl][r] + bb;
        if (ACT) v = fmaxf(v, 0.f);
        Y[(size_t)(r0+row)*NTOT + colg] = v;
      }
    }
}

// --------- flash attention, K-split (part = blockIdx.z&1 covers s in [p*512,(p+1)*512)) ---------
// Writes UNNORMALIZED acc (at scale m) to Pa[part] and (m,l) to ML[part]; combine kernel merges.
__global__ __launch_bounds__(256) void k_attn_split(const float* __restrict__ qkv,
    const int* __restrict__ counts, float* __restrict__ Pa, float* __restrict__ ML)
{
  const int z = blockIdx.z, b = z >> 1, part = z & 1;
  const int h = blockIdx.y, t0 = blockIdx.x*64;
  int half = counts[b] / 2; if (half > T_) half = T_; if (half < 0) half = 0;
  const int sbeg = part*512;
  const int send = (half < sbeg + 512) ? half : (sbeg + 512);
  if (t0 >= half || sbeg >= send) return;   // combine masks/skips
  const int tid = threadIdx.x;
  const int lane = tid & 63, wv = tid >> 6;
  const int lr = tid >> 2, lc = (tid & 3)*8;

  __shared__ float Qs[64][36];
  __shared__ float Ks[64][32];
  __shared__ float Ss[64][68];

  {
    const float* qp = qkv + (size_t)(b*T_ + t0 + lr)*QS_ + h*HD_ + lc;
    float4 a0 = *(const float4*)qp;
    float4 a1 = *(const float4*)(qp+4);
    *(float4*)&Qs[lr][lc]   = a0;
    *(float4*)&Qs[lr][lc+4] = a1;
  }

  const int ty = tid >> 4, tx = tid & 15;
  const int sr = wv*16 + (lane & 15);
  const int spart = (lane >> 4) * 16;
  const int rp = lane >> 3, cq = lane & 7;
  const int r0 = wv*16 + rp*2;

  float4 acc0 = {0.f,0.f,0.f,0.f}, acc1 = {0.f,0.f,0.f,0.f};
  float mst = -3e38f, lst = 0.f;
  const float scale = 0.17677669529663687f;
  const int ntile = (send - sbeg + 63) >> 6;

  for (int st = 0; st < ntile; ++st){
    const int s0 = sbeg + st*64;
    __syncthreads();
    {
      const float* kp = qkv + (size_t)(b*T_ + s0 + lr)*QS_ + 256 + h*HD_ + lc;
      float4 k0 = *(const float4*)kp;
      float4 k1 = *(const float4*)(kp+4);
      int key = (lr >> 2) & 7;
      int c0 = lc >> 2;
      *(float4*)&Ks[lr][4*((c0  ) ^ key)] = k0;
      *(float4*)&Ks[lr][4*((c0+1) ^ key)] = k1;
    }
    __syncthreads();

    float s4[4][4];
    #pragma unroll
    for (int i = 0; i < 4; i++)
      #pragma unroll
      for (int j = 0; j < 4; j++) s4[i][j] = 0.f;
    const int xk = tx & 7;
    #pragma unroll
    for (int kk4 = 0; kk4 < 8; kk4++){
      float4 a4[4], b4[4];
      #pragma unroll
      for (int i = 0; i < 4; i++) a4[i] = *(const float4*)&Qs[ty*4+i][kk4*4];
      const int pk = 4*(kk4 ^ xk);
      #pragma unroll
      for (int j = 0; j < 4; j++) b4[j] = *(const float4*)&Ks[tx*4+j][pk];
      #pragma unroll
      for (int i = 0; i < 4; i++)
        #pragma unroll
        for (int j = 0; j < 4; j++)
          s4[i][j] += a4[i].x*b4[j].x + a4[i].y*b4[j].y + a4[i].z*b4[j].z + a4[i].w*b4[j].w;
    }
    #pragma unroll
    for (int i = 0; i < 4; i++){
      float4 w4;
      w4.x = (s0 + tx*4 + 0 < half) ? s4[i][0]*scale : -1e30f;
      w4.y = (s0 + tx*4 + 1 < half) ? s4[i][1]*scale : -1e30f;
      w4.z = (s0 + tx*4 + 2 < half) ? s4[i][2]*scale : -1e30f;
      w4.w = (s0 + tx*4 + 3 < half) ? s4[i][3]*scale : -1e30f;
      *(float4*)&Ss[ty*4+i][tx*4] = w4;
    }

    float pvv[16];
    float vmax = -3e38f;
    #pragma unroll
    for (int c4 = 0; c4 < 4; c4++){
      float4 t4 = *(const float4*)&Ss[sr][spart + c4*4];
      pvv[c4*4+0] = t4.x; pvv[c4*4+1] = t4.y; pvv[c4*4+2] = t4.z; pvv[c4*4+3] = t4.w;
      vmax = fmaxf(vmax, fmaxf(fmaxf(t4.x, t4.y), fmaxf(t4.z, t4.w)));
    }
    vmax = fmaxf(vmax, __shfl_xor(vmax, 16));
    vmax = fmaxf(vmax, __shfl_xor(vmax, 32));
    float nm = fmaxf(mst, vmax);
    float alpha = expf(mst - nm);
    float psum = 0.f;
    #pragma unroll
    for (int c = 0; c < 16; c++){
      float p = expf(pvv[c] - nm);
      pvv[c] = p; psum += p;
    }
    psum += __shfl_xor(psum, 16);
    psum += __shfl_xor(psum, 32);
    lst = lst*alpha + psum;
    mst = nm;
    #pragma unroll
    for (int c4 = 0; c4 < 4; c4++){
      float4 w4; w4.x = pvv[c4*4+0]; w4.y = pvv[c4*4+1]; w4.z = pvv[c4*4+2]; w4.w = pvv[c4*4+3];
      *(float4*)&Ss[sr][spart + c4*4] = w4;
    }
    float al0 = __shfl(alpha, 2*rp);
    float al1 = __shfl(alpha, 2*rp + 1);
    acc0.x *= al0; acc0.y *= al0; acc0.z *= al0; acc0.w *= al0;
    acc1.x *= al1; acc1.y *= al1; acc1.z *= al1; acc1.w *= al1;

    const float* vbase = qkv + (size_t)(b*T_ + s0)*QS_ + 512 + h*HD_ + cq*4;
    #pragma unroll 4
    for (int kk4 = 0; kk4 < 16; kk4++){
      float4 p0 = *(const float4*)&Ss[r0  ][kk4*4];
      float4 p1 = *(const float4*)&Ss[r0+1][kk4*4];
      float4 v0 = *(const float4*)(vbase + (size_t)(kk4*4+0)*QS_);
      float4 v1 = *(const float4*)(vbase + (size_t)(kk4*4+1)*QS_);
      float4 v2 = *(const float4*)(vbase + (size_t)(kk4*4+2)*QS_);
      float4 v3 = *(const float4*)(vbase + (size_t)(kk4*4+3)*QS_);
      acc0.x += p0.x*v0.x + p0.y*v1.x + p0.z*v2.x + p0.w*v3.x;
      acc0.y += p0.x*v0.y + p0.y*v1.y + p0.z*v2.y + p0.w*v3.y;
      acc0.z += p0.x*v0.z + p0.y*v1.z + p0.z*v2.z + p0.w*v3.z;
      acc0.w += p0.x*v0.w + p0.y*v1.w + p0.z*v2.w + p0.w*v3.w;
      acc1.x += p1.x*v0.x + p1.y*v1.x + p1.z*v2.x + p1.w*v3.x;
      acc1.y += p1.x*v0.y + p1.y*v1.y + p1.z*v2.y + p1.w*v3.y;
      acc1.z += p1.x*v0.z + p1.y*v1.z + p1.z*v2.z + p1.w*v3.z;
      acc1.w += p1.x*v0.w + p1.y*v1.w + p1.z*v2.w + p1.w*v3.w;
    }
  }

  // ---- write partials (unnormalized) ----
  const int prow0 = (b*NH_ + h)*T_ + t0;
  float* accP = Pa + (size_t)part*1048576;
  *(float4*)(accP + (size_t)(prow0 + r0    )*32 + cq*4) = acc0;
  *(float4*)(accP + (size_t)(prow0 + r0 + 1)*32 + cq*4) = acc1;
  if (lane < 16){
    float* mlP = ML + (size_t)part*65536;
    int rr = prow0 + wv*16 + lane;
    mlP[(size_t)rr*2]   = mst;
    mlP[(size_t)rr*2+1] = lst;
  }
}

// --------- combine the two K-partitions (exact online-softmax merge) ---------
__global__ __launch_bounds__(256) void k_attn_comb(const float* __restrict__ Pa,
    const float* __restrict__ ML, const int* __restrict__ counts,
    float* __restrict__ y)
{
  int g = blockIdx.x*256 + threadIdx.x;        // < 1048576
  int r = g >> 8, c = g & 255;
  int b = r >> 10, t = r & 1023;
  int h = c >> 5, cc = c & 31;
  int half = counts[b] / 2; if (half > T_) half = T_;
  float out = 0.f;
  if (t < half){
    int prow = (b*NH_ + h)*T_ + t;
    float m0 = ML[(size_t)prow*2], l0 = ML[(size_t)prow*2+1];
    float a0 = Pa[(size_t)prow*32 + cc];
    if (half > 512){
      float m1 = ML[65536 + (size_t)prow*2], l1 = ML[65536 + (size_t)prow*2+1];
      float a1 = Pa[1048576 + (size_t)prow*32 + cc];
      float m = fmaxf(m0, m1);
      float w0 = expf(m0 - m), w1 = expf(m1 - m);
      float den = w0*l0 + w1*l1;
      out = (den > 0.f) ? (w0*a0 + w1*a1)/den : 0.f;
    } else {
      out = (l0 > 0.f) ? a0/l0 : 0.f;
    }
  }
  y[(size_t)r*256 + c] = out;
}

// --------- final heads ---------
__global__ __launch_bounds__(128) void k_final(const float* __restrict__ hv,
    const float* __restrict__ aW2, const float* __restrict__ ab2,
    const float* __restrict__ vW2, const float* __restrict__ vb2,
    const int* __restrict__ counts, void* __restrict__ outv,
    float* __restrict__ vote_sum, const int* __restrict__ flag)
{
  int row = blockIdx.x, tid = threadIdx.x;
  int b = row / T_, t = row - b*T_;
  int half = counts[b] / 2; if (half > T_) half = T_;
  float pa = hv[(size_t)row*256 + tid]       * aW2[tid];
  float pv = hv[(size_t)row*256 + 128 + tid] * vW2[tid];
  #pragma unroll
  for (int off = 32; off > 0; off >>= 1){ pa += __shfl_down(pa, off); pv += __shfl_down(pv, off); }
  __shared__ float r[2][2];
  int wid = tid >> 6, lane = tid & 63;
  if (lane == 0){ r[0][wid] = pa; r[1][wid] = pv; }
  __syncthreads();
  if (tid == 0){
    float a  = sigm(r[0][0] + r[0][1] + ab2[0]);
    float vv = sigm(r[1][0] + r[1][1] + vb2[0]);
    bool mk = (t < half);
    float av = mk ? a : 0.f;
    if (*flag) ((u16*)outv)[4 + row] = f2bf(av);
    else       ((float*)outv)[4 + row] = av;
    if (mk) atomicAdd(vote_sum + b, vv);
  }
}

__global__ void k_votes(const float* __restrict__ vote_sum, const int* __restrict__ counts,
                        void* __restrict__ outv, const int* __restrict__ flag){
  int b = threadIdx.x;
  if (b < B_){
    int half = counts[b] / 2; if (half > T_) half = T_;
    float den = (float)(half > 1 ? half : 1);
    float vv = vote_sum[b] / den;
    if (*flag) ((u16*)outv)[b] = f2bf(vv);
    else       ((float*)outv)[b] = vv;
  }
}

extern "C" void kernel_launch(void* const* d_in, const int* in_sizes, int n_in,
                              void* d_out, int out_size, void* d_ws, size_t ws_size,
                              hipStream_t stream)
{
  const void* A_adj = d_in[0];
  const int* counts = (const int*)d_in[1];

  const size_t M1 = (size_t)1048576;
  const size_t NEED = (5*M1 + M1 + 2*M1 + 2*M1 + 700416 + 16416 + 8224
                       + 16384 + 8192 + 520000 + 520000 + 32) * sizeof(float);
  if (ws_size < NEED) return;

  float* ws = (float*)d_ws;
  float* R    = ws;              // 5 x 1M rotating region (Lh lives here)
  float* Lc   = R + 5*M1;
  float* Ch   = Lc + M1;
  float* Cc   = Ch + 2*M1;
  float* wp   = Cc + 2*M1;       // f32 pool + u16 frag pool
  unsigned* off_c = (unsigned*)(wp + 700416);
  unsigned* off_l = off_c + 16416;
  unsigned* cnt_c = off_l + 8224;
  unsigned* cnt_l = cnt_c + 16384;
  u16* val_c = (u16*)(cnt_l + 8192);
  u16* val_l = (u16*)((float*)val_c + 520000);
  float* tail = (float*)val_l + 520000;
  float* vote_sum = tail;
  int* flag = (int*)(tail + 8);
  unsigned* bits = (unsigned*)R;

  float* R0 = R, *R1 = R + M1, *R2 = R + 2*M1, *R3 = R + 3*M1, *R4 = R + 4*M1;

  k_detect<<<1, 256, 0, stream>>>((const unsigned int*)A_adj, flag);

  // ---- f32 param conversion jobs ----
  CJobs cj;
  int ncj = 0;
  unsigned off = 0;
  auto cadd = [&](int idx, unsigned n)->float*{
    cj.src[ncj] = d_in[idx]; cj.n[ncj] = n; cj.off[ncj] = off;
    float* p = wp + off; off += (n + 3u) & ~3u; ncj++; return p;
  };
  float* Linit = cadd(2, 128);
  float* Cinit = cadd(3, 128);
  float *LC_b1 = cadd(5, 128), *LC_b2 = cadd(7, 128), *LC_b3 = cadd(9, 128);
  float *CL_b1 = cadd(11,128), *CL_b2 = cadd(13,128), *CL_b3 = cadd(15,128);
  float *Lu_lni_g = cadd(18,512), *Lu_lni_b = cadd(19,512);
  float *Lu_lnh_g = cadd(20,512), *Lu_lnh_b = cadd(21,512);
  float *Lu_lnc_g = cadd(22,128), *Lu_lnc_b = cadd(23,128);
  float *Cu_lni_g = cadd(26,512), *Cu_lni_b = cadd(27,512);
  float *Cu_lnh_g = cadd(28,512), *Cu_lnh_b = cadd(29,512);
  float *Cu_lnc_g = cadd(30,128), *Cu_lnc_b = cadd(31,128);
  float *asn_W2 = cadd(40,128), *asn_b2 = cadd(41,1);
  float *vote_W2 = cadd(44,128), *vote_b2 = cadd(45,1);
  float* bqkv = wp + off;
  cj.src[ncj]=d_in[35]; cj.n[ncj]=256; cj.off[ncj]=off;       ncj++;
  cj.src[ncj]=d_in[33]; cj.n[ncj]=256; cj.off[ncj]=off+256;   ncj++;
  cj.src[ncj]=d_in[37]; cj.n[ncj]=256; cj.off[ncj]=off+512;   ncj++;
  off += 768;
  float* bhv = wp + off;
  cj.src[ncj]=d_in[39]; cj.n[ncj]=128; cj.off[ncj]=off;       ncj++;
  cj.src[ncj]=d_in[43]; cj.n[ncj]=128; cj.off[ncj]=off+128;   ncj++;
  off += 256;
  { dim3 g(2, NCJ_); k_cvt_all<<<g, 256, 0, stream>>>(cj, wp, flag); }

  // ---- frag-linear split-bf16 weight prep ----
  u16* up = (u16*)(wp + ((off + 3u) & ~3u));
  PJobs pj;
  int npj = 0;
  unsigned uoff = 0;
  auto padd = [&](int idx, unsigned n, unsigned Nw, unsigned koff, unsigned ksb,
                  unsigned dsth, unsigned dstl){
    pj.src[npj]=d_in[idx]; pj.n[npj]=n; pj.N[npj]=Nw; pj.koff[npj]=koff;
    pj.ksb[npj]=ksb; pj.dh[npj]=dsth; pj.dl[npj]=dstl; npj++;
  };
  auto solo = [&](int idx, unsigned n, unsigned Nw, unsigned koff, unsigned ksb,
                  const u16** h, const u16** l){
    padd(idx, n, Nw, koff, ksb, uoff, uoff + n);
    *h = up + uoff; *l = up + uoff + n; uoff += 2*n;
  };
  const u16 *lc1h,*lc1l,*lc2h,*lc2l,*lc3h,*lc3l,*cl1h,*cl1l,*cl2h,*cl2l,*cl3h,*cl3l;
  const u16 *cwih_h,*cwih_l,*cwhh_h,*cwhh_l;
  const u16 *lwa_h,*lwa_l,*lwb_h,*lwb_l,*lwhh_h,*lwhh_l;
  solo(4, 16384,128,0,2,&lc1h,&lc1l);  solo(6, 16384,128,0,2,&lc2h,&lc2l);
  solo(8, 16384,128,0,2,&lc3h,&lc3l);  solo(10,16384,128,0,2,&cl1h,&cl1l);
  solo(12,16384,128,0,2,&cl2h,&cl2l);  solo(14,16384,128,0,2,&cl3h,&cl3l);
  solo(24,65536,512,0,2,&cwih_h,&cwih_l);
  solo(25,65536,512,0,2,&cwhh_h,&cwhh_l);
  solo(16,65536,512,0,  2,&lwa_h,&lwa_l);
  solo(16,65536,512,128,2,&lwb_h,&lwb_l);
  solo(17,65536,512,0,2,&lwhh_h,&lwhh_l);
  const u16* wqkv_h = up + uoff;
  const u16* wqkv_l = up + uoff + 196608;
  padd(34, 65536, 256, 0, 3, uoff,           uoff+196608);
  padd(32, 65536, 256, 0, 3, uoff+65536,     uoff+196608+65536);
  padd(36, 65536, 256, 0, 3, uoff+131072,    uoff+196608+131072);
  uoff += 393216;
  const u16* whv_h = up + uoff;
  const u16* whv_l = up + uoff + 65536;
  padd(38, 32768, 128, 0, 3, uoff,        uoff+65536);
  padd(42, 32768, 128, 0, 3, uoff+32768,  uoff+65536+32768);
  uoff += 131072;
  { dim3 g(256, NPJ_); k_prep<<<g, 256, 0, stream>>>(pj, up, flag); }

  // ---- CSR build ----
  k_zero_u<<<(16384+255)/256, 256, 0, stream>>>(cnt_c, 16384);
  k_pack<<<BL_, 128, 0, stream>>>(A_adj, bits, cnt_l, flag);
  k_scan<<<1, 256, 0, stream>>>(cnt_l, off_l, 8192);
  k_fill_l<<<BL_, 128, 0, stream>>>(bits, off_l, val_l, cnt_c);
  k_scan<<<1, 256, 0, stream>>>(cnt_c, off_c, 16384);
  k_fill_c<<<4096, 256, 0, stream>>>(bits, off_c, cnt_c, val_c);

  // ---- init states (overwrites bits region) ----
  k_init<<<(BL_*D_)/256, 256, 0, stream>>>(R0, Lc, Linit, BL_*D_);
  k_init<<<(BNC_*D_)/256, 256, 0, stream>>>(Ch, Cc, Cinit, BNC_*D_);

  for (int it = 0; it < ITERS_; ++it){
    bool ev = ((it & 1) == 0);
    float* cur  = ev ? R0 : R4;
    float* msgL = ev ? R1 : R0;
    float* LCb  = ev ? R2 : R1;
    float* msgC = LCb;
    float* CLb  = ev ? R1 : R3;
    float* nxt  = ev ? R4 : R0;

    k_mlp3m<<<BL_/32, 512, 0, stream>>>(cur, lc1h,lc1l, lc2h,lc2l, lc3h,lc3l,
                                        LC_b1, LC_b2, LC_b3, msgL);
    k_spmm<<<BNC_/4, 256, 0, stream>>>(off_c, val_c, msgL, LCb, 12, 11);
    k_lstm_mfma<2><<<BNC_/32, 512, 0, stream>>>(LCb, Ch, nullptr, 0,
        cwih_h, cwih_l, cwhh_h, cwhh_l, nullptr, nullptr,
        Cu_lni_g, Cu_lni_b, Cu_lnh_g, Cu_lnh_b, Cu_lnc_g, Cu_lnc_b, Cc, Cc, Ch);
    k_mlp3m<<<BNC_/32, 512, 0, stream>>>(Ch, cl1h,cl1l, cl2h,cl2l, cl3h,cl3l,
                                         CL_b1, CL_b2, CL_b3, msgC);
    k_spmm<<<BL_/4, 256, 0, stream>>>(off_l, val_l, msgC, CLb, 11, 12);
    k_lstm_mfma<3><<<BL_/32, 512, 0, stream>>>(CLb, cur, cur, 1024,
        lwa_h, lwa_l, lwb_h, lwb_l, lwhh_h, lwhh_l,
        Lu_lni_g, Lu_lni_b, Lu_lnh_g, Lu_lnh_b, Lu_lnc_g, Lu_lnc_b, Lc, Lc, nxt);
  }
  float* Lh = R0;

  // ---- readout+qkv (fused gather), split attention, combine, heads ----
  float* qkvb  = Ch;            // 3M spans Ch + first 1M of Cc
  float* yb    = R1;            // 1M
  float* hv    = R2;            // 1M
  // attention partials: acc in R3(+R4 contiguous), (m,l) in Lc — all dead now

  { dim3 g((B_*T_)/32, 2);
    k_gemm_mfma<3,2,8,0,1><<<g, 512, 0, stream>>>(Lh, wqkv_h, wqkv_l, bqkv, qkvb, counts); }
  { dim3 g(T_/64, NH_, B_*2);
    k_attn_split<<<g, 256, 0, stream>>>(qkvb, counts, R3, Lc); }
  k_attn_comb<<<4096, 256, 0, stream>>>(R3, Lc, counts, yb);
  { dim3 g((B_*T_)/32, 2);
    k_gemm_mfma<1,2,8,1,0><<<g, 512, 0, stream>>>(yb, whv_h, whv_l, bhv, hv, counts); }
  k_zero<<<1, 64, 0, stream>>>(vote_sum, B_);
  k_final<<<B_*T_, 128, 0, stream>>>(hv, asn_W2, asn_b2, vote_W2, vote_b2,
                                     counts, d_out, vote_sum, flag);
  k_votes<<<1, 64, 0, stream>>>(vote_sum, counts, d_out, flag);
}